// Round 9
// baseline (717.428 us; speedup 1.0000x reference)
//
#include <hip/hip_runtime.h>
#include <hip/hip_bf16.h>
#include <cmath>

// LSS pipeline R9: conv3_bevm B-dbuf (1 barrier/tap) + sA pad 44;
// heads as MFMA GEMM on bf16 NHWC x2; one-pass k_final2; meanN fused into gemm1.

typedef __attribute__((ext_vector_type(8))) short short8;
typedef __attribute__((ext_vector_type(4))) float floatx4;
typedef __hip_bfloat16 hb;

__device__ __forceinline__ float sigf(float x){ return 1.0f/(1.0f+expf(-x)); }
__device__ __forceinline__ float siluf(float x){ return x*sigf(x); }
__device__ __forceinline__ void split2(float v, hb* h, hb* l){
  hb hv = __float2bfloat16(v);
  *h = hv; *l = __float2bfloat16(v - __bfloat162float(hv));
}

// ---------- feats NCHW -> NHWC bf16 hi/lo [n][396][1280], one 64x64 tile/block ----------
__global__ __launch_bounds__(256) void k_trans_feats(
    const float* __restrict__ feats, hb* __restrict__ Fh, hb* __restrict__ Fl)
{
  __shared__ float tile[64][65];
  int n = blockIdx.z;
  int p0 = blockIdx.x*64;
  int c0 = blockIdx.y*64;
  int tid = threadIdx.x;
  int tr = tid >> 6;
  int tc = tid & 63;
  #pragma unroll
  for (int it=0; it<16; ++it){
    int ci = c0 + it*4 + tr;
    int p = p0 + tc;
    float v = 0.f;
    if (p < 396) v = feats[((size_t)n*1280 + ci)*396 + p];
    tile[it*4+tr][tc] = v;
  }
  __syncthreads();
  #pragma unroll
  for (int it=0; it<16; ++it){
    int pl = it*4 + tr;
    int p = p0 + pl;
    if (p < 396){
      hb hv, lv; split2(tile[tc][pl], &hv, &lv);
      size_t o = ((size_t)n*396 + p)*1280 + c0 + tc;
      Fh[o] = hv; Fl[o] = lv;
    }
  }
}

// ---------- pack 1x1 weights [256][1280] -> [(kb*16+nb)*64+lane][8] ----------
__global__ __launch_bounds__(256) void k_wpack1(
    const float* __restrict__ W, hb* __restrict__ Wph, hb* __restrict__ Wpl)
{
  int i = blockIdx.x*256 + threadIdx.x;
  if (i >= 40*16*512) return;
  int j = i & 7;
  int lane = (i>>3) & 63;
  int t2 = i >> 9;
  int nb = t2 & 15;
  int kb = t2 >> 4;
  int ci = kb*32 + (lane>>4)*8 + j;
  int co = nb*16 + (lane&15);
  hb hv, lv; split2(W[(size_t)co*1280 + ci], &hv, &lv);
  Wph[i] = hv; Wpl[i] = lv;
}

// ---------- pack 3x3 weights tap-major (image conv) ----------
__global__ __launch_bounds__(256) void k_wpack(
    const float* __restrict__ W, hb* __restrict__ Wph, hb* __restrict__ Wpl, int NB)
{
  int i = blockIdx.x*256 + threadIdx.x;
  int total = 9*8*NB*512;
  if (i >= total) return;
  int j = i & 7;
  int t1 = i >> 3;
  int lane = t1 & 63;
  int t2 = t1 >> 6;
  int nb = t2 % NB;
  int t3 = t2 / NB;
  int kb = t3 & 7;
  int tap = t3 >> 3;
  int ci = kb*32 + (lane>>4)*8 + j;
  int co = nb*16 + (lane&15);
  hb hv, lv; split2(W[(size_t)co*2304 + ci*9 + tap], &hv, &lv);
  Wph[i] = hv; Wpl[i] = lv;
}

// ---------- pack 3x3 weights kb-major (BEV conv) ----------
__global__ __launch_bounds__(256) void k_wpackT(
    const float* __restrict__ W, hb* __restrict__ Wph, hb* __restrict__ Wpl, int NB)
{
  int i = blockIdx.x*256 + threadIdx.x;
  int total = 9*8*NB*512;
  if (i >= total) return;
  int j = i & 7;
  int t1 = i >> 3;
  int lane = t1 & 63;
  int t2 = t1 >> 6;
  int nb = t2 % NB;
  int t3 = t2 / NB;
  int tap = t3 % 9;
  int kb = t3 / 9;
  int ci = kb*32 + (lane>>4)*8 + j;
  int co = nb*16 + (lane&15);
  hb hv, lv; split2(W[(size_t)co*2304 + ci*9 + tap], &hv, &lv);
  Wph[i] = hv; Wpl[i] = lv;
}

// ---------- pack heads weights [kb 0..7][nb 0..6][lane][8]; co<40 dhw, 40..103 chw ----------
__global__ __launch_bounds__(256) void k_wpackH(
    const float* __restrict__ dhw, const float* __restrict__ chw,
    hb* __restrict__ Wph, hb* __restrict__ Wpl)
{
  int i = blockIdx.x*256 + threadIdx.x;
  if (i >= 8*7*512) return;
  int j = i & 7;
  int t1 = i >> 3;
  int lane = t1 & 63;
  int t2 = t1 >> 6;
  int nb = t2 % 7;
  int kb = t2 / 7;
  int ci = kb*32 + (lane>>4)*8 + j;
  int co = nb*16 + (lane&15);
  float w = 0.f;
  if (co < 40) w = dhw[(size_t)co*256 + ci];
  else if (co < 104) w = chw[(size_t)(co-40)*256 + ci];
  hb hv, lv; split2(w, &hv, &lv);
  Wph[i] = hv; Wpl[i] = lv;
}

// ---------- conv1 as MFMA GEMM; BN+SiLU; out NHWC; fused channel-sum atomics ----------
__global__ __launch_bounds__(256) void k_mfma_gemm1(
    const hb* __restrict__ Fh, const hb* __restrict__ Fl,
    const hb* __restrict__ Wph, const hb* __restrict__ Wpl,
    const float* __restrict__ bns, const float* __restrict__ bnb,
    float* __restrict__ out, float* __restrict__ msum)
{
  __shared__ short8 lbh[256], lbl[256];
  int tid = threadIdx.x;
  int wv = tid >> 6, lane = tid & 63;
  int cog = blockIdx.y;
  int Pbase = blockIdx.x*128 + wv*32;
  int m = lane & 15, q = lane >> 4;
  int P0 = Pbase + m;      if (P0 > 4751) P0 = 4751;
  int P1 = Pbase + 16 + m; if (P1 > 4751) P1 = 4751;
  size_t rA0 = (size_t)P0*160 + q;
  size_t rA1 = (size_t)P1*160 + q;
  const short8* gAh = (const short8*)(const void*)Fh;
  const short8* gAl = (const short8*)(const void*)Fl;
  const short8* gWh = (const short8*)(const void*)Wph;
  const short8* gWl = (const short8*)(const void*)Wpl;
  size_t sb = (size_t)(cog*4 + wv)*64 + lane;
  floatx4 acc[2][4];
  #pragma unroll
  for (int i=0;i<2;++i)
    #pragma unroll
    for (int j=0;j<4;++j) acc[i][j] = (floatx4)(0.f);
  short8 ph = gWh[sb], pw = gWl[sb];
  short8 cah0 = gAh[rA0], cal0 = gAl[rA0], cah1 = gAh[rA1], cal1 = gAl[rA1];
  for (int kb=0; kb<40; ++kb){
    __syncthreads();
    lbh[tid] = ph; lbl[tid] = pw;
    int nx = (kb+1 < 40) ? kb+1 : 39;
    ph = gWh[(size_t)nx*1024 + sb]; pw = gWl[(size_t)nx*1024 + sb];
    __syncthreads();
    short8 nah0 = gAh[rA0 + (size_t)nx*4];
    short8 nal0 = gAl[rA0 + (size_t)nx*4];
    short8 nah1 = gAh[rA1 + (size_t)nx*4];
    short8 nal1 = gAl[rA1 + (size_t)nx*4];
    #pragma unroll
    for (int nb=0; nb<4; ++nb){
      short8 bh = lbh[nb*64 + lane];
      short8 bl = lbl[nb*64 + lane];
      acc[0][nb] = __builtin_amdgcn_mfma_f32_16x16x32_bf16(cah0, bh, acc[0][nb], 0,0,0);
      acc[0][nb] = __builtin_amdgcn_mfma_f32_16x16x32_bf16(cah0, bl, acc[0][nb], 0,0,0);
      acc[0][nb] = __builtin_amdgcn_mfma_f32_16x16x32_bf16(cal0, bh, acc[0][nb], 0,0,0);
      acc[1][nb] = __builtin_amdgcn_mfma_f32_16x16x32_bf16(cah1, bh, acc[1][nb], 0,0,0);
      acc[1][nb] = __builtin_amdgcn_mfma_f32_16x16x32_bf16(cah1, bl, acc[1][nb], 0,0,0);
      acc[1][nb] = __builtin_amdgcn_mfma_f32_16x16x32_bf16(cal1, bh, acc[1][nb], 0,0,0);
    }
    cah0 = nah0; cal0 = nal0; cah1 = nah1; cal1 = nal1;
  }
  int n16 = lane & 15;
  #pragma unroll
  for (int mg=0; mg<2; ++mg){
    #pragma unroll
    for (int nb=0; nb<4; ++nb){
      int co = cog*64 + nb*16 + n16;
      float s = bns[co], bv = bnb[co];
      #pragma unroll
      for (int r=0; r<4; ++r){
        int P = Pbase + mg*16 + q*4 + r;
        if (P < 4752){
          float v = siluf(acc[mg][nb][r]*s + bv);
          out[(size_t)P*256 + co] = v;
          atomicAdd(&msum[(P/396)*256 + co], v);
        }
      }
    }
  }
}

// ---------- SE FC (mean scaled by inv) ----------
__global__ __launch_bounds__(256) void k_se_fc(
    const float* __restrict__ mean, const float* __restrict__ w1, const float* __restrict__ b1,
    const float* __restrict__ w2, const float* __restrict__ b2, float* __restrict__ g,
    int H, float inv)
{
  __shared__ float m[256];
  __shared__ float h[32];
  int n = blockIdx.x; int t = threadIdx.x;
  m[t] = mean[n*256 + t] * inv;
  __syncthreads();
  if (t < H){
    float s = b1[t];
    for (int c=0; c<256; ++c) s += m[c]*w1[t*256+c];
    h[t] = siluf(s);
  }
  __syncthreads();
  float s = b2[t];
  for (int j=0; j<H; ++j) s += h[j]*w2[t*H+j];
  g[n*256+t] = sigf(s);
}

// ---------- x1 NHWC * g -> padded [n][14][35][256] bf16 hi/lo ----------
__global__ __launch_bounds__(256) void k_topad(
    const float* __restrict__ x1, const float* __restrict__ g,
    hb* __restrict__ Xh, hb* __restrict__ Xl)
{
  int y = blockIdx.x;
  int n = blockIdx.y;
  int c = threadIdx.x;
  float gc = g[n*256+c];
  for (int xx=0; xx<35; ++xx){
    float v = 0.f;
    if (y>=1 && y<=12 && xx>=1 && xx<=33)
      v = x1[((size_t)n*396 + (y-1)*33 + (xx-1))*256 + c]*gc;
    hb hv, lv; split2(v, &hv, &lv);
    size_t o = (((size_t)n*14+y)*35+xx)*256 + c;
    Xh[o] = hv; Xl[o] = lv;
  }
}

// ---------- image 3x3 conv MFMA; out bf16 hi/lo NHWC [P][256] ----------
__global__ __launch_bounds__(256) void k_conv3s_mfma(
    const hb* __restrict__ Xh, const hb* __restrict__ Xl,
    const hb* __restrict__ Wph, const hb* __restrict__ Wpl,
    const float* __restrict__ bns, const float* __restrict__ bnb,
    hb* __restrict__ outh, hb* __restrict__ outl)
{
  __shared__ short8 lbh[256], lbl[256];
  int tid = threadIdx.x;
  int wv = tid >> 6, lane = tid & 63;
  int cog = blockIdx.y;
  int Pbase = blockIdx.x*128 + wv*32;
  int m = lane & 15, q = lane >> 4;
  int P0 = Pbase + m;      if (P0 > 4751) P0 = 4751;
  int P1 = Pbase + 16 + m; if (P1 > 4751) P1 = 4751;
  int n0 = P0/396, pim0 = P0%396;
  int n1 = P1/396, pim1 = P1%396;
  size_t base0 = (size_t)((n0*14 + pim0/33)*35 + pim0%33)*32 + q;
  size_t base1 = (size_t)((n1*14 + pim1/33)*35 + pim1%33)*32 + q;
  const short8* gAh = (const short8*)(const void*)Xh;
  const short8* gAl = (const short8*)(const void*)Xl;
  const short8* gWh = (const short8*)(const void*)Wph;
  const short8* gWl = (const short8*)(const void*)Wpl;
  size_t sb = (size_t)(cog*4 + wv)*64 + lane;
  floatx4 acc[2][4];
  #pragma unroll
  for (int i=0;i<2;++i)
    #pragma unroll
    for (int j=0;j<4;++j) acc[i][j] = (floatx4)(0.f);
  short8 ph = gWh[sb], pw = gWl[sb];
  short8 cah0 = gAh[base0], cal0 = gAl[base0], cah1 = gAh[base1], cal1 = gAl[base1];
  for (int idx=0; idx<72; ++idx){
    __syncthreads();
    lbh[tid] = ph; lbl[tid] = pw;
    int nx = (idx+1 < 72) ? idx+1 : 71;
    ph = gWh[(size_t)nx*1024 + sb]; pw = gWl[(size_t)nx*1024 + sb];
    __syncthreads();
    int tap = nx >> 3, kb = nx & 7;
    int dy = (tap*11) >> 5;
    int dx = tap - dy*3;
    int ao = (dy*35+dx)*32 + kb*4;
    short8 nah0 = gAh[base0 + ao];
    short8 nal0 = gAl[base0 + ao];
    short8 nah1 = gAh[base1 + ao];
    short8 nal1 = gAl[base1 + ao];
    #pragma unroll
    for (int nb=0; nb<4; ++nb){
      short8 bh = lbh[nb*64 + lane];
      short8 bl = lbl[nb*64 + lane];
      acc[0][nb] = __builtin_amdgcn_mfma_f32_16x16x32_bf16(cah0, bh, acc[0][nb], 0,0,0);
      acc[0][nb] = __builtin_amdgcn_mfma_f32_16x16x32_bf16(cah0, bl, acc[0][nb], 0,0,0);
      acc[0][nb] = __builtin_amdgcn_mfma_f32_16x16x32_bf16(cal0, bh, acc[0][nb], 0,0,0);
      acc[1][nb] = __builtin_amdgcn_mfma_f32_16x16x32_bf16(cah1, bh, acc[1][nb], 0,0,0);
      acc[1][nb] = __builtin_amdgcn_mfma_f32_16x16x32_bf16(cah1, bl, acc[1][nb], 0,0,0);
      acc[1][nb] = __builtin_amdgcn_mfma_f32_16x16x32_bf16(cal1, bh, acc[1][nb], 0,0,0);
    }
    cah0 = nah0; cal0 = nal0; cah1 = nah1; cal1 = nal1;
  }
  int n16 = lane & 15;
  #pragma unroll
  for (int mg=0; mg<2; ++mg){
    #pragma unroll
    for (int r=0; r<4; ++r){
      int P = Pbase + mg*16 + q*4 + r;
      if (P < 4752){
        #pragma unroll
        for (int nb=0; nb<4; ++nb){
          int co = cog*64 + nb*16 + n16;
          float v = siluf(acc[mg][nb][r]*bns[co] + bnb[co]);
          hb hv, lv; split2(v, &hv, &lv);
          outh[(size_t)P*256 + co] = hv;
          outl[(size_t)P*256 + co] = lv;
        }
      }
    }
  }
}

// ---------- heads as MFMA GEMM: M=4752, N=112(pad of 104), K=256 ----------
// grid (38, 2): cog 0 -> nb 0..3 (co 0..63), cog 1 -> nb 0..2 (co 64..111)
__global__ __launch_bounds__(256) void k_headsM(
    const hb* __restrict__ x2h, const hb* __restrict__ x2l,
    const hb* __restrict__ Whh, const hb* __restrict__ Whl,
    const float* __restrict__ dhb, const float* __restrict__ chb,
    float* __restrict__ dep, float* __restrict__ ctx2)
{
  __shared__ short8 lbh[256], lbl[256];
  int tid = threadIdx.x;
  int wv = tid >> 6, lane = tid & 63;
  int cog = blockIdx.y;
  int nb0 = cog*4;
  int nbN = cog ? 3 : 4;
  int Pbase = blockIdx.x*128 + wv*32;
  int m = lane & 15, q = lane >> 4;
  int P0 = Pbase + m;      if (P0 > 4751) P0 = 4751;
  int P1 = Pbase + 16 + m; if (P1 > 4751) P1 = 4751;
  size_t rA0 = (size_t)P0*32 + q;
  size_t rA1 = (size_t)P1*32 + q;
  const short8* gAh = (const short8*)(const void*)x2h;
  const short8* gAl = (const short8*)(const void*)x2l;
  const short8* gWh = (const short8*)(const void*)Whh;
  const short8* gWl = (const short8*)(const void*)Whl;
  floatx4 acc[2][4];
  #pragma unroll
  for (int i=0;i<2;++i)
    #pragma unroll
    for (int j=0;j<4;++j) acc[i][j] = (floatx4)(0.f);
  for (int kb=0; kb<8; ++kb){
    __syncthreads();
    for (int i=tid; i<nbN*64; i+=256){
      lbh[i] = gWh[(size_t)(kb*7 + nb0)*64 + i];
      lbl[i] = gWl[(size_t)(kb*7 + nb0)*64 + i];
    }
    __syncthreads();
    short8 ah0 = gAh[rA0 + kb*4], al0 = gAl[rA0 + kb*4];
    short8 ah1 = gAh[rA1 + kb*4], al1 = gAl[rA1 + kb*4];
    for (int nb=0; nb<nbN; ++nb){
      short8 bh = lbh[nb*64 + lane];
      short8 bl = lbl[nb*64 + lane];
      acc[0][nb] = __builtin_amdgcn_mfma_f32_16x16x32_bf16(ah0, bh, acc[0][nb], 0,0,0);
      acc[0][nb] = __builtin_amdgcn_mfma_f32_16x16x32_bf16(ah0, bl, acc[0][nb], 0,0,0);
      acc[0][nb] = __builtin_amdgcn_mfma_f32_16x16x32_bf16(al0, bh, acc[0][nb], 0,0,0);
      acc[1][nb] = __builtin_amdgcn_mfma_f32_16x16x32_bf16(ah1, bh, acc[1][nb], 0,0,0);
      acc[1][nb] = __builtin_amdgcn_mfma_f32_16x16x32_bf16(ah1, bl, acc[1][nb], 0,0,0);
      acc[1][nb] = __builtin_amdgcn_mfma_f32_16x16x32_bf16(al1, bh, acc[1][nb], 0,0,0);
    }
  }
  int n16 = lane & 15;
  #pragma unroll
  for (int mg=0; mg<2; ++mg){
    #pragma unroll
    for (int r=0; r<4; ++r){
      int P = Pbase + mg*16 + q*4 + r;
      if (P < 4752){
        int nn = P/396, pim = P%396;
        for (int nb=0; nb<nbN; ++nb){
          int co = cog*64 + nb*16 + n16;
          float v = acc[mg][nb][r];
          if (co < 40)
            dep[((size_t)nn*40 + co)*396 + pim] = v + dhb[co];
          else if (co < 104)
            ctx2[((size_t)nn*396 + pim)*64 + (co-40)] = v + chb[co-40];
        }
      }
    }
  }
}

// ---------- softmax over 40 depth channels ----------
__global__ __launch_bounds__(256) void k_softmax40(float* __restrict__ dep)
{
  int i = blockIdx.x*256 + threadIdx.x;
  if (i >= 12*396) return;
  int n = i/396, p = i%396;
  float* base = dep + (size_t)n*40*396 + p;
  float mx = -1e30f;
  for (int d=0; d<40; ++d) mx = fmaxf(mx, base[(size_t)d*396]);
  float s = 0.f;
  for (int d=0; d<40; ++d){ float e = expf(base[(size_t)d*396]-mx); base[(size_t)d*396]=e; s+=e; }
  float inv = 1.f/s;
  for (int d=0; d<40; ++d) base[(size_t)d*396] *= inv;
}

// ---------- geometry + count (fused) ----------
__global__ __launch_bounds__(256) void k_geom(
    const float* __restrict__ rots, const float* __restrict__ trans,
    const float* __restrict__ intr, int* __restrict__ vox, int* __restrict__ cnt)
{
  int pt = blockIdx.x*256 + threadIdx.x;
  if (pt >= 190080) return;
  int b = pt/95040; int r = pt%95040;
  int n = r/15840;  int r2 = r%15840;
  int d = r2/396;   int pim = r2%396;
  int y = pim/33, x = pim%33;
  int bn = b*6+n;
  const float* R = rots + (size_t)bn*9;
  const float* T = trans + (size_t)bn*3;
  const float* K = intr + (size_t)bn*9;
  float fx=K[0], cx=K[2], fy=K[4], cy=K[5];
  float xs = (float)x * 32.96875f;
  float ys = (float)((double)y * (383.0/11.0));
  float dv = 4.0f + (float)d;
  float camx = (xs-cx)*dv/fx;
  float camy = (ys-cy)*dv/fy;
  float gx = R[0]*camx + R[1]*camy + R[2]*dv + T[0];
  float gy = R[3]*camx + R[4]*camy + R[5]*dv + T[1];
  float gz = R[6]*camx + R[7]*camy + R[8]*dv + T[2];
  int ix = (int)floorf(gx + 50.f);
  int iy = (int)floorf(gy + 50.f);
  int iz = (int)floorf((gz + 10.f)/5.f);
  bool valid = (ix>=0 && ix<100 && iy>=0 && iy<100 && iz>=0 && iz<4);
  int sid = iz*10000 + ix*100 + iy;
  vox[pt] = valid ? sid : -1;
  if (valid) atomicAdd(&cnt[b*40000 + sid], 1);
}

// ---------- scan ----------
__global__ __launch_bounds__(256) void k_scan1(
    const int* __restrict__ cnt, int* __restrict__ off, int* __restrict__ bsum)
{
  __shared__ int s[256];
  int t = threadIdx.x;
  int i = blockIdx.x*256 + t;
  int v = (i < 80000) ? cnt[i] : 0;
  s[t] = v; __syncthreads();
  for (int o=1;o<256;o<<=1){
    int x = (t>=o) ? s[t-o] : 0;
    __syncthreads();
    s[t] += x;
    __syncthreads();
  }
  if (i < 80000) off[i] = s[t] - v;
  if (t == 255) bsum[blockIdx.x] = s[255];
}

__global__ void k_scan2(int* __restrict__ bsum, int nblk)
{
  if (threadIdx.x==0 && blockIdx.x==0){
    int run = 0;
    for (int j=0;j<nblk;++j){ int t = bsum[j]; bsum[j] = run; run += t; }
  }
}

__global__ __launch_bounds__(256) void k_scan3(
    int* __restrict__ off, const int* __restrict__ bsum, int* __restrict__ cur)
{
  int i = blockIdx.x*256 + threadIdx.x;
  if (i >= 80000) return;
  int o = off[i] + bsum[i>>8];
  off[i] = o;
  cur[i] = o;
}

__global__ __launch_bounds__(256) void k_fill(
    const int* __restrict__ vox, int* __restrict__ cur, int* __restrict__ list)
{
  int pt = blockIdx.x*256 + threadIdx.x;
  if (pt >= 190080) return;
  int s = vox[pt];
  if (s < 0) return;
  int b = pt/95040;
  int slot = atomicAdd(&cur[b*40000 + s], 1);
  list[slot] = pt;
}

// ---------- gather: one wave per (b,sid), lane=channel ----------
__global__ __launch_bounds__(256) void k_gather(
    const int* __restrict__ off, const int* __restrict__ cnt, const int* __restrict__ list,
    const float* __restrict__ ctx2, const float* __restrict__ dep, float* __restrict__ bev)
{
  int tid = threadIdx.x;
  int bv = blockIdx.x*4 + (tid>>6);
  int c = tid & 63;
  int b = bv/40000, sid = bv%40000;
  int st = off[bv], nn = cnt[bv];
  float s = 0.f;
  for (int k=0;k<nn;++k){
    int pt = list[st+k];
    int r = pt%95040;
    int bn = b*6 + r/15840;
    int r2 = r%15840;
    int dd = r2/396, pim = r2%396;
    s += ctx2[((size_t)bn*396+pim)*64 + c] * dep[((size_t)bn*40+dd)*396 + pim];
  }
  int iz = sid/10000, rem = sid%10000;
  bev[(size_t)b*2560000 + (size_t)iz*640000 + (size_t)c*10000 + rem] = s;
}

// ---------- NCHW fp32 (*g) -> padded NHWC bf16 hi/lo, coalesced LDS transpose ----------
__global__ __launch_bounds__(256) void k_tohwc2(
    const float* __restrict__ in, hb* __restrict__ Ah, hb* __restrict__ Al,
    const float* __restrict__ g)
{
  __shared__ float tile[32*105];
  int py = blockIdx.x;
  int b  = blockIdx.y;
  int cg = blockIdx.z;
  int tid = threadIdx.x;
  bool inner = (py >= 1 && py <= 100);
  if (inner){
    if (tid < 64){ int cil = tid & 31; int col = (tid>>5) ? 101 : 0; tile[cil*105 + col] = 0.f; }
    for (int i = tid; i < 3200; i += 256){
      int cil = i / 100, x = i % 100;
      int ci = cg*32 + cil;
      tile[cil*105 + (x+1)] = in[(((size_t)b*256 + ci)*100 + (py-1))*100 + x];
    }
  }
  __syncthreads();
  for (int i = tid; i < 32*102; i += 256){
    int px = i >> 5, cil = i & 31;
    int ci = cg*32 + cil;
    float v = 0.f;
    if (inner){
      v = tile[cil*105 + px];
      if (g) v *= g[b*256 + ci];
    }
    hb hv, lv; split2(v, &hv, &lv);
    size_t o = (((size_t)b*102 + py)*102 + px)*256 + ci;
    Ah[o] = hv; Al[o] = lv;
  }
}

// ---------- row mean (NCHW rows) ----------
__global__ __launch_bounds__(256) void k_rowmean(
    const float* __restrict__ in, float* __restrict__ out, int rowlen, float inv)
{
  __shared__ float ws[4];
  int row = blockIdx.x; int t = threadIdx.x;
  const float* p = in + (size_t)row*rowlen;
  float s = 0.f;
  for (int i=t; i<rowlen; i+=256) s += p[i];
  #pragma unroll
  for (int off=32; off; off>>=1) s += __shfl_down(s, off);
  if ((t&63)==0) ws[t>>6] = s;
  __syncthreads();
  if (t==0) out[row] = (ws[0]+ws[1]+ws[2]+ws[3]) * inv;
}

// ---------- BEV MFMA conv, LDS A-staging, B double-buffer (1 barrier/tap) ----------
__global__ __launch_bounds__(256) void k_conv3_bevm(
    const hb* __restrict__ Ah, const hb* __restrict__ Al,
    const hb* __restrict__ Wph, const hb* __restrict__ Wpl,
    const float* __restrict__ bns, const float* __restrict__ bnb,
    const float* __restrict__ res, float* __restrict__ out, int Cout, int NBG)
{
  __shared__ __align__(16) short sAh[10*18*44];   // pad 44: 16 distinct banks per m
  __shared__ __align__(16) short sAl[10*18*44];
  __shared__ short8 lbh[2][256], lbl[2][256];
  const int NB = Cout >> 4;
  int tid = threadIdx.x;
  int wv = tid >> 6, lane = tid & 63;
  int L = blockIdx.x;
  int spatial = L / (NBG*2);
  int rem = L % (NBG*2);
  int cog = rem % NBG;
  int bb  = rem / NBG;
  int xg = spatial % 7, yg = spatial / 7;
  int x0 = xg*16;
  int y0 = yg*8 + wv;
  int m = lane & 15, q = lane >> 4;
  int nb0 = cog*4;
  floatx4 acc[2][4];
  #pragma unroll
  for (int i=0;i<2;++i)
    #pragma unroll
    for (int j=0;j<4;++j) acc[i][j] = (floatx4)(0.f);

  const short8* gAh = (const short8*)(const void*)Ah;
  const short8* gAl = (const short8*)(const void*)Al;
  const short8* gWh = (const short8*)(const void*)Wph;
  const short8* gWl = (const short8*)(const void*)Wpl;
  const size_t nbstride = (size_t)NB*64;
  const size_t sb = (size_t)(nb0 + wv)*64 + lane;

  short8 ph = gWh[sb], pl = gWl[sb];
  int cur = 0;

  for (int kb=0; kb<8; ++kb){
    #pragma unroll 3
    for (int tap=0; tap<9; ++tap){
      int idx2 = kb*9 + tap;
      if (tap == 0){
        __syncthreads();               // prior kb's sA reads + lb[cur^1] reads done
        for (int i = tid; i < 720; i += 256){
          int rc = i >> 2, part = i & 3;
          int r = rc / 18, c = rc % 18;
          int yr = yg*8 + r; if (yr > 101) yr = 101;
          int xc = x0 + c;   if (xc > 101) xc = 101;
          size_t so = ((size_t)((bb*102 + yr)*102 + xc))*32 + kb*4 + part;
          short8 vh = gAh[so], vl = gAl[so];
          int dst = (r*18 + c)*44 + part*8;
          *(short8*)(sAh + dst) = vh;
          *(short8*)(sAl + dst) = vl;
        }
      }
      lbh[cur][tid] = ph; lbl[cur][tid] = pl;
      int nx = (idx2+1 < 72) ? idx2+1 : 71;
      ph = gWh[(size_t)nx*nbstride + sb];
      pl = gWl[(size_t)nx*nbstride + sb];
      __syncthreads();                 // sA (if staged) + lb[cur] visible
      int dy = (tap*11) >> 5;
      int dx = tap - dy*3;
      int cc = dx + m;
      int a0 = ((wv + dy)*18 + cc)*44 + q*8;
      int a1 = ((wv + 4 + dy)*18 + cc)*44 + q*8;
      short8 cah0 = *(const short8*)(sAh + a0);
      short8 cal0 = *(const short8*)(sAl + a0);
      short8 cah1 = *(const short8*)(sAh + a1);
      short8 cal1 = *(const short8*)(sAl + a1);
      #pragma unroll
      for (int nb=0; nb<4; ++nb){
        short8 bh = lbh[cur][nb*64 + lane];
        short8 bl = lbl[cur][nb*64 + lane];
        acc[0][nb] = __builtin_amdgcn_mfma_f32_16x16x32_bf16(cah0, bh, acc[0][nb], 0,0,0);
        acc[0][nb] = __builtin_amdgcn_mfma_f32_16x16x32_bf16(cah0, bl, acc[0][nb], 0,0,0);
        acc[0][nb] = __builtin_amdgcn_mfma_f32_16x16x32_bf16(cal0, bh, acc[0][nb], 0,0,0);
        acc[1][nb] = __builtin_amdgcn_mfma_f32_16x16x32_bf16(cah1, bh, acc[1][nb], 0,0,0);
        acc[1][nb] = __builtin_amdgcn_mfma_f32_16x16x32_bf16(cah1, bl, acc[1][nb], 0,0,0);
        acc[1][nb] = __builtin_amdgcn_mfma_f32_16x16x32_bf16(cal1, bh, acc[1][nb], 0,0,0);
      }
      cur ^= 1;
    }
  }

  int n = lane & 15;
  int xq = x0 + q*4;
  #pragma unroll
  for (int mg=0; mg<2; ++mg){
    int yo = y0 + mg*4;
    if (yo < 100 && xq < 100){
      #pragma unroll
      for (int nb=0; nb<4; ++nb){
        int co = cog*64 + nb*16 + n;
        float s = bns[co], bv = bnb[co];
        floatx4 a = acc[mg][nb];
        float4 v;
        v.x = fmaxf(a[0]*s+bv, 0.f);
        v.y = fmaxf(a[1]*s+bv, 0.f);
        v.z = fmaxf(a[2]*s+bv, 0.f);
        v.w = fmaxf(a[3]*s+bv, 0.f);
        size_t o = ((size_t)(bb*Cout+co)*100 + yo)*100 + xq;
        if (res){
          float4 rv = *(const float4*)(res + o);
          v.x += rv.x; v.y += rv.y; v.z += rv.z; v.w += rv.w;
        }
        *(float4*)(out + o) = v;
      }
    }
  }
}

// ---------- final 1x1 conv 128->16, one pass over h3 ----------
__global__ __launch_bounds__(256) void k_final2(
    const float* __restrict__ h, const float* __restrict__ W, const float* __restrict__ bias,
    float* __restrict__ out)
{
  __shared__ float wsl[2048];
  __shared__ float bs[16];
  int tid = threadIdx.x;
  int b = blockIdx.y;
  for (int i=tid; i<2048; i+=256) wsl[i] = W[i];
  if (tid < 16) bs[tid] = bias[tid];
  __syncthreads();
  int pix = blockIdx.x*256 + tid;
  if (pix >= 10000) return;
  float acc[16];
  #pragma unroll
  for (int oc=0; oc<16; ++oc) acc[oc] = bs[oc];
  const float* hb_ = h + (size_t)b*128*10000 + pix;
  for (int ci=0; ci<128; ++ci){
    float hv = hb_[(size_t)ci*10000];
    #pragma unroll
    for (int oc=0; oc<16; ++oc) acc[oc] += hv * wsl[oc*128 + ci];
  }
  #pragma unroll
  for (int oc=0; oc<16; ++oc)
    out[((size_t)(b*16+oc))*10000 + pix] = acc[oc];
}

extern "C" void kernel_launch(void* const* d_in, const int* in_sizes, int n_in,
                              void* d_out, int out_size, void* d_ws, size_t ws_size,
                              hipStream_t stream)
{
  (void)in_sizes; (void)n_in; (void)out_size; (void)ws_size;
  const float* feats = (const float*)d_in[0];
  const float* rots  = (const float*)d_in[1];
  const float* trans = (const float*)d_in[2];
  const float* intr  = (const float*)d_in[3];
  const float* nw1   = (const float*)d_in[4];
  const float* bn1s  = (const float*)d_in[5];
  const float* bn1b  = (const float*)d_in[6];
  const float* se1w1 = (const float*)d_in[7];
  const float* se1b1 = (const float*)d_in[8];
  const float* se1w2 = (const float*)d_in[9];
  const float* se1b2 = (const float*)d_in[10];
  const float* nw2   = (const float*)d_in[11];
  const float* bn2s  = (const float*)d_in[12];
  const float* bn2b  = (const float*)d_in[13];
  const float* dhw   = (const float*)d_in[14];
  const float* dhb   = (const float*)d_in[15];
  const float* chw   = (const float*)d_in[16];
  const float* chb   = (const float*)d_in[17];
  const float* bcw1  = (const float*)d_in[18];
  const float* bcs1  = (const float*)d_in[19];
  const float* bcb1  = (const float*)d_in[20];
  const float* bcsw1 = (const float*)d_in[21];
  const float* bcsb1 = (const float*)d_in[22];
  const float* bcsw2 = (const float*)d_in[23];
  const float* bcsb2 = (const float*)d_in[24];
  const float* bcw2  = (const float*)d_in[25];
  const float* bcs2  = (const float*)d_in[26];
  const float* bcb2  = (const float*)d_in[27];
  const float* dw1   = (const float*)d_in[28];
  const float* ds1   = (const float*)d_in[29];
  const float* db1   = (const float*)d_in[30];
  const float* dw2   = (const float*)d_in[31];
  const float* db2   = (const float*)d_in[32];
  float* out = (float*)d_out;

  // ---- workspace layout (float units) ----
  float* ws = (float*)d_ws;
  float* bev   = ws;                       // S0: 5,120,000
  float* h1    = ws + 5120000;             // S1: 5,120,000
  hb*    Ah    = (hb*)(ws + 10240000);     // S2: 2,663,424 fu
  hb*    Al    = (hb*)(ws + 12903424);     // S3: 2,663,424 fu
  float* x2    = ws + 15566848;            // S4: 1,216,512
  float* S5    = ws + 16783360;            // 589,824
  float* dep   = ws + 17373184;            // 190,080
  float* ctx2  = ws + 17563264;            // 304,128
  float* mean1 = ws + 17867392;            // 3072
  float* g1    = mean1 + 3072;
  float* mean2 = g1 + 3072;
  float* g2    = mean2 + 512;
  int*   vox   = (int*)(ws + 17875584);    // 190,080 ints
  // phase aliases
  hb* Fh   = (hb*)bev;                     // 3,041,280 fu
  hb* Wc1h = (hb*)(bev + 3041280);         // 163,840 fu
  hb* Wc1l = (hb*)(bev + 3205120);         // 163,840 fu
  float* x1 = h1;                          // NHWC conv1 out
  hb* Fl   = (hb*)(h1 + 1216512);          // 3,041,280 fu
  hb* Xh   = (hb*)Ah;
  hb* Xl   = (hb*)Al;
  hb* Wc2h = (hb*)S5;                      // 294,912 fu
  hb* Wc2l = (hb*)(S5 + 294912);           // 294,912 fu
  hb* x2h  = (hb*)x2;                      // 608,256 fu (bf16 NHWC hi)
  hb* x2l  = (hb*)(x2 + 608256);           // 608,256 fu
  hb* Whh  = (hb*)S5;                      // heads weights (after conv3s; Wc2 dead)
  hb* Whl  = (hb*)(S5 + 14336);            // 28,672 bf16 each
  int* cnt  = (int*)h1;
  int* off  = cnt + 80000;
  int* cur  = off + 80000;
  int* bsum = cur + 80000;
  int* list = bsum + 1024;
  float* h3 = h1;
  hb* Wp1h = (hb*)x2;                      // BEV conv weights (x2h/l dead after headsM)
  hb* Wp1l = (hb*)(x2 + 294912);
  hb* Wp3h = (hb*)(x2 + 589824);
  hb* Wp3l = (hb*)(x2 + 589824 + 147456);
  hb* Wp2h = (hb*)S5;                      // Wh dead after headsM
  hb* Wp2l = (hb*)(S5 + 294912);

  // ---- image branch (MFMA) ----
  hipMemsetAsync(mean1, 0, 3072*sizeof(float), stream);
  k_trans_feats<<<dim3(7,20,12),256,0,stream>>>(feats,Fh,Fl);
  k_wpack1<<<1280,256,0,stream>>>(nw1,Wc1h,Wc1l);
  k_mfma_gemm1<<<dim3(38,4),256,0,stream>>>(Fh,Fl,Wc1h,Wc1l,bn1s,bn1b,x1,mean1);
  k_se_fc<<<12,256,0,stream>>>(mean1,se1w1,se1b1,se1w2,se1b2,g1,32,1.f/396.f);
  k_topad<<<dim3(14,12),256,0,stream>>>(x1,g1,Xh,Xl);
  k_wpack<<<2304,256,0,stream>>>(nw2,Wc2h,Wc2l,16);
  k_conv3s_mfma<<<dim3(38,4),256,0,stream>>>(Xh,Xl,Wc2h,Wc2l,bn2s,bn2b,x2h,x2l);
  k_wpackH<<<112,256,0,stream>>>(dhw,chw,Whh,Whl);
  k_headsM<<<dim3(38,2),256,0,stream>>>(x2h,x2l,Whh,Whl,dhb,chb,dep,ctx2);
  k_softmax40<<<19,256,0,stream>>>(dep);

  // ---- pack BEV conv weights kb-major (x2h/l, Wh dead now) ----
  k_wpackT<<<2304,256,0,stream>>>(bcw1,Wp1h,Wp1l,16);
  k_wpackT<<<2304,256,0,stream>>>(bcw2,Wp2h,Wp2l,16);
  k_wpackT<<<1152,256,0,stream>>>(dw1,Wp3h,Wp3l,8);

  // ---- lift-splat (gather form) ----
  hipMemsetAsync(cnt, 0, 80000*sizeof(int), stream);
  k_geom<<<(190080+255)/256,256,0,stream>>>(rots,trans,intr,vox,cnt);
  k_scan1<<<313,256,0,stream>>>(cnt,off,bsum);
  k_scan2<<<1,64,0,stream>>>(bsum,313);
  k_scan3<<<(80000+255)/256,256,0,stream>>>(off,bsum,cur);
  k_fill<<<(190080+255)/256,256,0,stream>>>(vox,cur,list);
  k_gather<<<20000,256,0,stream>>>(off,cnt,list,ctx2,dep,bev);

  // ---- BEV encoder (MFMA convs, LDS-staged, B-dbuf) ----
  k_tohwc2<<<dim3(102,2,8),256,0,stream>>>(bev,Ah,Al,nullptr);
  k_conv3_bevm<<<728,256,0,stream>>>(Ah,Al,Wp1h,Wp1l,bcs1,bcb1,nullptr,h1,256,4);
  k_rowmean<<<512,256,0,stream>>>(h1,mean2,10000,1e-4f);
  k_se_fc<<<2,256,0,stream>>>(mean2,bcsw1,bcsb1,bcsw2,bcsb2,g2,16,1.f);
  k_tohwc2<<<dim3(102,2,8),256,0,stream>>>(h1,Ah,Al,g2);
  k_conv3_bevm<<<728,256,0,stream>>>(Ah,Al,Wp2h,Wp2l,bcs2,bcb2,bev,bev,256,4);
  k_tohwc2<<<dim3(102,2,8),256,0,stream>>>(bev,Ah,Al,nullptr);
  k_conv3_bevm<<<364,256,0,stream>>>(Ah,Al,Wp3h,Wp3l,ds1,db1,nullptr,h3,128,2);
  k_final2<<<dim3(40,2),256,0,stream>>>(h3,dw2,db2,out);
}

// Round 10
// 686.971 us; speedup vs baseline: 1.0443x; 1.0443x over previous
//
#include <hip/hip_runtime.h>
#include <hip/hip_bf16.h>
#include <cmath>

// LSS pipeline R10: revert gemm1 atomic-mean (3072-address contention);
// feats packed directly in MFMA A-frag order (coalesced gemm1 A-loads).

typedef __attribute__((ext_vector_type(8))) short short8;
typedef __attribute__((ext_vector_type(4))) float floatx4;
typedef __hip_bfloat16 hb;

__device__ __forceinline__ float sigf(float x){ return 1.0f/(1.0f+expf(-x)); }
__device__ __forceinline__ float siluf(float x){ return x*sigf(x); }
__device__ __forceinline__ void split2(float v, hb* h, hb* l){
  hb hv = __float2bfloat16(v);
  *h = hv; *l = __float2bfloat16(v - __bfloat162float(hv));
}

// ---------- feats NCHW -> A-frag-packed bf16 hi/lo Fp[(T*40+kb)*64+lane][8] ----------
// T = P/16 (P = n*396+p, 4752 = 297 tiles exact), lane = q*16 + (P%16), ci = kb*32+q*8+j
__global__ __launch_bounds__(256) void k_trans_featsP(
    const float* __restrict__ feats, hb* __restrict__ Fph, hb* __restrict__ Fpl)
{
  __shared__ float tile[64][65];
  int n = blockIdx.z;
  int p0 = blockIdx.x*64;
  int c0 = blockIdx.y*64;
  int tid = threadIdx.x;
  int tr = tid >> 6;
  int tc = tid & 63;
  #pragma unroll
  for (int it=0; it<16; ++it){
    int ci = c0 + it*4 + tr;
    int p = p0 + tc;
    float v = 0.f;
    if (p < 396) v = feats[((size_t)n*1280 + ci)*396 + p];
    tile[it*4+tr][tc] = v;   // [ci_local][p_local]
  }
  __syncthreads();
  #pragma unroll
  for (int iter=0; iter<2; ++iter){
    int idx = iter*256 + tid;
    int oc = idx >> 6;       // ci-oct 0..7
    int pl = idx & 63;       // pixel local
    int p = p0 + pl;
    if (p < 396){
      int P = n*396 + p;
      int T = P >> 4, mm = P & 15;
      int kb = (c0 >> 5) + (oc >> 2);
      int q = oc & 3;
      int lane = q*16 + mm;
      size_t o = (((size_t)T*40 + kb)*64 + lane)*8;
      #pragma unroll
      for (int j=0; j<8; ++j){
        hb hv, lv; split2(tile[oc*8+j][pl], &hv, &lv);
        Fph[o+j] = hv; Fpl[o+j] = lv;
      }
    }
  }
}

// ---------- pack 1x1 weights [256][1280] -> [(kb*16+nb)*64+lane][8] ----------
__global__ __launch_bounds__(256) void k_wpack1(
    const float* __restrict__ W, hb* __restrict__ Wph, hb* __restrict__ Wpl)
{
  int i = blockIdx.x*256 + threadIdx.x;
  if (i >= 40*16*512) return;
  int j = i & 7;
  int lane = (i>>3) & 63;
  int t2 = i >> 9;
  int nb = t2 & 15;
  int kb = t2 >> 4;
  int ci = kb*32 + (lane>>4)*8 + j;
  int co = nb*16 + (lane&15);
  hb hv, lv; split2(W[(size_t)co*1280 + ci], &hv, &lv);
  Wph[i] = hv; Wpl[i] = lv;
}

// ---------- pack 3x3 weights tap-major (image conv) ----------
__global__ __launch_bounds__(256) void k_wpack(
    const float* __restrict__ W, hb* __restrict__ Wph, hb* __restrict__ Wpl, int NB)
{
  int i = blockIdx.x*256 + threadIdx.x;
  int total = 9*8*NB*512;
  if (i >= total) return;
  int j = i & 7;
  int t1 = i >> 3;
  int lane = t1 & 63;
  int t2 = t1 >> 6;
  int nb = t2 % NB;
  int t3 = t2 / NB;
  int kb = t3 & 7;
  int tap = t3 >> 3;
  int ci = kb*32 + (lane>>4)*8 + j;
  int co = nb*16 + (lane&15);
  hb hv, lv; split2(W[(size_t)co*2304 + ci*9 + tap], &hv, &lv);
  Wph[i] = hv; Wpl[i] = lv;
}

// ---------- pack 3x3 weights kb-major (BEV conv) ----------
__global__ __launch_bounds__(256) void k_wpackT(
    const float* __restrict__ W, hb* __restrict__ Wph, hb* __restrict__ Wpl, int NB)
{
  int i = blockIdx.x*256 + threadIdx.x;
  int total = 9*8*NB*512;
  if (i >= total) return;
  int j = i & 7;
  int t1 = i >> 3;
  int lane = t1 & 63;
  int t2 = t1 >> 6;
  int nb = t2 % NB;
  int t3 = t2 / NB;
  int tap = t3 % 9;
  int kb = t3 / 9;
  int ci = kb*32 + (lane>>4)*8 + j;
  int co = nb*16 + (lane&15);
  hb hv, lv; split2(W[(size_t)co*2304 + ci*9 + tap], &hv, &lv);
  Wph[i] = hv; Wpl[i] = lv;
}

// ---------- pack heads weights ----------
__global__ __launch_bounds__(256) void k_wpackH(
    const float* __restrict__ dhw, const float* __restrict__ chw,
    hb* __restrict__ Wph, hb* __restrict__ Wpl)
{
  int i = blockIdx.x*256 + threadIdx.x;
  if (i >= 8*7*512) return;
  int j = i & 7;
  int t1 = i >> 3;
  int lane = t1 & 63;
  int t2 = t1 >> 6;
  int nb = t2 % 7;
  int kb = t2 / 7;
  int ci = kb*32 + (lane>>4)*8 + j;
  int co = nb*16 + (lane&15);
  float w = 0.f;
  if (co < 40) w = dhw[(size_t)co*256 + ci];
  else if (co < 104) w = chw[(size_t)(co-40)*256 + ci];
  hb hv, lv; split2(w, &hv, &lv);
  Wph[i] = hv; Wpl[i] = lv;
}

// ---------- conv1 as MFMA GEMM on frag-packed A; BN+SiLU; out NHWC ----------
__global__ __launch_bounds__(256) void k_mfma_gemm1(
    const hb* __restrict__ Fph, const hb* __restrict__ Fpl,
    const hb* __restrict__ Wph, const hb* __restrict__ Wpl,
    const float* __restrict__ bns, const float* __restrict__ bnb,
    float* __restrict__ out)
{
  __shared__ short8 lbh[256], lbl[256];
  int tid = threadIdx.x;
  int wv = tid >> 6, lane = tid & 63;
  int cog = blockIdx.y;
  int Pbase = blockIdx.x*128 + wv*32;
  int q = lane >> 4;
  int T0 = blockIdx.x*8 + wv*2; if (T0 > 296) T0 = 296;
  int T1 = T0 + 1;              if (T1 > 296) T1 = 296;
  size_t a0 = (size_t)T0*2560 + lane;   // short8 units; +kb*64 per step
  size_t a1 = (size_t)T1*2560 + lane;
  const short8* gAh = (const short8*)(const void*)Fph;
  const short8* gAl = (const short8*)(const void*)Fpl;
  const short8* gWh = (const short8*)(const void*)Wph;
  const short8* gWl = (const short8*)(const void*)Wpl;
  size_t sb = (size_t)(cog*4 + wv)*64 + lane;
  floatx4 acc[2][4];
  #pragma unroll
  for (int i=0;i<2;++i)
    #pragma unroll
    for (int j=0;j<4;++j) acc[i][j] = (floatx4)(0.f);
  short8 ph = gWh[sb], pw = gWl[sb];
  short8 cah0 = gAh[a0], cal0 = gAl[a0], cah1 = gAh[a1], cal1 = gAl[a1];
  for (int kb=0; kb<40; ++kb){
    __syncthreads();
    lbh[tid] = ph; lbl[tid] = pw;
    int nx = (kb+1 < 40) ? kb+1 : 39;
    ph = gWh[(size_t)nx*1024 + sb]; pw = gWl[(size_t)nx*1024 + sb];
    __syncthreads();
    short8 nah0 = gAh[a0 + (size_t)nx*64];
    short8 nal0 = gAl[a0 + (size_t)nx*64];
    short8 nah1 = gAh[a1 + (size_t)nx*64];
    short8 nal1 = gAl[a1 + (size_t)nx*64];
    #pragma unroll
    for (int nb=0; nb<4; ++nb){
      short8 bh = lbh[nb*64 + lane];
      short8 bl = lbl[nb*64 + lane];
      acc[0][nb] = __builtin_amdgcn_mfma_f32_16x16x32_bf16(cah0, bh, acc[0][nb], 0,0,0);
      acc[0][nb] = __builtin_amdgcn_mfma_f32_16x16x32_bf16(cah0, bl, acc[0][nb], 0,0,0);
      acc[0][nb] = __builtin_amdgcn_mfma_f32_16x16x32_bf16(cal0, bh, acc[0][nb], 0,0,0);
      acc[1][nb] = __builtin_amdgcn_mfma_f32_16x16x32_bf16(cah1, bh, acc[1][nb], 0,0,0);
      acc[1][nb] = __builtin_amdgcn_mfma_f32_16x16x32_bf16(cah1, bl, acc[1][nb], 0,0,0);
      acc[1][nb] = __builtin_amdgcn_mfma_f32_16x16x32_bf16(cal1, bh, acc[1][nb], 0,0,0);
    }
    cah0 = nah0; cal0 = nal0; cah1 = nah1; cal1 = nal1;
  }
  int n16 = lane & 15;
  #pragma unroll
  for (int mg=0; mg<2; ++mg){
    #pragma unroll
    for (int nb=0; nb<4; ++nb){
      int co = cog*64 + nb*16 + n16;
      float s = bns[co], bv = bnb[co];
      #pragma unroll
      for (int r=0; r<4; ++r){
        int P = Pbase + mg*16 + q*4 + r;
        if (P < 4752) out[(size_t)P*256 + co] = siluf(acc[mg][nb][r]*s + bv);
      }
    }
  }
}

// ---------- NHWC mean over 396 pixels ----------
__global__ __launch_bounds__(256) void k_meanN(
    const float* __restrict__ x1, float* __restrict__ mean)
{
  int n = blockIdx.x; int c = threadIdx.x;
  float s = 0.f;
  for (int p=0; p<396; ++p) s += x1[((size_t)n*396+p)*256 + c];
  mean[n*256+c] = s*(1.f/396.f);
}

// ---------- SE FC ----------
__global__ __launch_bounds__(256) void k_se_fc(
    const float* __restrict__ mean, const float* __restrict__ w1, const float* __restrict__ b1,
    const float* __restrict__ w2, const float* __restrict__ b2, float* __restrict__ g,
    int H, float inv)
{
  __shared__ float m[256];
  __shared__ float h[32];
  int n = blockIdx.x; int t = threadIdx.x;
  m[t] = mean[n*256 + t] * inv;
  __syncthreads();
  if (t < H){
    float s = b1[t];
    for (int c=0; c<256; ++c) s += m[c]*w1[t*256+c];
    h[t] = siluf(s);
  }
  __syncthreads();
  float s = b2[t];
  for (int j=0; j<H; ++j) s += h[j]*w2[t*H+j];
  g[n*256+t] = sigf(s);
}

// ---------- x1 NHWC * g -> padded [n][14][35][256] bf16 hi/lo ----------
__global__ __launch_bounds__(256) void k_topad(
    const float* __restrict__ x1, const float* __restrict__ g,
    hb* __restrict__ Xh, hb* __restrict__ Xl)
{
  int y = blockIdx.x;
  int n = blockIdx.y;
  int c = threadIdx.x;
  float gc = g[n*256+c];
  for (int xx=0; xx<35; ++xx){
    float v = 0.f;
    if (y>=1 && y<=12 && xx>=1 && xx<=33)
      v = x1[((size_t)n*396 + (y-1)*33 + (xx-1))*256 + c]*gc;
    hb hv, lv; split2(v, &hv, &lv);
    size_t o = (((size_t)n*14+y)*35+xx)*256 + c;
    Xh[o] = hv; Xl[o] = lv;
  }
}

// ---------- image 3x3 conv MFMA; out bf16 hi/lo NHWC [P][256] ----------
__global__ __launch_bounds__(256) void k_conv3s_mfma(
    const hb* __restrict__ Xh, const hb* __restrict__ Xl,
    const hb* __restrict__ Wph, const hb* __restrict__ Wpl,
    const float* __restrict__ bns, const float* __restrict__ bnb,
    hb* __restrict__ outh, hb* __restrict__ outl)
{
  __shared__ short8 lbh[256], lbl[256];
  int tid = threadIdx.x;
  int wv = tid >> 6, lane = tid & 63;
  int cog = blockIdx.y;
  int Pbase = blockIdx.x*128 + wv*32;
  int m = lane & 15, q = lane >> 4;
  int P0 = Pbase + m;      if (P0 > 4751) P0 = 4751;
  int P1 = Pbase + 16 + m; if (P1 > 4751) P1 = 4751;
  int n0 = P0/396, pim0 = P0%396;
  int n1 = P1/396, pim1 = P1%396;
  size_t base0 = (size_t)((n0*14 + pim0/33)*35 + pim0%33)*32 + q;
  size_t base1 = (size_t)((n1*14 + pim1/33)*35 + pim1%33)*32 + q;
  const short8* gAh = (const short8*)(const void*)Xh;
  const short8* gAl = (const short8*)(const void*)Xl;
  const short8* gWh = (const short8*)(const void*)Wph;
  const short8* gWl = (const short8*)(const void*)Wpl;
  size_t sb = (size_t)(cog*4 + wv)*64 + lane;
  floatx4 acc[2][4];
  #pragma unroll
  for (int i=0;i<2;++i)
    #pragma unroll
    for (int j=0;j<4;++j) acc[i][j] = (floatx4)(0.f);
  short8 ph = gWh[sb], pw = gWl[sb];
  short8 cah0 = gAh[base0], cal0 = gAl[base0], cah1 = gAh[base1], cal1 = gAl[base1];
  for (int idx=0; idx<72; ++idx){
    __syncthreads();
    lbh[tid] = ph; lbl[tid] = pw;
    int nx = (idx+1 < 72) ? idx+1 : 71;
    ph = gWh[(size_t)nx*1024 + sb]; pw = gWl[(size_t)nx*1024 + sb];
    __syncthreads();
    int tap = nx >> 3, kb = nx & 7;
    int dy = (tap*11) >> 5;
    int dx = tap - dy*3;
    int ao = (dy*35+dx)*32 + kb*4;
    short8 nah0 = gAh[base0 + ao];
    short8 nal0 = gAl[base0 + ao];
    short8 nah1 = gAh[base1 + ao];
    short8 nal1 = gAl[base1 + ao];
    #pragma unroll
    for (int nb=0; nb<4; ++nb){
      short8 bh = lbh[nb*64 + lane];
      short8 bl = lbl[nb*64 + lane];
      acc[0][nb] = __builtin_amdgcn_mfma_f32_16x16x32_bf16(cah0, bh, acc[0][nb], 0,0,0);
      acc[0][nb] = __builtin_amdgcn_mfma_f32_16x16x32_bf16(cah0, bl, acc[0][nb], 0,0,0);
      acc[0][nb] = __builtin_amdgcn_mfma_f32_16x16x32_bf16(cal0, bh, acc[0][nb], 0,0,0);
      acc[1][nb] = __builtin_amdgcn_mfma_f32_16x16x32_bf16(cah1, bh, acc[1][nb], 0,0,0);
      acc[1][nb] = __builtin_amdgcn_mfma_f32_16x16x32_bf16(cah1, bl, acc[1][nb], 0,0,0);
      acc[1][nb] = __builtin_amdgcn_mfma_f32_16x16x32_bf16(cal1, bh, acc[1][nb], 0,0,0);
    }
    cah0 = nah0; cal0 = nal0; cah1 = nah1; cal1 = nal1;
  }
  int n16 = lane & 15;
  #pragma unroll
  for (int mg=0; mg<2; ++mg){
    #pragma unroll
    for (int r=0; r<4; ++r){
      int P = Pbase + mg*16 + q*4 + r;
      if (P < 4752){
        #pragma unroll
        for (int nb=0; nb<4; ++nb){
          int co = cog*64 + nb*16 + n16;
          float v = siluf(acc[mg][nb][r]*bns[co] + bnb[co]);
          hb hv, lv; split2(v, &hv, &lv);
          outh[(size_t)P*256 + co] = hv;
          outl[(size_t)P*256 + co] = lv;
        }
      }
    }
  }
}

// ---------- heads as MFMA GEMM: M=4752, N=112, K=256 ----------
__global__ __launch_bounds__(256) void k_headsM(
    const hb* __restrict__ x2h, const hb* __restrict__ x2l,
    const hb* __restrict__ Whh, const hb* __restrict__ Whl,
    const float* __restrict__ dhb, const float* __restrict__ chb,
    float* __restrict__ dep, float* __restrict__ ctx2)
{
  __shared__ short8 lbh[256], lbl[256];
  int tid = threadIdx.x;
  int wv = tid >> 6, lane = tid & 63;
  int cog = blockIdx.y;
  int nb0 = cog*4;
  int nbN = cog ? 3 : 4;
  int Pbase = blockIdx.x*128 + wv*32;
  int m = lane & 15, q = lane >> 4;
  int P0 = Pbase + m;      if (P0 > 4751) P0 = 4751;
  int P1 = Pbase + 16 + m; if (P1 > 4751) P1 = 4751;
  size_t rA0 = (size_t)P0*32 + q;
  size_t rA1 = (size_t)P1*32 + q;
  const short8* gAh = (const short8*)(const void*)x2h;
  const short8* gAl = (const short8*)(const void*)x2l;
  const short8* gWh = (const short8*)(const void*)Whh;
  const short8* gWl = (const short8*)(const void*)Whl;
  floatx4 acc[2][4];
  #pragma unroll
  for (int i=0;i<2;++i)
    #pragma unroll
    for (int j=0;j<4;++j) acc[i][j] = (floatx4)(0.f);
  for (int kb=0; kb<8; ++kb){
    __syncthreads();
    for (int i=tid; i<nbN*64; i+=256){
      lbh[i] = gWh[(size_t)(kb*7 + nb0)*64 + i];
      lbl[i] = gWl[(size_t)(kb*7 + nb0)*64 + i];
    }
    __syncthreads();
    short8 ah0 = gAh[rA0 + kb*4], al0 = gAl[rA0 + kb*4];
    short8 ah1 = gAh[rA1 + kb*4], al1 = gAl[rA1 + kb*4];
    for (int nb=0; nb<nbN; ++nb){
      short8 bh = lbh[nb*64 + lane];
      short8 bl = lbl[nb*64 + lane];
      acc[0][nb] = __builtin_amdgcn_mfma_f32_16x16x32_bf16(ah0, bh, acc[0][nb], 0,0,0);
      acc[0][nb] = __builtin_amdgcn_mfma_f32_16x16x32_bf16(ah0, bl, acc[0][nb], 0,0,0);
      acc[0][nb] = __builtin_amdgcn_mfma_f32_16x16x32_bf16(al0, bh, acc[0][nb], 0,0,0);
      acc[1][nb] = __builtin_amdgcn_mfma_f32_16x16x32_bf16(ah1, bh, acc[1][nb], 0,0,0);
      acc[1][nb] = __builtin_amdgcn_mfma_f32_16x16x32_bf16(ah1, bl, acc[1][nb], 0,0,0);
      acc[1][nb] = __builtin_amdgcn_mfma_f32_16x16x32_bf16(al1, bh, acc[1][nb], 0,0,0);
    }
  }
  int n16 = lane & 15;
  #pragma unroll
  for (int mg=0; mg<2; ++mg){
    #pragma unroll
    for (int r=0; r<4; ++r){
      int P = Pbase + mg*16 + q*4 + r;
      if (P < 4752){
        int nn = P/396, pim = P%396;
        for (int nb=0; nb<nbN; ++nb){
          int co = cog*64 + nb*16 + n16;
          float v = acc[mg][nb][r];
          if (co < 40)
            dep[((size_t)nn*40 + co)*396 + pim] = v + dhb[co];
          else if (co < 104)
            ctx2[((size_t)nn*396 + pim)*64 + (co-40)] = v + chb[co-40];
        }
      }
    }
  }
}

// ---------- softmax over 40 depth channels ----------
__global__ __launch_bounds__(256) void k_softmax40(float* __restrict__ dep)
{
  int i = blockIdx.x*256 + threadIdx.x;
  if (i >= 12*396) return;
  int n = i/396, p = i%396;
  float* base = dep + (size_t)n*40*396 + p;
  float mx = -1e30f;
  for (int d=0; d<40; ++d) mx = fmaxf(mx, base[(size_t)d*396]);
  float s = 0.f;
  for (int d=0; d<40; ++d){ float e = expf(base[(size_t)d*396]-mx); base[(size_t)d*396]=e; s+=e; }
  float inv = 1.f/s;
  for (int d=0; d<40; ++d) base[(size_t)d*396] *= inv;
}

// ---------- geometry + count (fused) ----------
__global__ __launch_bounds__(256) void k_geom(
    const float* __restrict__ rots, const float* __restrict__ trans,
    const float* __restrict__ intr, int* __restrict__ vox, int* __restrict__ cnt)
{
  int pt = blockIdx.x*256 + threadIdx.x;
  if (pt >= 190080) return;
  int b = pt/95040; int r = pt%95040;
  int n = r/15840;  int r2 = r%15840;
  int d = r2/396;   int pim = r2%396;
  int y = pim/33, x = pim%33;
  int bn = b*6+n;
  const float* R = rots + (size_t)bn*9;
  const float* T = trans + (size_t)bn*3;
  const float* K = intr + (size_t)bn*9;
  float fx=K[0], cx=K[2], fy=K[4], cy=K[5];
  float xs = (float)x * 32.96875f;
  float ys = (float)((double)y * (383.0/11.0));
  float dv = 4.0f + (float)d;
  float camx = (xs-cx)*dv/fx;
  float camy = (ys-cy)*dv/fy;
  float gx = R[0]*camx + R[1]*camy + R[2]*dv + T[0];
  float gy = R[3]*camx + R[4]*camy + R[5]*dv + T[1];
  float gz = R[6]*camx + R[7]*camy + R[8]*dv + T[2];
  int ix = (int)floorf(gx + 50.f);
  int iy = (int)floorf(gy + 50.f);
  int iz = (int)floorf((gz + 10.f)/5.f);
  bool valid = (ix>=0 && ix<100 && iy>=0 && iy<100 && iz>=0 && iz<4);
  int sid = iz*10000 + ix*100 + iy;
  vox[pt] = valid ? sid : -1;
  if (valid) atomicAdd(&cnt[b*40000 + sid], 1);
}

// ---------- scan ----------
__global__ __launch_bounds__(256) void k_scan1(
    const int* __restrict__ cnt, int* __restrict__ off, int* __restrict__ bsum)
{
  __shared__ int s[256];
  int t = threadIdx.x;
  int i = blockIdx.x*256 + t;
  int v = (i < 80000) ? cnt[i] : 0;
  s[t] = v; __syncthreads();
  for (int o=1;o<256;o<<=1){
    int x = (t>=o) ? s[t-o] : 0;
    __syncthreads();
    s[t] += x;
    __syncthreads();
  }
  if (i < 80000) off[i] = s[t] - v;
  if (t == 255) bsum[blockIdx.x] = s[255];
}

__global__ void k_scan2(int* __restrict__ bsum, int nblk)
{
  if (threadIdx.x==0 && blockIdx.x==0){
    int run = 0;
    for (int j=0;j<nblk;++j){ int t = bsum[j]; bsum[j] = run; run += t; }
  }
}

__global__ __launch_bounds__(256) void k_scan3(
    int* __restrict__ off, const int* __restrict__ bsum, int* __restrict__ cur)
{
  int i = blockIdx.x*256 + threadIdx.x;
  if (i >= 80000) return;
  int o = off[i] + bsum[i>>8];
  off[i] = o;
  cur[i] = o;
}

__global__ __launch_bounds__(256) void k_fill(
    const int* __restrict__ vox, int* __restrict__ cur, int* __restrict__ list)
{
  int pt = blockIdx.x*256 + threadIdx.x;
  if (pt >= 190080) return;
  int s = vox[pt];
  if (s < 0) return;
  int b = pt/95040;
  int slot = atomicAdd(&cur[b*40000 + s], 1);
  list[slot] = pt;
}

// ---------- gather: one wave per (b,sid), lane=channel ----------
__global__ __launch_bounds__(256) void k_gather(
    const int* __restrict__ off, const int* __restrict__ cnt, const int* __restrict__ list,
    const float* __restrict__ ctx2, const float* __restrict__ dep, float* __restrict__ bev)
{
  int tid = threadIdx.x;
  int bv = blockIdx.x*4 + (tid>>6);
  int c = tid & 63;
  int b = bv/40000, sid = bv%40000;
  int st = off[bv], nn = cnt[bv];
  float s = 0.f;
  for (int k=0;k<nn;++k){
    int pt = list[st+k];
    int r = pt%95040;
    int bn = b*6 + r/15840;
    int r2 = r%15840;
    int dd = r2/396, pim = r2%396;
    s += ctx2[((size_t)bn*396+pim)*64 + c] * dep[((size_t)bn*40+dd)*396 + pim];
  }
  int iz = sid/10000, rem = sid%10000;
  bev[(size_t)b*2560000 + (size_t)iz*640000 + (size_t)c*10000 + rem] = s;
}

// ---------- NCHW fp32 (*g) -> padded NHWC bf16 hi/lo, coalesced LDS transpose ----------
__global__ __launch_bounds__(256) void k_tohwc2(
    const float* __restrict__ in, hb* __restrict__ Ah, hb* __restrict__ Al,
    const float* __restrict__ g)
{
  __shared__ float tile[32*105];
  int py = blockIdx.x;
  int b  = blockIdx.y;
  int cg = blockIdx.z;
  int tid = threadIdx.x;
  bool inner = (py >= 1 && py <= 100);
  if (inner){
    if (tid < 64){ int cil = tid & 31; int col = (tid>>5) ? 101 : 0; tile[cil*105 + col] = 0.f; }
    for (int i = tid; i < 3200; i += 256){
      int cil = i / 100, x = i % 100;
      int ci = cg*32 + cil;
      tile[cil*105 + (x+1)] = in[(((size_t)b*256 + ci)*100 + (py-1))*100 + x];
    }
  }
  __syncthreads();
  for (int i = tid; i < 32*102; i += 256){
    int px = i >> 5, cil = i & 31;
    int ci = cg*32 + cil;
    float v = 0.f;
    if (inner){
      v = tile[cil*105 + px];
      if (g) v *= g[b*256 + ci];
    }
    hb hv, lv; split2(v, &hv, &lv);
    size_t o = (((size_t)b*102 + py)*102 + px)*256 + ci;
    Ah[o] = hv; Al[o] = lv;
  }
}

// ---------- row mean (NCHW rows) ----------
__global__ __launch_bounds__(256) void k_rowmean(
    const float* __restrict__ in, float* __restrict__ out, int rowlen, float inv)
{
  __shared__ float ws[4];
  int row = blockIdx.x; int t = threadIdx.x;
  const float* p = in + (size_t)row*rowlen;
  float s = 0.f;
  for (int i=t; i<rowlen; i+=256) s += p[i];
  #pragma unroll
  for (int off=32; off; off>>=1) s += __shfl_down(s, off);
  if ((t&63)==0) ws[t>>6] = s;
  __syncthreads();
  if (t==0) out[row] = (ws[0]+ws[1]+ws[2]+ws[3]) * inv;
}

// ---------- BEV MFMA conv, LDS A-staging, B double-buffer ----------
__global__ __launch_bounds__(256) void k_conv3_bevm(
    const hb* __restrict__ Ah, const hb* __restrict__ Al,
    const hb* __restrict__ Wph, const hb* __restrict__ Wpl,
    const float* __restrict__ bns, const float* __restrict__ bnb,
    const float* __restrict__ res, float* __restrict__ out, int Cout, int NBG)
{
  __shared__ __align__(16) short sAh[10*18*44];
  __shared__ __align__(16) short sAl[10*18*44];
  __shared__ short8 lbh[2][256], lbl[2][256];
  const int NB = Cout >> 4;
  int tid = threadIdx.x;
  int wv = tid >> 6, lane = tid & 63;
  int L = blockIdx.x;
  int spatial = L / (NBG*2);
  int rem = L % (NBG*2);
  int cog = rem % NBG;
  int bb  = rem / NBG;
  int xg = spatial % 7, yg = spatial / 7;
  int x0 = xg*16;
  int y0 = yg*8 + wv;
  int m = lane & 15, q = lane >> 4;
  int nb0 = cog*4;
  floatx4 acc[2][4];
  #pragma unroll
  for (int i=0;i<2;++i)
    #pragma unroll
    for (int j=0;j<4;++j) acc[i][j] = (floatx4)(0.f);

  const short8* gAh = (const short8*)(const void*)Ah;
  const short8* gAl = (const short8*)(const void*)Al;
  const short8* gWh = (const short8*)(const void*)Wph;
  const short8* gWl = (const short8*)(const void*)Wpl;
  const size_t nbstride = (size_t)NB*64;
  const size_t sb = (size_t)(nb0 + wv)*64 + lane;

  short8 ph = gWh[sb], pl = gWl[sb];
  int cur = 0;

  for (int kb=0; kb<8; ++kb){
    #pragma unroll 3
    for (int tap=0; tap<9; ++tap){
      int idx2 = kb*9 + tap;
      if (tap == 0){
        __syncthreads();
        for (int i = tid; i < 720; i += 256){
          int rc = i >> 2, part = i & 3;
          int r = rc / 18, c = rc % 18;
          int yr = yg*8 + r; if (yr > 101) yr = 101;
          int xc = x0 + c;   if (xc > 101) xc = 101;
          size_t so = ((size_t)((bb*102 + yr)*102 + xc))*32 + kb*4 + part;
          short8 vh = gAh[so], vl = gAl[so];
          int dst = (r*18 + c)*44 + part*8;
          *(short8*)(sAh + dst) = vh;
          *(short8*)(sAl + dst) = vl;
        }
      }
      lbh[cur][tid] = ph; lbl[cur][tid] = pl;
      int nx = (idx2+1 < 72) ? idx2+1 : 71;
      ph = gWh[(size_t)nx*nbstride + sb];
      pl = gWl[(size_t)nx*nbstride + sb];
      __syncthreads();
      int dy = (tap*11) >> 5;
      int dx = tap - dy*3;
      int cc = dx + m;
      int a0 = ((wv + dy)*18 + cc)*44 + q*8;
      int a1 = ((wv + 4 + dy)*18 + cc)*44 + q*8;
      short8 cah0 = *(const short8*)(sAh + a0);
      short8 cal0 = *(const short8*)(sAl + a0);
      short8 cah1 = *(const short8*)(sAh + a1);
      short8 cal1 = *(const short8*)(sAl + a1);
      #pragma unroll
      for (int nb=0; nb<4; ++nb){
        short8 bh = lbh[cur][nb*64 + lane];
        short8 bl = lbl[cur][nb*64 + lane];
        acc[0][nb] = __builtin_amdgcn_mfma_f32_16x16x32_bf16(cah0, bh, acc[0][nb], 0,0,0);
        acc[0][nb] = __builtin_amdgcn_mfma_f32_16x16x32_bf16(cah0, bl, acc[0][nb], 0,0,0);
        acc[0][nb] = __builtin_amdgcn_mfma_f32_16x16x32_bf16(cal0, bh, acc[0][nb], 0,0,0);
        acc[1][nb] = __builtin_amdgcn_mfma_f32_16x16x32_bf16(cah1, bh, acc[1][nb], 0,0,0);
        acc[1][nb] = __builtin_amdgcn_mfma_f32_16x16x32_bf16(cah1, bl, acc[1][nb], 0,0,0);
        acc[1][nb] = __builtin_amdgcn_mfma_f32_16x16x32_bf16(cal1, bh, acc[1][nb], 0,0,0);
      }
      cur ^= 1;
    }
  }

  int n = lane & 15;
  int xq = x0 + q*4;
  #pragma unroll
  for (int mg=0; mg<2; ++mg){
    int yo = y0 + mg*4;
    if (yo < 100 && xq < 100){
      #pragma unroll
      for (int nb=0; nb<4; ++nb){
        int co = cog*64 + nb*16 + n;
        float s = bns[co], bv = bnb[co];
        floatx4 a = acc[mg][nb];
        float4 v;
        v.x = fmaxf(a[0]*s+bv, 0.f);
        v.y = fmaxf(a[1]*s+bv, 0.f);
        v.z = fmaxf(a[2]*s+bv, 0.f);
        v.w = fmaxf(a[3]*s+bv, 0.f);
        size_t o = ((size_t)(bb*Cout+co)*100 + yo)*100 + xq;
        if (res){
          float4 rv = *(const float4*)(res + o);
          v.x += rv.x; v.y += rv.y; v.z += rv.z; v.w += rv.w;
        }
        *(float4*)(out + o) = v;
      }
    }
  }
}

// ---------- final 1x1 conv 128->16, one pass over h3 ----------
__global__ __launch_bounds__(256) void k_final2(
    const float* __restrict__ h, const float* __restrict__ W, const float* __restrict__ bias,
    float* __restrict__ out)
{
  __shared__ float wsl[2048];
  __shared__ float bs[16];
  int tid = threadIdx.x;
  int b = blockIdx.y;
  for (int i=tid; i<2048; i+=256) wsl[i] = W[i];
  if (tid < 16) bs[tid] = bias[tid];
  __syncthreads();
  int pix = blockIdx.x*256 + tid;
  if (pix >= 10000) return;
  float acc[16];
  #pragma unroll
  for (int oc=0; oc<16; ++oc) acc[oc] = bs[oc];
  const float* hb_ = h + (size_t)b*128*10000 + pix;
  for (int ci=0; ci<128; ++ci){
    float hv = hb_[(size_t)ci*10000];
    #pragma unroll
    for (int oc=0; oc<16; ++oc) acc[oc] += hv * wsl[oc*128 + ci];
  }
  #pragma unroll
  for (int oc=0; oc<16; ++oc)
    out[((size_t)(b*16+oc))*10000 + pix] = acc[oc];
}

extern "C" void kernel_launch(void* const* d_in, const int* in_sizes, int n_in,
                              void* d_out, int out_size, void* d_ws, size_t ws_size,
                              hipStream_t stream)
{
  (void)in_sizes; (void)n_in; (void)out_size; (void)ws_size;
  const float* feats = (const float*)d_in[0];
  const float* rots  = (const float*)d_in[1];
  const float* trans = (const float*)d_in[2];
  const float* intr  = (const float*)d_in[3];
  const float* nw1   = (const float*)d_in[4];
  const float* bn1s  = (const float*)d_in[5];
  const float* bn1b  = (const float*)d_in[6];
  const float* se1w1 = (const float*)d_in[7];
  const float* se1b1 = (const float*)d_in[8];
  const float* se1w2 = (const float*)d_in[9];
  const float* se1b2 = (const float*)d_in[10];
  const float* nw2   = (const float*)d_in[11];
  const float* bn2s  = (const float*)d_in[12];
  const float* bn2b  = (const float*)d_in[13];
  const float* dhw   = (const float*)d_in[14];
  const float* dhb   = (const float*)d_in[15];
  const float* chw   = (const float*)d_in[16];
  const float* chb   = (const float*)d_in[17];
  const float* bcw1  = (const float*)d_in[18];
  const float* bcs1  = (const float*)d_in[19];
  const float* bcb1  = (const float*)d_in[20];
  const float* bcsw1 = (const float*)d_in[21];
  const float* bcsb1 = (const float*)d_in[22];
  const float* bcsw2 = (const float*)d_in[23];
  const float* bcsb2 = (const float*)d_in[24];
  const float* bcw2  = (const float*)d_in[25];
  const float* bcs2  = (const float*)d_in[26];
  const float* bcb2  = (const float*)d_in[27];
  const float* dw1   = (const float*)d_in[28];
  const float* ds1   = (const float*)d_in[29];
  const float* db1   = (const float*)d_in[30];
  const float* dw2   = (const float*)d_in[31];
  const float* db2   = (const float*)d_in[32];
  float* out = (float*)d_out;

  // ---- workspace layout (float units) ----
  float* ws = (float*)d_ws;
  float* bev   = ws;                       // S0: 5,120,000
  float* h1    = ws + 5120000;             // S1: 5,120,000
  hb*    Ah    = (hb*)(ws + 10240000);     // S2: 2,663,424 fu
  hb*    Al    = (hb*)(ws + 12903424);     // S3: 2,663,424 fu
  float* x2    = ws + 15566848;            // S4: 1,216,512
  float* S5    = ws + 16783360;            // 589,824
  float* dep   = ws + 17373184;            // 190,080
  float* ctx2  = ws + 17563264;            // 304,128
  float* mean1 = ws + 17867392;            // 3072
  float* g1    = mean1 + 3072;
  float* mean2 = g1 + 3072;
  float* g2    = mean2 + 512;
  int*   vox   = (int*)(ws + 17875584);    // 190,080 ints
  // phase aliases
  hb* Fph  = (hb*)bev;                     // 3,041,280 fu (frag-packed hi)
  hb* Wc1h = (hb*)(bev + 3041280);         // 163,840 fu
  hb* Wc1l = (hb*)(bev + 3205120);         // 163,840 fu
  float* x1 = h1;                          // NHWC conv1 out
  hb* Fpl  = (hb*)(h1 + 1216512);          // 3,041,280 fu (frag-packed lo)
  hb* Xh   = (hb*)Ah;
  hb* Xl   = (hb*)Al;
  hb* Wc2h = (hb*)S5;                      // 294,912 fu
  hb* Wc2l = (hb*)(S5 + 294912);           // 294,912 fu
  hb* x2h  = (hb*)x2;                      // 608,256 fu
  hb* x2l  = (hb*)(x2 + 608256);           // 608,256 fu
  hb* Whh  = (hb*)S5;
  hb* Whl  = (hb*)(S5 + 14336);
  int* cnt  = (int*)h1;
  int* off  = cnt + 80000;
  int* cur  = off + 80000;
  int* bsum = cur + 80000;
  int* list = bsum + 1024;
  float* h3 = h1;
  hb* Wp1h = (hb*)x2;
  hb* Wp1l = (hb*)(x2 + 294912);
  hb* Wp3h = (hb*)(x2 + 589824);
  hb* Wp3l = (hb*)(x2 + 589824 + 147456);
  hb* Wp2h = (hb*)S5;
  hb* Wp2l = (hb*)(S5 + 294912);

  // ---- image branch (MFMA) ----
  k_trans_featsP<<<dim3(7,20,12),256,0,stream>>>(feats,Fph,Fpl);
  k_wpack1<<<1280,256,0,stream>>>(nw1,Wc1h,Wc1l);
  k_mfma_gemm1<<<dim3(38,4),256,0,stream>>>(Fph,Fpl,Wc1h,Wc1l,bn1s,bn1b,x1);
  k_meanN<<<12,256,0,stream>>>(x1,mean1);
  k_se_fc<<<12,256,0,stream>>>(mean1,se1w1,se1b1,se1w2,se1b2,g1,32,1.f);
  k_topad<<<dim3(14,12),256,0,stream>>>(x1,g1,Xh,Xl);
  k_wpack<<<2304,256,0,stream>>>(nw2,Wc2h,Wc2l,16);
  k_conv3s_mfma<<<dim3(38,4),256,0,stream>>>(Xh,Xl,Wc2h,Wc2l,bn2s,bn2b,x2h,x2l);
  k_wpackH<<<112,256,0,stream>>>(dhw,chw,Whh,Whl);
  k_headsM<<<dim3(38,2),256,0,stream>>>(x2h,x2l,Whh,Whl,dhb,chb,dep,ctx2);
  k_softmax40<<<19,256,0,stream>>>(dep);

  // ---- pack BEV conv weights kb-major ----
  k_wpackT<<<2304,256,0,stream>>>(bcw1,Wp1h,Wp1l,16);
  k_wpackT<<<2304,256,0,stream>>>(bcw2,Wp2h,Wp2l,16);
  k_wpackT<<<1152,256,0,stream>>>(dw1,Wp3h,Wp3l,8);

  // ---- lift-splat (gather form) ----
  hipMemsetAsync(cnt, 0, 80000*sizeof(int), stream);
  k_geom<<<(190080+255)/256,256,0,stream>>>(rots,trans,intr,vox,cnt);
  k_scan1<<<313,256,0,stream>>>(cnt,off,bsum);
  k_scan2<<<1,64,0,stream>>>(bsum,313);
  k_scan3<<<(80000+255)/256,256,0,stream>>>(off,bsum,cur);
  k_fill<<<(190080+255)/256,256,0,stream>>>(vox,cur,list);
  k_gather<<<20000,256,0,stream>>>(off,cnt,list,ctx2,dep,bev);

  // ---- BEV encoder (MFMA convs) ----
  k_tohwc2<<<dim3(102,2,8),256,0,stream>>>(bev,Ah,Al,nullptr);
  k_conv3_bevm<<<728,256,0,stream>>>(Ah,Al,Wp1h,Wp1l,bcs1,bcb1,nullptr,h1,256,4);
  k_rowmean<<<512,256,0,stream>>>(h1,mean2,10000,1e-4f);
  k_se_fc<<<2,256,0,stream>>>(mean2,bcsw1,bcsb1,bcsw2,bcsb2,g2,16,1.f);
  k_tohwc2<<<dim3(102,2,8),256,0,stream>>>(h1,Ah,Al,g2);
  k_conv3_bevm<<<728,256,0,stream>>>(Ah,Al,Wp2h,Wp2l,bcs2,bcb2,bev,bev,256,4);
  k_tohwc2<<<dim3(102,2,8),256,0,stream>>>(bev,Ah,Al,nullptr);
  k_conv3_bevm<<<364,256,0,stream>>>(Ah,Al,Wp3h,Wp3l,ds1,db1,nullptr,h3,128,2);
  k_final2<<<dim3(40,2),256,0,stream>>>(h3,dw2,db2,out);
}

// Round 11
// 671.491 us; speedup vs baseline: 1.0684x; 1.0231x over previous
//
#include <hip/hip_runtime.h>
#include <hip/hip_bf16.h>
#include <cmath>

// LSS pipeline R11: image 3x3 conv -> LDS-staged MFMA (same structure as BEV
// conv); gather fused with bf16 NHWC pack (drop tohwc#1, add zero_ring);
// merged pack kernels and meanN+se_fc (4 fewer launches).

typedef __attribute__((ext_vector_type(8))) short short8;
typedef __attribute__((ext_vector_type(4))) float floatx4;
typedef __hip_bfloat16 hb;

__device__ __forceinline__ float sigf(float x){ return 1.0f/(1.0f+expf(-x)); }
__device__ __forceinline__ float siluf(float x){ return x*sigf(x); }
__device__ __forceinline__ void split2(float v, hb* h, hb* l){
  hb hv = __float2bfloat16(v);
  *h = hv; *l = __float2bfloat16(v - __bfloat162float(hv));
}

// ---------- feats NCHW -> A-frag-packed bf16 hi/lo Fp[(T*40+kb)*64+lane][8] ----------
__global__ __launch_bounds__(256) void k_trans_featsP(
    const float* __restrict__ feats, hb* __restrict__ Fph, hb* __restrict__ Fpl)
{
  __shared__ float tile[64][65];
  int n = blockIdx.z;
  int p0 = blockIdx.x*64;
  int c0 = blockIdx.y*64;
  int tid = threadIdx.x;
  int tr = tid >> 6;
  int tc = tid & 63;
  #pragma unroll
  for (int it=0; it<16; ++it){
    int ci = c0 + it*4 + tr;
    int p = p0 + tc;
    float v = 0.f;
    if (p < 396) v = feats[((size_t)n*1280 + ci)*396 + p];
    tile[it*4+tr][tc] = v;
  }
  __syncthreads();
  #pragma unroll
  for (int iter=0; iter<2; ++iter){
    int idx = iter*256 + tid;
    int oc = idx >> 6;
    int pl = idx & 63;
    int p = p0 + pl;
    if (p < 396){
      int P = n*396 + p;
      int T = P >> 4, mm = P & 15;
      int kb = (c0 >> 5) + (oc >> 2);
      int q = oc & 3;
      int lane = q*16 + mm;
      size_t o = (((size_t)T*40 + kb)*64 + lane)*8;
      #pragma unroll
      for (int j=0; j<8; ++j){
        hb hv, lv; split2(tile[oc*8+j][pl], &hv, &lv);
        Fph[o+j] = hv; Fpl[o+j] = lv;
      }
    }
  }
}

// ---------- merged early packs: conv1 weights + image 3x3 weights (kb-major) ----------
__global__ __launch_bounds__(256) void k_wpackE(
    const float* __restrict__ nw1, const float* __restrict__ nw2,
    hb* __restrict__ Wc1h, hb* __restrict__ Wc1l,
    hb* __restrict__ Wc2h, hb* __restrict__ Wc2l)
{
  int i = blockIdx.x*256 + threadIdx.x;
  if (i < 327680){
    int j = i & 7;
    int lane = (i>>3) & 63;
    int t2 = i >> 9;
    int nb = t2 & 15;
    int kb = t2 >> 4;
    int ci = kb*32 + (lane>>4)*8 + j;
    int co = nb*16 + (lane&15);
    hb hv, lv; split2(nw1[(size_t)co*1280 + ci], &hv, &lv);
    Wc1h[i] = hv; Wc1l[i] = lv;
  } else {
    int i2 = i - 327680;
    if (i2 >= 589824) return;
    int j = i2 & 7;
    int t1 = i2 >> 3;
    int lane = t1 & 63;
    int t2 = t1 >> 6;
    int nb = t2 % 16;
    int t3 = t2 / 16;
    int tap = t3 % 9;
    int kb = t3 / 9;
    int ci = kb*32 + (lane>>4)*8 + j;
    int co = nb*16 + (lane&15);
    hb hv, lv; split2(nw2[(size_t)co*2304 + ci*9 + tap], &hv, &lv);
    Wc2h[i2] = hv; Wc2l[i2] = lv;
  }
}

// ---------- merged BEV packs kb-major: bcw1->Wp1, bcw2->Wp2, dw1->Wp3 ----------
__global__ __launch_bounds__(256) void k_wpackT3(
    const float* __restrict__ bcw1, const float* __restrict__ bcw2,
    const float* __restrict__ dw1,
    hb* __restrict__ W1h, hb* __restrict__ W1l,
    hb* __restrict__ W2h, hb* __restrict__ W2l,
    hb* __restrict__ W3h, hb* __restrict__ W3l)
{
  int gi = blockIdx.x*256 + threadIdx.x;
  const float* W; hb* Wh; hb* Wl; int NB; int i;
  if (gi < 589824){ W = bcw1; Wh = W1h; Wl = W1l; NB = 16; i = gi; }
  else if (gi < 1179648){ W = bcw2; Wh = W2h; Wl = W2l; NB = 16; i = gi - 589824; }
  else if (gi < 1474560){ W = dw1; Wh = W3h; Wl = W3l; NB = 8; i = gi - 1179648; }
  else return;
  int j = i & 7;
  int t1 = i >> 3;
  int lane = t1 & 63;
  int t2 = t1 >> 6;
  int nb = t2 % NB;
  int t3 = t2 / NB;
  int tap = t3 % 9;
  int kb = t3 / 9;
  int ci = kb*32 + (lane>>4)*8 + j;
  int co = nb*16 + (lane&15);
  hb hv, lv; split2(W[(size_t)co*2304 + ci*9 + tap], &hv, &lv);
  Wh[i] = hv; Wl[i] = lv;
}

// ---------- pack heads weights ----------
__global__ __launch_bounds__(256) void k_wpackH(
    const float* __restrict__ dhw, const float* __restrict__ chw,
    hb* __restrict__ Wph, hb* __restrict__ Wpl)
{
  int i = blockIdx.x*256 + threadIdx.x;
  if (i >= 8*7*512) return;
  int j = i & 7;
  int t1 = i >> 3;
  int lane = t1 & 63;
  int t2 = t1 >> 6;
  int nb = t2 % 7;
  int kb = t2 / 7;
  int ci = kb*32 + (lane>>4)*8 + j;
  int co = nb*16 + (lane&15);
  float w = 0.f;
  if (co < 40) w = dhw[(size_t)co*256 + ci];
  else if (co < 104) w = chw[(size_t)(co-40)*256 + ci];
  hb hv, lv; split2(w, &hv, &lv);
  Wph[i] = hv; Wpl[i] = lv;
}

// ---------- conv1 as MFMA GEMM on frag-packed A; BN+SiLU; out NHWC ----------
__global__ __launch_bounds__(256) void k_mfma_gemm1(
    const hb* __restrict__ Fph, const hb* __restrict__ Fpl,
    const hb* __restrict__ Wph, const hb* __restrict__ Wpl,
    const float* __restrict__ bns, const float* __restrict__ bnb,
    float* __restrict__ out)
{
  __shared__ short8 lbh[256], lbl[256];
  int tid = threadIdx.x;
  int wv = tid >> 6, lane = tid & 63;
  int cog = blockIdx.y;
  int Pbase = blockIdx.x*128 + wv*32;
  int q = lane >> 4;
  int T0 = blockIdx.x*8 + wv*2; if (T0 > 296) T0 = 296;
  int T1 = T0 + 1;              if (T1 > 296) T1 = 296;
  size_t a0 = (size_t)T0*2560 + lane;
  size_t a1 = (size_t)T1*2560 + lane;
  const short8* gAh = (const short8*)(const void*)Fph;
  const short8* gAl = (const short8*)(const void*)Fpl;
  const short8* gWh = (const short8*)(const void*)Wph;
  const short8* gWl = (const short8*)(const void*)Wpl;
  size_t sb = (size_t)(cog*4 + wv)*64 + lane;
  floatx4 acc[2][4];
  #pragma unroll
  for (int i=0;i<2;++i)
    #pragma unroll
    for (int j=0;j<4;++j) acc[i][j] = (floatx4)(0.f);
  short8 ph = gWh[sb], pw = gWl[sb];
  short8 cah0 = gAh[a0], cal0 = gAl[a0], cah1 = gAh[a1], cal1 = gAl[a1];
  for (int kb=0; kb<40; ++kb){
    __syncthreads();
    lbh[tid] = ph; lbl[tid] = pw;
    int nx = (kb+1 < 40) ? kb+1 : 39;
    ph = gWh[(size_t)nx*1024 + sb]; pw = gWl[(size_t)nx*1024 + sb];
    __syncthreads();
    short8 nah0 = gAh[a0 + (size_t)nx*64];
    short8 nal0 = gAl[a0 + (size_t)nx*64];
    short8 nah1 = gAh[a1 + (size_t)nx*64];
    short8 nal1 = gAl[a1 + (size_t)nx*64];
    #pragma unroll
    for (int nb=0; nb<4; ++nb){
      short8 bh = lbh[nb*64 + lane];
      short8 bl = lbl[nb*64 + lane];
      acc[0][nb] = __builtin_amdgcn_mfma_f32_16x16x32_bf16(cah0, bh, acc[0][nb], 0,0,0);
      acc[0][nb] = __builtin_amdgcn_mfma_f32_16x16x32_bf16(cah0, bl, acc[0][nb], 0,0,0);
      acc[0][nb] = __builtin_amdgcn_mfma_f32_16x16x32_bf16(cal0, bh, acc[0][nb], 0,0,0);
      acc[1][nb] = __builtin_amdgcn_mfma_f32_16x16x32_bf16(cah1, bh, acc[1][nb], 0,0,0);
      acc[1][nb] = __builtin_amdgcn_mfma_f32_16x16x32_bf16(cah1, bl, acc[1][nb], 0,0,0);
      acc[1][nb] = __builtin_amdgcn_mfma_f32_16x16x32_bf16(cal1, bh, acc[1][nb], 0,0,0);
    }
    cah0 = nah0; cal0 = nal0; cah1 = nah1; cal1 = nal1;
  }
  int n16 = lane & 15;
  #pragma unroll
  for (int mg=0; mg<2; ++mg){
    #pragma unroll
    for (int nb=0; nb<4; ++nb){
      int co = cog*64 + nb*16 + n16;
      float s = bns[co], bv = bnb[co];
      #pragma unroll
      for (int r=0; r<4; ++r){
        int P = Pbase + mg*16 + q*4 + r;
        if (P < 4752) out[(size_t)P*256 + co] = siluf(acc[mg][nb][r]*s + bv);
      }
    }
  }
}

// ---------- fused mean(396) + SE FC (image branch), one block per n ----------
__global__ __launch_bounds__(256) void k_meanse(
    const float* __restrict__ x1, const float* __restrict__ w1, const float* __restrict__ b1,
    const float* __restrict__ w2, const float* __restrict__ b2, float* __restrict__ g)
{
  __shared__ float m[256];
  __shared__ float h[32];
  int n = blockIdx.x; int t = threadIdx.x;
  float s = 0.f;
  for (int p=0; p<396; ++p) s += x1[((size_t)n*396+p)*256 + t];
  m[t] = s*(1.f/396.f);
  __syncthreads();
  if (t < 32){
    float s2 = b1[t];
    for (int c=0; c<256; ++c) s2 += m[c]*w1[t*256+c];
    h[t] = siluf(s2);
  }
  __syncthreads();
  float s3 = b2[t];
  for (int j=0; j<32; ++j) s3 += h[j]*w2[t*32+j];
  g[n*256+t] = sigf(s3);
}

// ---------- SE FC (BEV, H=16) ----------
__global__ __launch_bounds__(256) void k_se_fc(
    const float* __restrict__ mean, const float* __restrict__ w1, const float* __restrict__ b1,
    const float* __restrict__ w2, const float* __restrict__ b2, float* __restrict__ g, int H)
{
  __shared__ float m[256];
  __shared__ float h[32];
  int n = blockIdx.x; int t = threadIdx.x;
  m[t] = mean[n*256 + t];
  __syncthreads();
  if (t < H){
    float s = b1[t];
    for (int c=0; c<256; ++c) s += m[c]*w1[t*256+c];
    h[t] = siluf(s);
  }
  __syncthreads();
  float s = b2[t];
  for (int j=0; j<H; ++j) s += h[j]*w2[t*H+j];
  g[n*256+t] = sigf(s);
}

// ---------- x1 NHWC * g -> padded [n][14][35][256] bf16 hi/lo ----------
__global__ __launch_bounds__(256) void k_topad(
    const float* __restrict__ x1, const float* __restrict__ g,
    hb* __restrict__ Xh, hb* __restrict__ Xl)
{
  int y = blockIdx.x;
  int n = blockIdx.y;
  int c = threadIdx.x;
  float gc = g[n*256+c];
  for (int xx=0; xx<35; ++xx){
    float v = 0.f;
    if (y>=1 && y<=12 && xx>=1 && xx<=33)
      v = x1[((size_t)n*396 + (y-1)*33 + (xx-1))*256 + c]*gc;
    hb hv, lv; split2(v, &hv, &lv);
    size_t o = (((size_t)n*14+y)*35+xx)*256 + c;
    Xh[o] = hv; Xl[o] = lv;
  }
}

// ---------- image 3x3 conv, LDS-staged MFMA (BEV-conv structure, 14x35 dims) ----------
// grid (3, 24, 4): xg, (n,yg), cog.  Output NHWC bf16 hi/lo [P=n*396+pim][256].
__global__ __launch_bounds__(256) void k_conv3_img(
    const hb* __restrict__ Xh, const hb* __restrict__ Xl,
    const hb* __restrict__ Wph, const hb* __restrict__ Wpl,
    const float* __restrict__ bns, const float* __restrict__ bnb,
    hb* __restrict__ outh, hb* __restrict__ outl)
{
  __shared__ __align__(16) short sAh[10*18*44];
  __shared__ __align__(16) short sAl[10*18*44];
  __shared__ short8 lbh[2][256], lbl[2][256];
  int tid = threadIdx.x;
  int wv = tid >> 6, lane = tid & 63;
  int xg = blockIdx.x;
  int n = blockIdx.y >> 1, yg = blockIdx.y & 1;
  int cog = blockIdx.z;
  int x0 = xg*16;
  int y0 = yg*8 + wv;
  int m = lane & 15, q = lane >> 4;
  floatx4 acc[2][4];
  #pragma unroll
  for (int i=0;i<2;++i)
    #pragma unroll
    for (int j=0;j<4;++j) acc[i][j] = (floatx4)(0.f);

  const short8* gAh = (const short8*)(const void*)Xh;
  const short8* gAl = (const short8*)(const void*)Xl;
  const short8* gWh = (const short8*)(const void*)Wph;
  const short8* gWl = (const short8*)(const void*)Wpl;
  const size_t sb = (size_t)(cog*4 + wv)*64 + lane;
  const size_t nbase = (size_t)n*14*35*32;   // short8 units

  short8 ph = gWh[sb], pl = gWl[sb];
  int cur = 0;

  for (int kb=0; kb<8; ++kb){
    #pragma unroll 3
    for (int tap=0; tap<9; ++tap){
      int idx2 = kb*9 + tap;
      if (tap == 0){
        __syncthreads();
        for (int i = tid; i < 720; i += 256){
          int rc = i >> 2, part = i & 3;
          int r = rc / 18, c2 = rc % 18;
          int yr = yg*8 + r; if (yr > 13) yr = 13;
          int xc = x0 + c2;  if (xc > 34) xc = 34;
          size_t so = nbase + (size_t)(yr*35 + xc)*32 + kb*4 + part;
          short8 vh = gAh[so], vl = gAl[so];
          int dst = (r*18 + c2)*44 + part*8;
          *(short8*)(sAh + dst) = vh;
          *(short8*)(sAl + dst) = vl;
        }
      }
      lbh[cur][tid] = ph; lbl[cur][tid] = pl;
      int nx = (idx2+1 < 72) ? idx2+1 : 71;
      ph = gWh[(size_t)nx*1024 + sb];
      pl = gWl[(size_t)nx*1024 + sb];
      __syncthreads();
      int dy = (tap*11) >> 5;
      int dx = tap - dy*3;
      int cc = dx + m;
      int a0 = ((wv + dy)*18 + cc)*44 + q*8;
      int a1 = ((wv + 4 + dy)*18 + cc)*44 + q*8;
      short8 cah0 = *(const short8*)(sAh + a0);
      short8 cal0 = *(const short8*)(sAl + a0);
      short8 cah1 = *(const short8*)(sAh + a1);
      short8 cal1 = *(const short8*)(sAl + a1);
      #pragma unroll
      for (int nb=0; nb<4; ++nb){
        short8 bh = lbh[cur][nb*64 + lane];
        short8 bl = lbl[cur][nb*64 + lane];
        acc[0][nb] = __builtin_amdgcn_mfma_f32_16x16x32_bf16(cah0, bh, acc[0][nb], 0,0,0);
        acc[0][nb] = __builtin_amdgcn_mfma_f32_16x16x32_bf16(cah0, bl, acc[0][nb], 0,0,0);
        acc[0][nb] = __builtin_amdgcn_mfma_f32_16x16x32_bf16(cal0, bh, acc[0][nb], 0,0,0);
        acc[1][nb] = __builtin_amdgcn_mfma_f32_16x16x32_bf16(cah1, bh, acc[1][nb], 0,0,0);
        acc[1][nb] = __builtin_amdgcn_mfma_f32_16x16x32_bf16(cah1, bl, acc[1][nb], 0,0,0);
        acc[1][nb] = __builtin_amdgcn_mfma_f32_16x16x32_bf16(cal1, bh, acc[1][nb], 0,0,0);
      }
      cur ^= 1;
    }
  }

  int n16 = lane & 15;
  #pragma unroll
  for (int mg=0; mg<2; ++mg){
    int oy = y0 + mg*4;
    if (oy < 12){
      #pragma unroll
      for (int r=0; r<4; ++r){
        int ox = x0 + q*4 + r;
        if (ox < 33){
          int P = n*396 + oy*33 + ox;
          #pragma unroll
          for (int nb=0; nb<4; ++nb){
            int co = cog*64 + nb*16 + n16;
            float v = siluf(acc[mg][nb][r]*bns[co] + bnb[co]);
            hb hv, lv; split2(v, &hv, &lv);
            outh[(size_t)P*256 + co] = hv;
            outl[(size_t)P*256 + co] = lv;
          }
        }
      }
    }
  }
}

// ---------- heads as MFMA GEMM: M=4752, N=112, K=256 ----------
__global__ __launch_bounds__(256) void k_headsM(
    const hb* __restrict__ x2h, const hb* __restrict__ x2l,
    const hb* __restrict__ Whh, const hb* __restrict__ Whl,
    const float* __restrict__ dhb, const float* __restrict__ chb,
    float* __restrict__ dep, float* __restrict__ ctx2)
{
  __shared__ short8 lbh[256], lbl[256];
  int tid = threadIdx.x;
  int wv = tid >> 6, lane = tid & 63;
  int cog = blockIdx.y;
  int nb0 = cog*4;
  int nbN = cog ? 3 : 4;
  int Pbase = blockIdx.x*128 + wv*32;
  int m = lane & 15, q = lane >> 4;
  int P0 = Pbase + m;      if (P0 > 4751) P0 = 4751;
  int P1 = Pbase + 16 + m; if (P1 > 4751) P1 = 4751;
  size_t rA0 = (size_t)P0*32 + q;
  size_t rA1 = (size_t)P1*32 + q;
  const short8* gAh = (const short8*)(const void*)x2h;
  const short8* gAl = (const short8*)(const void*)x2l;
  const short8* gWh = (const short8*)(const void*)Whh;
  const short8* gWl = (const short8*)(const void*)Whl;
  floatx4 acc[2][4];
  #pragma unroll
  for (int i=0;i<2;++i)
    #pragma unroll
    for (int j=0;j<4;++j) acc[i][j] = (floatx4)(0.f);
  for (int kb=0; kb<8; ++kb){
    __syncthreads();
    for (int i=tid; i<nbN*64; i+=256){
      lbh[i] = gWh[(size_t)(kb*7 + nb0)*64 + i];
      lbl[i] = gWl[(size_t)(kb*7 + nb0)*64 + i];
    }
    __syncthreads();
    short8 ah0 = gAh[rA0 + kb*4], al0 = gAl[rA0 + kb*4];
    short8 ah1 = gAh[rA1 + kb*4], al1 = gAl[rA1 + kb*4];
    for (int nb=0; nb<nbN; ++nb){
      short8 bh = lbh[nb*64 + lane];
      short8 bl = lbl[nb*64 + lane];
      acc[0][nb] = __builtin_amdgcn_mfma_f32_16x16x32_bf16(ah0, bh, acc[0][nb], 0,0,0);
      acc[0][nb] = __builtin_amdgcn_mfma_f32_16x16x32_bf16(ah0, bl, acc[0][nb], 0,0,0);
      acc[0][nb] = __builtin_amdgcn_mfma_f32_16x16x32_bf16(al0, bh, acc[0][nb], 0,0,0);
      acc[1][nb] = __builtin_amdgcn_mfma_f32_16x16x32_bf16(ah1, bh, acc[1][nb], 0,0,0);
      acc[1][nb] = __builtin_amdgcn_mfma_f32_16x16x32_bf16(ah1, bl, acc[1][nb], 0,0,0);
      acc[1][nb] = __builtin_amdgcn_mfma_f32_16x16x32_bf16(al1, bh, acc[1][nb], 0,0,0);
    }
  }
  int n16 = lane & 15;
  #pragma unroll
  for (int mg=0; mg<2; ++mg){
    #pragma unroll
    for (int r=0; r<4; ++r){
      int P = Pbase + mg*16 + q*4 + r;
      if (P < 4752){
        int nn = P/396, pim = P%396;
        for (int nb=0; nb<nbN; ++nb){
          int co = cog*64 + nb*16 + n16;
          float v = acc[mg][nb][r];
          if (co < 40)
            dep[((size_t)nn*40 + co)*396 + pim] = v + dhb[co];
          else if (co < 104)
            ctx2[((size_t)nn*396 + pim)*64 + (co-40)] = v + chb[co-40];
        }
      }
    }
  }
}

// ---------- softmax over 40 depth channels ----------
__global__ __launch_bounds__(256) void k_softmax40(float* __restrict__ dep)
{
  int i = blockIdx.x*256 + threadIdx.x;
  if (i >= 12*396) return;
  int n = i/396, p = i%396;
  float* base = dep + (size_t)n*40*396 + p;
  float mx = -1e30f;
  for (int d=0; d<40; ++d) mx = fmaxf(mx, base[(size_t)d*396]);
  float s = 0.f;
  for (int d=0; d<40; ++d){ float e = expf(base[(size_t)d*396]-mx); base[(size_t)d*396]=e; s+=e; }
  float inv = 1.f/s;
  for (int d=0; d<40; ++d) base[(size_t)d*396] *= inv;
}

// ---------- geometry + count (fused) ----------
__global__ __launch_bounds__(256) void k_geom(
    const float* __restrict__ rots, const float* __restrict__ trans,
    const float* __restrict__ intr, int* __restrict__ vox, int* __restrict__ cnt)
{
  int pt = blockIdx.x*256 + threadIdx.x;
  if (pt >= 190080) return;
  int b = pt/95040; int r = pt%95040;
  int n = r/15840;  int r2 = r%15840;
  int d = r2/396;   int pim = r2%396;
  int y = pim/33, x = pim%33;
  int bn = b*6+n;
  const float* R = rots + (size_t)bn*9;
  const float* T = trans + (size_t)bn*3;
  const float* K = intr + (size_t)bn*9;
  float fx=K[0], cx=K[2], fy=K[4], cy=K[5];
  float xs = (float)x * 32.96875f;
  float ys = (float)((double)y * (383.0/11.0));
  float dv = 4.0f + (float)d;
  float camx = (xs-cx)*dv/fx;
  float camy = (ys-cy)*dv/fy;
  float gx = R[0]*camx + R[1]*camy + R[2]*dv + T[0];
  float gy = R[3]*camx + R[4]*camy + R[5]*dv + T[1];
  float gz = R[6]*camx + R[7]*camy + R[8]*dv + T[2];
  int ix = (int)floorf(gx + 50.f);
  int iy = (int)floorf(gy + 50.f);
  int iz = (int)floorf((gz + 10.f)/5.f);
  bool valid = (ix>=0 && ix<100 && iy>=0 && iy<100 && iz>=0 && iz<4);
  int sid = iz*10000 + ix*100 + iy;
  vox[pt] = valid ? sid : -1;
  if (valid) atomicAdd(&cnt[b*40000 + sid], 1);
}

// ---------- scan ----------
__global__ __launch_bounds__(256) void k_scan1(
    const int* __restrict__ cnt, int* __restrict__ off, int* __restrict__ bsum)
{
  __shared__ int s[256];
  int t = threadIdx.x;
  int i = blockIdx.x*256 + t;
  int v = (i < 80000) ? cnt[i] : 0;
  s[t] = v; __syncthreads();
  for (int o=1;o<256;o<<=1){
    int x = (t>=o) ? s[t-o] : 0;
    __syncthreads();
    s[t] += x;
    __syncthreads();
  }
  if (i < 80000) off[i] = s[t] - v;
  if (t == 255) bsum[blockIdx.x] = s[255];
}

__global__ void k_scan2(int* __restrict__ bsum, int nblk)
{
  if (threadIdx.x==0 && blockIdx.x==0){
    int run = 0;
    for (int j=0;j<nblk;++j){ int t = bsum[j]; bsum[j] = run; run += t; }
  }
}

__global__ __launch_bounds__(256) void k_scan3(
    int* __restrict__ off, const int* __restrict__ bsum, int* __restrict__ cur)
{
  int i = blockIdx.x*256 + threadIdx.x;
  if (i >= 80000) return;
  int o = off[i] + bsum[i>>8];
  off[i] = o;
  cur[i] = o;
}

__global__ __launch_bounds__(256) void k_fill(
    const int* __restrict__ vox, int* __restrict__ cur, int* __restrict__ list)
{
  int pt = blockIdx.x*256 + threadIdx.x;
  if (pt >= 190080) return;
  int s = vox[pt];
  if (s < 0) return;
  int b = pt/95040;
  int slot = atomicAdd(&cur[b*40000 + s], 1);
  list[slot] = pt;
}

// ---------- zero the padding ring of Ah/Al ----------
__global__ __launch_bounds__(256) void k_zero_ring(hb* __restrict__ Ah, hb* __restrict__ Al)
{
  int i = blockIdx.x*256 + threadIdx.x;
  if (i >= 2*404*256) return;
  int c = i & 255;
  int t = i >> 8;
  int b = t / 404;
  int ridx = t % 404;
  int py, px;
  if (ridx < 102){ py = 0; px = ridx; }
  else if (ridx < 204){ py = 101; px = ridx-102; }
  else if (ridx < 304){ py = ridx-204+1; px = 0; }
  else { py = ridx-304+1; px = 101; }
  size_t o = (((size_t)b*102 + py)*102 + px)*256 + c;
  hb z = __float2bfloat16(0.f);
  Ah[o] = z; Al[o] = z;
}

// ---------- gather: one wave per (b,sid), lane=channel; writes bev fp32 + Ah/Al bf16 ----------
__global__ __launch_bounds__(256) void k_gather(
    const int* __restrict__ off, const int* __restrict__ cnt, const int* __restrict__ list,
    const float* __restrict__ ctx2, const float* __restrict__ dep, float* __restrict__ bev,
    hb* __restrict__ Ah, hb* __restrict__ Al)
{
  int tid = threadIdx.x;
  int bv = blockIdx.x*4 + (tid>>6);
  int c = tid & 63;
  int b = bv/40000, sid = bv%40000;
  int st = off[bv], nn = cnt[bv];
  float s = 0.f;
  for (int k=0;k<nn;++k){
    int pt = list[st+k];
    int r = pt%95040;
    int bn = b*6 + r/15840;
    int r2 = r%15840;
    int dd = r2/396, pim = r2%396;
    s += ctx2[((size_t)bn*396+pim)*64 + c] * dep[((size_t)bn*40+dd)*396 + pim];
  }
  int iz = sid/10000, rem = sid%10000;
  bev[(size_t)b*2560000 + (size_t)iz*640000 + (size_t)c*10000 + rem] = s;
  int ix = rem/100, iy = rem%100;
  size_t oh = (((size_t)b*102 + (ix+1))*102 + (iy+1))*256 + iz*64 + c;
  hb hv, lv; split2(s, &hv, &lv);
  Ah[oh] = hv; Al[oh] = lv;
}

// ---------- NCHW fp32 (*g) -> padded NHWC bf16 hi/lo, coalesced LDS transpose ----------
__global__ __launch_bounds__(256) void k_tohwc2(
    const float* __restrict__ in, hb* __restrict__ Ah, hb* __restrict__ Al,
    const float* __restrict__ g)
{
  __shared__ float tile[32*105];
  int py = blockIdx.x;
  int b  = blockIdx.y;
  int cg = blockIdx.z;
  int tid = threadIdx.x;
  bool inner = (py >= 1 && py <= 100);
  if (inner){
    if (tid < 64){ int cil = tid & 31; int col = (tid>>5) ? 101 : 0; tile[cil*105 + col] = 0.f; }
    for (int i = tid; i < 3200; i += 256){
      int cil = i / 100, x = i % 100;
      int ci = cg*32 + cil;
      tile[cil*105 + (x+1)] = in[(((size_t)b*256 + ci)*100 + (py-1))*100 + x];
    }
  }
  __syncthreads();
  for (int i = tid; i < 32*102; i += 256){
    int px = i >> 5, cil = i & 31;
    int ci = cg*32 + cil;
    float v = 0.f;
    if (inner){
      v = tile[cil*105 + px];
      if (g) v *= g[b*256 + ci];
    }
    hb hv, lv; split2(v, &hv, &lv);
    size_t o = (((size_t)b*102 + py)*102 + px)*256 + ci;
    Ah[o] = hv; Al[o] = lv;
  }
}

// ---------- row mean (NCHW rows) ----------
__global__ __launch_bounds__(256) void k_rowmean(
    const float* __restrict__ in, float* __restrict__ out, int rowlen, float inv)
{
  __shared__ float ws[4];
  int row = blockIdx.x; int t = threadIdx.x;
  const float* p = in + (size_t)row*rowlen;
  float s = 0.f;
  for (int i=t; i<rowlen; i+=256) s += p[i];
  #pragma unroll
  for (int off=32; off; off>>=1) s += __shfl_down(s, off);
  if ((t&63)==0) ws[t>>6] = s;
  __syncthreads();
  if (t==0) out[row] = (ws[0]+ws[1]+ws[2]+ws[3]) * inv;
}

// ---------- BEV MFMA conv, LDS A-staging, B double-buffer ----------
__global__ __launch_bounds__(256) void k_conv3_bevm(
    const hb* __restrict__ Ah, const hb* __restrict__ Al,
    const hb* __restrict__ Wph, const hb* __restrict__ Wpl,
    const float* __restrict__ bns, const float* __restrict__ bnb,
    const float* __restrict__ res, float* __restrict__ out, int Cout, int NBG)
{
  __shared__ __align__(16) short sAh[10*18*44];
  __shared__ __align__(16) short sAl[10*18*44];
  __shared__ short8 lbh[2][256], lbl[2][256];
  const int NB = Cout >> 4;
  int tid = threadIdx.x;
  int wv = tid >> 6, lane = tid & 63;
  int L = blockIdx.x;
  int spatial = L / (NBG*2);
  int rem = L % (NBG*2);
  int cog = rem % NBG;
  int bb  = rem / NBG;
  int xg = spatial % 7, yg = spatial / 7;
  int x0 = xg*16;
  int y0 = yg*8 + wv;
  int m = lane & 15, q = lane >> 4;
  int nb0 = cog*4;
  floatx4 acc[2][4];
  #pragma unroll
  for (int i=0;i<2;++i)
    #pragma unroll
    for (int j=0;j<4;++j) acc[i][j] = (floatx4)(0.f);

  const short8* gAh = (const short8*)(const void*)Ah;
  const short8* gAl = (const short8*)(const void*)Al;
  const short8* gWh = (const short8*)(const void*)Wph;
  const short8* gWl = (const short8*)(const void*)Wpl;
  const size_t nbstride = (size_t)NB*64;
  const size_t sb = (size_t)(nb0 + wv)*64 + lane;

  short8 ph = gWh[sb], pl = gWl[sb];
  int cur = 0;

  for (int kb=0; kb<8; ++kb){
    #pragma unroll 3
    for (int tap=0; tap<9; ++tap){
      int idx2 = kb*9 + tap;
      if (tap == 0){
        __syncthreads();
        for (int i = tid; i < 720; i += 256){
          int rc = i >> 2, part = i & 3;
          int r = rc / 18, c = rc % 18;
          int yr = yg*8 + r; if (yr > 101) yr = 101;
          int xc = x0 + c;   if (xc > 101) xc = 101;
          size_t so = ((size_t)((bb*102 + yr)*102 + xc))*32 + kb*4 + part;
          short8 vh = gAh[so], vl = gAl[so];
          int dst = (r*18 + c)*44 + part*8;
          *(short8*)(sAh + dst) = vh;
          *(short8*)(sAl + dst) = vl;
        }
      }
      lbh[cur][tid] = ph; lbl[cur][tid] = pl;
      int nx = (idx2+1 < 72) ? idx2+1 : 71;
      ph = gWh[(size_t)nx*nbstride + sb];
      pl = gWl[(size_t)nx*nbstride + sb];
      __syncthreads();
      int dy = (tap*11) >> 5;
      int dx = tap - dy*3;
      int cc = dx + m;
      int a0 = ((wv + dy)*18 + cc)*44 + q*8;
      int a1 = ((wv + 4 + dy)*18 + cc)*44 + q*8;
      short8 cah0 = *(const short8*)(sAh + a0);
      short8 cal0 = *(const short8*)(sAl + a0);
      short8 cah1 = *(const short8*)(sAh + a1);
      short8 cal1 = *(const short8*)(sAl + a1);
      #pragma unroll
      for (int nb=0; nb<4; ++nb){
        short8 bh = lbh[cur][nb*64 + lane];
        short8 bl = lbl[cur][nb*64 + lane];
        acc[0][nb] = __builtin_amdgcn_mfma_f32_16x16x32_bf16(cah0, bh, acc[0][nb], 0,0,0);
        acc[0][nb] = __builtin_amdgcn_mfma_f32_16x16x32_bf16(cah0, bl, acc[0][nb], 0,0,0);
        acc[0][nb] = __builtin_amdgcn_mfma_f32_16x16x32_bf16(cal0, bh, acc[0][nb], 0,0,0);
        acc[1][nb] = __builtin_amdgcn_mfma_f32_16x16x32_bf16(cah1, bh, acc[1][nb], 0,0,0);
        acc[1][nb] = __builtin_amdgcn_mfma_f32_16x16x32_bf16(cah1, bl, acc[1][nb], 0,0,0);
        acc[1][nb] = __builtin_amdgcn_mfma_f32_16x16x32_bf16(cal1, bh, acc[1][nb], 0,0,0);
      }
      cur ^= 1;
    }
  }

  int n = lane & 15;
  int xq = x0 + q*4;
  #pragma unroll
  for (int mg=0; mg<2; ++mg){
    int yo = y0 + mg*4;
    if (yo < 100 && xq < 100){
      #pragma unroll
      for (int nb=0; nb<4; ++nb){
        int co = cog*64 + nb*16 + n;
        float s = bns[co], bv = bnb[co];
        floatx4 a = acc[mg][nb];
        float4 v;
        v.x = fmaxf(a[0]*s+bv, 0.f);
        v.y = fmaxf(a[1]*s+bv, 0.f);
        v.z = fmaxf(a[2]*s+bv, 0.f);
        v.w = fmaxf(a[3]*s+bv, 0.f);
        size_t o = ((size_t)(bb*Cout+co)*100 + yo)*100 + xq;
        if (res){
          float4 rv = *(const float4*)(res + o);
          v.x += rv.x; v.y += rv.y; v.z += rv.z; v.w += rv.w;
        }
        *(float4*)(out + o) = v;
      }
    }
  }
}

// ---------- final 1x1 conv 128->16, one pass over h3 ----------
__global__ __launch_bounds__(256) void k_final2(
    const float* __restrict__ h, const float* __restrict__ W, const float* __restrict__ bias,
    float* __restrict__ out)
{
  __shared__ float wsl[2048];
  __shared__ float bs[16];
  int tid = threadIdx.x;
  int b = blockIdx.y;
  for (int i=tid; i<2048; i+=256) wsl[i] = W[i];
  if (tid < 16) bs[tid] = bias[tid];
  __syncthreads();
  int pix = blockIdx.x*256 + tid;
  if (pix >= 10000) return;
  float acc[16];
  #pragma unroll
  for (int oc=0; oc<16; ++oc) acc[oc] = bs[oc];
  const float* hb_ = h + (size_t)b*128*10000 + pix;
  for (int ci=0; ci<128; ++ci){
    float hv = hb_[(size_t)ci*10000];
    #pragma unroll
    for (int oc=0; oc<16; ++oc) acc[oc] += hv * wsl[oc*128 + ci];
  }
  #pragma unroll
  for (int oc=0; oc<16; ++oc)
    out[((size_t)(b*16+oc))*10000 + pix] = acc[oc];
}

extern "C" void kernel_launch(void* const* d_in, const int* in_sizes, int n_in,
                              void* d_out, int out_size, void* d_ws, size_t ws_size,
                              hipStream_t stream)
{
  (void)in_sizes; (void)n_in; (void)out_size; (void)ws_size;
  const float* feats = (const float*)d_in[0];
  const float* rots  = (const float*)d_in[1];
  const float* trans = (const float*)d_in[2];
  const float* intr  = (const float*)d_in[3];
  const float* nw1   = (const float*)d_in[4];
  const float* bn1s  = (const float*)d_in[5];
  const float* bn1b  = (const float*)d_in[6];
  const float* se1w1 = (const float*)d_in[7];
  const float* se1b1 = (const float*)d_in[8];
  const float* se1w2 = (const float*)d_in[9];
  const float* se1b2 = (const float*)d_in[10];
  const float* nw2   = (const float*)d_in[11];
  const float* bn2s  = (const float*)d_in[12];
  const float* bn2b  = (const float*)d_in[13];
  const float* dhw   = (const float*)d_in[14];
  const float* dhb   = (const float*)d_in[15];
  const float* chw   = (const float*)d_in[16];
  const float* chb   = (const float*)d_in[17];
  const float* bcw1  = (const float*)d_in[18];
  const float* bcs1  = (const float*)d_in[19];
  const float* bcb1  = (const float*)d_in[20];
  const float* bcsw1 = (const float*)d_in[21];
  const float* bcsb1 = (const float*)d_in[22];
  const float* bcsw2 = (const float*)d_in[23];
  const float* bcsb2 = (const float*)d_in[24];
  const float* bcw2  = (const float*)d_in[25];
  const float* bcs2  = (const float*)d_in[26];
  const float* bcb2  = (const float*)d_in[27];
  const float* dw1   = (const float*)d_in[28];
  const float* ds1   = (const float*)d_in[29];
  const float* db1   = (const float*)d_in[30];
  const float* dw2   = (const float*)d_in[31];
  const float* db2   = (const float*)d_in[32];
  float* out = (float*)d_out;

  // ---- workspace layout (float units) ----
  float* ws = (float*)d_ws;
  float* bev   = ws;                       // S0: 5,120,000
  float* h1    = ws + 5120000;             // S1: 5,120,000
  hb*    Ah    = (hb*)(ws + 10240000);     // S2: 2,663,424 fu
  hb*    Al    = (hb*)(ws + 12903424);     // S3: 2,663,424 fu
  float* x2    = ws + 15566848;            // S4: 1,216,512
  float* S5    = ws + 16783360;            // 589,824
  float* dep   = ws + 17373184;            // 190,080
  float* ctx2  = ws + 17563264;            // 304,128
  float* mean1 = ws + 17867392;            // 3072
  float* g1    = mean1 + 3072;
  float* mean2 = g1 + 3072;
  float* g2    = mean2 + 512;
  int*   vox   = (int*)(ws + 17875584);    // 190,080 ints
  // phase aliases
  hb* Fph  = (hb*)bev;                     // 3,041,280 fu
  hb* Wc1h = (hb*)(bev + 3041280);         // 163,840 fu
  hb* Wc1l = (hb*)(bev + 3205120);         // 163,840 fu
  float* x1 = h1;
  hb* Fpl  = (hb*)(h1 + 1216512);          // 3,041,280 fu
  hb* Xh   = (hb*)Ah;
  hb* Xl   = (hb*)Al;
  hb* Wc2h = (hb*)S5;                      // 294,912 fu
  hb* Wc2l = (hb*)(S5 + 294912);           // 294,912 fu
  hb* x2h  = (hb*)x2;                      // 608,256 fu
  hb* x2l  = (hb*)(x2 + 608256);
  hb* Whh  = (hb*)S5;
  hb* Whl  = (hb*)(S5 + 14336);
  int* cnt  = (int*)h1;
  int* off  = cnt + 80000;
  int* cur  = off + 80000;
  int* bsum = cur + 80000;
  int* list = bsum + 1024;
  float* h3 = h1;
  hb* Wp1h = (hb*)x2;
  hb* Wp1l = (hb*)(x2 + 294912);
  hb* Wp3h = (hb*)(x2 + 589824);
  hb* Wp3l = (hb*)(x2 + 589824 + 147456);
  hb* Wp2h = (hb*)S5;
  hb* Wp2l = (hb*)(S5 + 294912);

  // ---- image branch (MFMA) ----
  k_trans_featsP<<<dim3(7,20,12),256,0,stream>>>(feats,Fph,Fpl);
  k_wpackE<<<3584,256,0,stream>>>(nw1,nw2,Wc1h,Wc1l,Wc2h,Wc2l);
  k_mfma_gemm1<<<dim3(38,4),256,0,stream>>>(Fph,Fpl,Wc1h,Wc1l,bn1s,bn1b,x1);
  k_meanse<<<12,256,0,stream>>>(x1,se1w1,se1b1,se1w2,se1b2,g1);
  k_topad<<<dim3(14,12),256,0,stream>>>(x1,g1,Xh,Xl);
  k_conv3_img<<<dim3(3,24,4),256,0,stream>>>(Xh,Xl,Wc2h,Wc2l,bn2s,bn2b,x2h,x2l);
  k_wpackH<<<112,256,0,stream>>>(dhw,chw,Whh,Whl);
  k_headsM<<<dim3(38,2),256,0,stream>>>(x2h,x2l,Whh,Whl,dhb,chb,dep,ctx2);
  k_softmax40<<<19,256,0,stream>>>(dep);

  // ---- pack BEV conv weights kb-major (x2h/l, Wh dead now) ----
  k_wpackT3<<<5760,256,0,stream>>>(bcw1,bcw2,dw1,Wp1h,Wp1l,Wp2h,Wp2l,Wp3h,Wp3l);

  // ---- lift-splat (gather form; fused bf16 NHWC pack) ----
  hipMemsetAsync(cnt, 0, 80000*sizeof(int), stream);
  k_geom<<<(190080+255)/256,256,0,stream>>>(rots,trans,intr,vox,cnt);
  k_scan1<<<313,256,0,stream>>>(cnt,off,bsum);
  k_scan2<<<1,64,0,stream>>>(bsum,313);
  k_scan3<<<(80000+255)/256,256,0,stream>>>(off,bsum,cur);
  k_fill<<<(190080+255)/256,256,0,stream>>>(vox,cur,list);
  k_zero_ring<<<808,256,0,stream>>>(Ah,Al);
  k_gather<<<20000,256,0,stream>>>(off,cnt,list,ctx2,dep,bev,Ah,Al);

  // ---- BEV encoder (MFMA convs) ----
  k_conv3_bevm<<<728,256,0,stream>>>(Ah,Al,Wp1h,Wp1l,bcs1,bcb1,nullptr,h1,256,4);
  k_rowmean<<<512,256,0,stream>>>(h1,mean2,10000,1e-4f);
  k_se_fc<<<2,256,0,stream>>>(mean2,bcsw1,bcsb1,bcsw2,bcsb2,g2,16);
  k_tohwc2<<<dim3(102,2,8),256,0,stream>>>(h1,Ah,Al,g2);
  k_conv3_bevm<<<728,256,0,stream>>>(Ah,Al,Wp2h,Wp2l,bcs2,bcb2,bev,bev,256,4);
  k_tohwc2<<<dim3(102,2,8),256,0,stream>>>(bev,Ah,Al,nullptr);
  k_conv3_bevm<<<364,256,0,stream>>>(Ah,Al,Wp3h,Wp3l,ds1,db1,nullptr,h3,128,2);
  k_final2<<<dim3(40,2),256,0,stream>>>(h3,dw2,db2,out);
}

// Round 12
// 631.440 us; speedup vs baseline: 1.1362x; 1.0634x over previous
//
#include <hip/hip_runtime.h>
#include <hip/hip_bf16.h>
#include <cmath>

// LSS pipeline R12: conv3_bevm restructured — wave = 2co-blocks x 4y-rows,
// B-frags direct from global (register prefetch, no B-LDS, 16 barriers/block
// vs 80); parallel k_scan2.

typedef __attribute__((ext_vector_type(8))) short short8;
typedef __attribute__((ext_vector_type(4))) float floatx4;
typedef __hip_bfloat16 hb;

__device__ __forceinline__ float sigf(float x){ return 1.0f/(1.0f+expf(-x)); }
__device__ __forceinline__ float siluf(float x){ return x*sigf(x); }
__device__ __forceinline__ void split2(float v, hb* h, hb* l){
  hb hv = __float2bfloat16(v);
  *h = hv; *l = __float2bfloat16(v - __bfloat162float(hv));
}

// ---------- feats NCHW -> A-frag-packed bf16 hi/lo Fp[(T*40+kb)*64+lane][8] ----------
__global__ __launch_bounds__(256) void k_trans_featsP(
    const float* __restrict__ feats, hb* __restrict__ Fph, hb* __restrict__ Fpl)
{
  __shared__ float tile[64][65];
  int n = blockIdx.z;
  int p0 = blockIdx.x*64;
  int c0 = blockIdx.y*64;
  int tid = threadIdx.x;
  int tr = tid >> 6;
  int tc = tid & 63;
  #pragma unroll
  for (int it=0; it<16; ++it){
    int ci = c0 + it*4 + tr;
    int p = p0 + tc;
    float v = 0.f;
    if (p < 396) v = feats[((size_t)n*1280 + ci)*396 + p];
    tile[it*4+tr][tc] = v;
  }
  __syncthreads();
  #pragma unroll
  for (int iter=0; iter<2; ++iter){
    int idx = iter*256 + tid;
    int oc = idx >> 6;
    int pl = idx & 63;
    int p = p0 + pl;
    if (p < 396){
      int P = n*396 + p;
      int T = P >> 4, mm = P & 15;
      int kb = (c0 >> 5) + (oc >> 2);
      int q = oc & 3;
      int lane = q*16 + mm;
      size_t o = (((size_t)T*40 + kb)*64 + lane)*8;
      #pragma unroll
      for (int j=0; j<8; ++j){
        hb hv, lv; split2(tile[oc*8+j][pl], &hv, &lv);
        Fph[o+j] = hv; Fpl[o+j] = lv;
      }
    }
  }
}

// ---------- merged early packs: conv1 weights + image 3x3 weights (kb-major) ----------
__global__ __launch_bounds__(256) void k_wpackE(
    const float* __restrict__ nw1, const float* __restrict__ nw2,
    hb* __restrict__ Wc1h, hb* __restrict__ Wc1l,
    hb* __restrict__ Wc2h, hb* __restrict__ Wc2l)
{
  int i = blockIdx.x*256 + threadIdx.x;
  if (i < 327680){
    int j = i & 7;
    int lane = (i>>3) & 63;
    int t2 = i >> 9;
    int nb = t2 & 15;
    int kb = t2 >> 4;
    int ci = kb*32 + (lane>>4)*8 + j;
    int co = nb*16 + (lane&15);
    hb hv, lv; split2(nw1[(size_t)co*1280 + ci], &hv, &lv);
    Wc1h[i] = hv; Wc1l[i] = lv;
  } else {
    int i2 = i - 327680;
    if (i2 >= 589824) return;
    int j = i2 & 7;
    int t1 = i2 >> 3;
    int lane = t1 & 63;
    int t2 = t1 >> 6;
    int nb = t2 % 16;
    int t3 = t2 / 16;
    int tap = t3 % 9;
    int kb = t3 / 9;
    int ci = kb*32 + (lane>>4)*8 + j;
    int co = nb*16 + (lane&15);
    hb hv, lv; split2(nw2[(size_t)co*2304 + ci*9 + tap], &hv, &lv);
    Wc2h[i2] = hv; Wc2l[i2] = lv;
  }
}

// ---------- merged BEV packs kb-major ----------
__global__ __launch_bounds__(256) void k_wpackT3(
    const float* __restrict__ bcw1, const float* __restrict__ bcw2,
    const float* __restrict__ dw1,
    hb* __restrict__ W1h, hb* __restrict__ W1l,
    hb* __restrict__ W2h, hb* __restrict__ W2l,
    hb* __restrict__ W3h, hb* __restrict__ W3l)
{
  int gi = blockIdx.x*256 + threadIdx.x;
  const float* W; hb* Wh; hb* Wl; int NB; int i;
  if (gi < 589824){ W = bcw1; Wh = W1h; Wl = W1l; NB = 16; i = gi; }
  else if (gi < 1179648){ W = bcw2; Wh = W2h; Wl = W2l; NB = 16; i = gi - 589824; }
  else if (gi < 1474560){ W = dw1; Wh = W3h; Wl = W3l; NB = 8; i = gi - 1179648; }
  else return;
  int j = i & 7;
  int t1 = i >> 3;
  int lane = t1 & 63;
  int t2 = t1 >> 6;
  int nb = t2 % NB;
  int t3 = t2 / NB;
  int tap = t3 % 9;
  int kb = t3 / 9;
  int ci = kb*32 + (lane>>4)*8 + j;
  int co = nb*16 + (lane&15);
  hb hv, lv; split2(W[(size_t)co*2304 + ci*9 + tap], &hv, &lv);
  Wh[i] = hv; Wl[i] = lv;
}

// ---------- pack heads weights ----------
__global__ __launch_bounds__(256) void k_wpackH(
    const float* __restrict__ dhw, const float* __restrict__ chw,
    hb* __restrict__ Wph, hb* __restrict__ Wpl)
{
  int i = blockIdx.x*256 + threadIdx.x;
  if (i >= 8*7*512) return;
  int j = i & 7;
  int t1 = i >> 3;
  int lane = t1 & 63;
  int t2 = t1 >> 6;
  int nb = t2 % 7;
  int kb = t2 / 7;
  int ci = kb*32 + (lane>>4)*8 + j;
  int co = nb*16 + (lane&15);
  float w = 0.f;
  if (co < 40) w = dhw[(size_t)co*256 + ci];
  else if (co < 104) w = chw[(size_t)(co-40)*256 + ci];
  hb hv, lv; split2(w, &hv, &lv);
  Wph[i] = hv; Wpl[i] = lv;
}

// ---------- conv1 as MFMA GEMM on frag-packed A; BN+SiLU; out NHWC ----------
__global__ __launch_bounds__(256) void k_mfma_gemm1(
    const hb* __restrict__ Fph, const hb* __restrict__ Fpl,
    const hb* __restrict__ Wph, const hb* __restrict__ Wpl,
    const float* __restrict__ bns, const float* __restrict__ bnb,
    float* __restrict__ out)
{
  __shared__ short8 lbh[256], lbl[256];
  int tid = threadIdx.x;
  int wv = tid >> 6, lane = tid & 63;
  int cog = blockIdx.y;
  int Pbase = blockIdx.x*128 + wv*32;
  int q = lane >> 4;
  int T0 = blockIdx.x*8 + wv*2; if (T0 > 296) T0 = 296;
  int T1 = T0 + 1;              if (T1 > 296) T1 = 296;
  size_t a0 = (size_t)T0*2560 + lane;
  size_t a1 = (size_t)T1*2560 + lane;
  const short8* gAh = (const short8*)(const void*)Fph;
  const short8* gAl = (const short8*)(const void*)Fpl;
  const short8* gWh = (const short8*)(const void*)Wph;
  const short8* gWl = (const short8*)(const void*)Wpl;
  size_t sb = (size_t)(cog*4 + wv)*64 + lane;
  floatx4 acc[2][4];
  #pragma unroll
  for (int i=0;i<2;++i)
    #pragma unroll
    for (int j=0;j<4;++j) acc[i][j] = (floatx4)(0.f);
  short8 ph = gWh[sb], pw = gWl[sb];
  short8 cah0 = gAh[a0], cal0 = gAl[a0], cah1 = gAh[a1], cal1 = gAl[a1];
  for (int kb=0; kb<40; ++kb){
    __syncthreads();
    lbh[tid] = ph; lbl[tid] = pw;
    int nx = (kb+1 < 40) ? kb+1 : 39;
    ph = gWh[(size_t)nx*1024 + sb]; pw = gWl[(size_t)nx*1024 + sb];
    __syncthreads();
    short8 nah0 = gAh[a0 + (size_t)nx*64];
    short8 nal0 = gAl[a0 + (size_t)nx*64];
    short8 nah1 = gAh[a1 + (size_t)nx*64];
    short8 nal1 = gAl[a1 + (size_t)nx*64];
    #pragma unroll
    for (int nb=0; nb<4; ++nb){
      short8 bh = lbh[nb*64 + lane];
      short8 bl = lbl[nb*64 + lane];
      acc[0][nb] = __builtin_amdgcn_mfma_f32_16x16x32_bf16(cah0, bh, acc[0][nb], 0,0,0);
      acc[0][nb] = __builtin_amdgcn_mfma_f32_16x16x32_bf16(cah0, bl, acc[0][nb], 0,0,0);
      acc[0][nb] = __builtin_amdgcn_mfma_f32_16x16x32_bf16(cal0, bh, acc[0][nb], 0,0,0);
      acc[1][nb] = __builtin_amdgcn_mfma_f32_16x16x32_bf16(cah1, bh, acc[1][nb], 0,0,0);
      acc[1][nb] = __builtin_amdgcn_mfma_f32_16x16x32_bf16(cah1, bl, acc[1][nb], 0,0,0);
      acc[1][nb] = __builtin_amdgcn_mfma_f32_16x16x32_bf16(cal1, bh, acc[1][nb], 0,0,0);
    }
    cah0 = nah0; cal0 = nal0; cah1 = nah1; cal1 = nal1;
  }
  int n16 = lane & 15;
  #pragma unroll
  for (int mg=0; mg<2; ++mg){
    #pragma unroll
    for (int nb=0; nb<4; ++nb){
      int co = cog*64 + nb*16 + n16;
      float s = bns[co], bv = bnb[co];
      #pragma unroll
      for (int r=0; r<4; ++r){
        int P = Pbase + mg*16 + q*4 + r;
        if (P < 4752) out[(size_t)P*256 + co] = siluf(acc[mg][nb][r]*s + bv);
      }
    }
  }
}

// ---------- fused mean(396) + SE FC (image branch) ----------
__global__ __launch_bounds__(256) void k_meanse(
    const float* __restrict__ x1, const float* __restrict__ w1, const float* __restrict__ b1,
    const float* __restrict__ w2, const float* __restrict__ b2, float* __restrict__ g)
{
  __shared__ float m[256];
  __shared__ float h[32];
  int n = blockIdx.x; int t = threadIdx.x;
  float s = 0.f;
  for (int p=0; p<396; ++p) s += x1[((size_t)n*396+p)*256 + t];
  m[t] = s*(1.f/396.f);
  __syncthreads();
  if (t < 32){
    float s2 = b1[t];
    for (int c=0; c<256; ++c) s2 += m[c]*w1[t*256+c];
    h[t] = siluf(s2);
  }
  __syncthreads();
  float s3 = b2[t];
  for (int j=0; j<32; ++j) s3 += h[j]*w2[t*32+j];
  g[n*256+t] = sigf(s3);
}

// ---------- SE FC (BEV, H=16) ----------
__global__ __launch_bounds__(256) void k_se_fc(
    const float* __restrict__ mean, const float* __restrict__ w1, const float* __restrict__ b1,
    const float* __restrict__ w2, const float* __restrict__ b2, float* __restrict__ g, int H)
{
  __shared__ float m[256];
  __shared__ float h[32];
  int n = blockIdx.x; int t = threadIdx.x;
  m[t] = mean[n*256 + t];
  __syncthreads();
  if (t < H){
    float s = b1[t];
    for (int c=0; c<256; ++c) s += m[c]*w1[t*256+c];
    h[t] = siluf(s);
  }
  __syncthreads();
  float s = b2[t];
  for (int j=0; j<H; ++j) s += h[j]*w2[t*H+j];
  g[n*256+t] = sigf(s);
}

// ---------- x1 NHWC * g -> padded [n][14][35][256] bf16 hi/lo ----------
__global__ __launch_bounds__(256) void k_topad(
    const float* __restrict__ x1, const float* __restrict__ g,
    hb* __restrict__ Xh, hb* __restrict__ Xl)
{
  int y = blockIdx.x;
  int n = blockIdx.y;
  int c = threadIdx.x;
  float gc = g[n*256+c];
  for (int xx=0; xx<35; ++xx){
    float v = 0.f;
    if (y>=1 && y<=12 && xx>=1 && xx<=33)
      v = x1[((size_t)n*396 + (y-1)*33 + (xx-1))*256 + c]*gc;
    hb hv, lv; split2(v, &hv, &lv);
    size_t o = (((size_t)n*14+y)*35+xx)*256 + c;
    Xh[o] = hv; Xl[o] = lv;
  }
}

// ---------- image 3x3 conv, LDS-staged MFMA ----------
__global__ __launch_bounds__(256) void k_conv3_img(
    const hb* __restrict__ Xh, const hb* __restrict__ Xl,
    const hb* __restrict__ Wph, const hb* __restrict__ Wpl,
    const float* __restrict__ bns, const float* __restrict__ bnb,
    hb* __restrict__ outh, hb* __restrict__ outl)
{
  __shared__ __align__(16) short sAh[10*18*44];
  __shared__ __align__(16) short sAl[10*18*44];
  __shared__ short8 lbh[2][256], lbl[2][256];
  int tid = threadIdx.x;
  int wv = tid >> 6, lane = tid & 63;
  int xg = blockIdx.x;
  int n = blockIdx.y >> 1, yg = blockIdx.y & 1;
  int cog = blockIdx.z;
  int x0 = xg*16;
  int y0 = yg*8 + wv;
  int m = lane & 15, q = lane >> 4;
  floatx4 acc[2][4];
  #pragma unroll
  for (int i=0;i<2;++i)
    #pragma unroll
    for (int j=0;j<4;++j) acc[i][j] = (floatx4)(0.f);

  const short8* gAh = (const short8*)(const void*)Xh;
  const short8* gAl = (const short8*)(const void*)Xl;
  const short8* gWh = (const short8*)(const void*)Wph;
  const short8* gWl = (const short8*)(const void*)Wpl;
  const size_t sb = (size_t)(cog*4 + wv)*64 + lane;
  const size_t nbase = (size_t)n*14*35*32;

  short8 ph = gWh[sb], pl = gWl[sb];
  int cur = 0;

  for (int kb=0; kb<8; ++kb){
    #pragma unroll 3
    for (int tap=0; tap<9; ++tap){
      int idx2 = kb*9 + tap;
      if (tap == 0){
        __syncthreads();
        for (int i = tid; i < 720; i += 256){
          int rc = i >> 2, part = i & 3;
          int r = rc / 18, c2 = rc % 18;
          int yr = yg*8 + r; if (yr > 13) yr = 13;
          int xc = x0 + c2;  if (xc > 34) xc = 34;
          size_t so = nbase + (size_t)(yr*35 + xc)*32 + kb*4 + part;
          short8 vh = gAh[so], vl = gAl[so];
          int dst = (r*18 + c2)*44 + part*8;
          *(short8*)(sAh + dst) = vh;
          *(short8*)(sAl + dst) = vl;
        }
      }
      lbh[cur][tid] = ph; lbl[cur][tid] = pl;
      int nx = (idx2+1 < 72) ? idx2+1 : 71;
      ph = gWh[(size_t)nx*1024 + sb];
      pl = gWl[(size_t)nx*1024 + sb];
      __syncthreads();
      int dy = (tap*11) >> 5;
      int dx = tap - dy*3;
      int cc = dx + m;
      int a0 = ((wv + dy)*18 + cc)*44 + q*8;
      int a1 = ((wv + 4 + dy)*18 + cc)*44 + q*8;
      short8 cah0 = *(const short8*)(sAh + a0);
      short8 cal0 = *(const short8*)(sAl + a0);
      short8 cah1 = *(const short8*)(sAh + a1);
      short8 cal1 = *(const short8*)(sAl + a1);
      #pragma unroll
      for (int nb=0; nb<4; ++nb){
        short8 bh = lbh[cur][nb*64 + lane];
        short8 bl = lbl[cur][nb*64 + lane];
        acc[0][nb] = __builtin_amdgcn_mfma_f32_16x16x32_bf16(cah0, bh, acc[0][nb], 0,0,0);
        acc[0][nb] = __builtin_amdgcn_mfma_f32_16x16x32_bf16(cah0, bl, acc[0][nb], 0,0,0);
        acc[0][nb] = __builtin_amdgcn_mfma_f32_16x16x32_bf16(cal0, bh, acc[0][nb], 0,0,0);
        acc[1][nb] = __builtin_amdgcn_mfma_f32_16x16x32_bf16(cah1, bh, acc[1][nb], 0,0,0);
        acc[1][nb] = __builtin_amdgcn_mfma_f32_16x16x32_bf16(cah1, bl, acc[1][nb], 0,0,0);
        acc[1][nb] = __builtin_amdgcn_mfma_f32_16x16x32_bf16(cal1, bh, acc[1][nb], 0,0,0);
      }
      cur ^= 1;
    }
  }

  int n16 = lane & 15;
  #pragma unroll
  for (int mg=0; mg<2; ++mg){
    int oy = y0 + mg*4;
    if (oy < 12){
      #pragma unroll
      for (int r=0; r<4; ++r){
        int ox = x0 + q*4 + r;
        if (ox < 33){
          int P = n*396 + oy*33 + ox;
          #pragma unroll
          for (int nb=0; nb<4; ++nb){
            int co = cog*64 + nb*16 + n16;
            float v = siluf(acc[mg][nb][r]*bns[co] + bnb[co]);
            hb hv, lv; split2(v, &hv, &lv);
            outh[(size_t)P*256 + co] = hv;
            outl[(size_t)P*256 + co] = lv;
          }
        }
      }
    }
  }
}

// ---------- heads as MFMA GEMM ----------
__global__ __launch_bounds__(256) void k_headsM(
    const hb* __restrict__ x2h, const hb* __restrict__ x2l,
    const hb* __restrict__ Whh, const hb* __restrict__ Whl,
    const float* __restrict__ dhb, const float* __restrict__ chb,
    float* __restrict__ dep, float* __restrict__ ctx2)
{
  __shared__ short8 lbh[256], lbl[256];
  int tid = threadIdx.x;
  int wv = tid >> 6, lane = tid & 63;
  int cog = blockIdx.y;
  int nb0 = cog*4;
  int nbN = cog ? 3 : 4;
  int Pbase = blockIdx.x*128 + wv*32;
  int m = lane & 15, q = lane >> 4;
  int P0 = Pbase + m;      if (P0 > 4751) P0 = 4751;
  int P1 = Pbase + 16 + m; if (P1 > 4751) P1 = 4751;
  size_t rA0 = (size_t)P0*32 + q;
  size_t rA1 = (size_t)P1*32 + q;
  const short8* gAh = (const short8*)(const void*)x2h;
  const short8* gAl = (const short8*)(const void*)x2l;
  const short8* gWh = (const short8*)(const void*)Whh;
  const short8* gWl = (const short8*)(const void*)Whl;
  floatx4 acc[2][4];
  #pragma unroll
  for (int i=0;i<2;++i)
    #pragma unroll
    for (int j=0;j<4;++j) acc[i][j] = (floatx4)(0.f);
  for (int kb=0; kb<8; ++kb){
    __syncthreads();
    for (int i=tid; i<nbN*64; i+=256){
      lbh[i] = gWh[(size_t)(kb*7 + nb0)*64 + i];
      lbl[i] = gWl[(size_t)(kb*7 + nb0)*64 + i];
    }
    __syncthreads();
    short8 ah0 = gAh[rA0 + kb*4], al0 = gAl[rA0 + kb*4];
    short8 ah1 = gAh[rA1 + kb*4], al1 = gAl[rA1 + kb*4];
    for (int nb=0; nb<nbN; ++nb){
      short8 bh = lbh[nb*64 + lane];
      short8 bl = lbl[nb*64 + lane];
      acc[0][nb] = __builtin_amdgcn_mfma_f32_16x16x32_bf16(ah0, bh, acc[0][nb], 0,0,0);
      acc[0][nb] = __builtin_amdgcn_mfma_f32_16x16x32_bf16(ah0, bl, acc[0][nb], 0,0,0);
      acc[0][nb] = __builtin_amdgcn_mfma_f32_16x16x32_bf16(al0, bh, acc[0][nb], 0,0,0);
      acc[1][nb] = __builtin_amdgcn_mfma_f32_16x16x32_bf16(ah1, bh, acc[1][nb], 0,0,0);
      acc[1][nb] = __builtin_amdgcn_mfma_f32_16x16x32_bf16(ah1, bl, acc[1][nb], 0,0,0);
      acc[1][nb] = __builtin_amdgcn_mfma_f32_16x16x32_bf16(al1, bh, acc[1][nb], 0,0,0);
    }
  }
  int n16 = lane & 15;
  #pragma unroll
  for (int mg=0; mg<2; ++mg){
    #pragma unroll
    for (int r=0; r<4; ++r){
      int P = Pbase + mg*16 + q*4 + r;
      if (P < 4752){
        int nn = P/396, pim = P%396;
        for (int nb=0; nb<nbN; ++nb){
          int co = cog*64 + nb*16 + n16;
          float v = acc[mg][nb][r];
          if (co < 40)
            dep[((size_t)nn*40 + co)*396 + pim] = v + dhb[co];
          else if (co < 104)
            ctx2[((size_t)nn*396 + pim)*64 + (co-40)] = v + chb[co-40];
        }
      }
    }
  }
}

// ---------- softmax over 40 depth channels ----------
__global__ __launch_bounds__(256) void k_softmax40(float* __restrict__ dep)
{
  int i = blockIdx.x*256 + threadIdx.x;
  if (i >= 12*396) return;
  int n = i/396, p = i%396;
  float* base = dep + (size_t)n*40*396 + p;
  float mx = -1e30f;
  for (int d=0; d<40; ++d) mx = fmaxf(mx, base[(size_t)d*396]);
  float s = 0.f;
  for (int d=0; d<40; ++d){ float e = expf(base[(size_t)d*396]-mx); base[(size_t)d*396]=e; s+=e; }
  float inv = 1.f/s;
  for (int d=0; d<40; ++d) base[(size_t)d*396] *= inv;
}

// ---------- geometry + count (fused) ----------
__global__ __launch_bounds__(256) void k_geom(
    const float* __restrict__ rots, const float* __restrict__ trans,
    const float* __restrict__ intr, int* __restrict__ vox, int* __restrict__ cnt)
{
  int pt = blockIdx.x*256 + threadIdx.x;
  if (pt >= 190080) return;
  int b = pt/95040; int r = pt%95040;
  int n = r/15840;  int r2 = r%15840;
  int d = r2/396;   int pim = r2%396;
  int y = pim/33, x = pim%33;
  int bn = b*6+n;
  const float* R = rots + (size_t)bn*9;
  const float* T = trans + (size_t)bn*3;
  const float* K = intr + (size_t)bn*9;
  float fx=K[0], cx=K[2], fy=K[4], cy=K[5];
  float xs = (float)x * 32.96875f;
  float ys = (float)((double)y * (383.0/11.0));
  float dv = 4.0f + (float)d;
  float camx = (xs-cx)*dv/fx;
  float camy = (ys-cy)*dv/fy;
  float gx = R[0]*camx + R[1]*camy + R[2]*dv + T[0];
  float gy = R[3]*camx + R[4]*camy + R[5]*dv + T[1];
  float gz = R[6]*camx + R[7]*camy + R[8]*dv + T[2];
  int ix = (int)floorf(gx + 50.f);
  int iy = (int)floorf(gy + 50.f);
  int iz = (int)floorf((gz + 10.f)/5.f);
  bool valid = (ix>=0 && ix<100 && iy>=0 && iy<100 && iz>=0 && iz<4);
  int sid = iz*10000 + ix*100 + iy;
  vox[pt] = valid ? sid : -1;
  if (valid) atomicAdd(&cnt[b*40000 + sid], 1);
}

// ---------- scan ----------
__global__ __launch_bounds__(256) void k_scan1(
    const int* __restrict__ cnt, int* __restrict__ off, int* __restrict__ bsum)
{
  __shared__ int s[256];
  int t = threadIdx.x;
  int i = blockIdx.x*256 + t;
  int v = (i < 80000) ? cnt[i] : 0;
  s[t] = v; __syncthreads();
  for (int o=1;o<256;o<<=1){
    int x = (t>=o) ? s[t-o] : 0;
    __syncthreads();
    s[t] += x;
    __syncthreads();
  }
  if (i < 80000) off[i] = s[t] - v;
  if (t == 255) bsum[blockIdx.x] = s[255];
}

// parallel wave scan over nblk block sums
__global__ void k_scan2(int* __restrict__ bsum, int nblk)
{
  int lane = threadIdx.x & 63;
  int run = 0;
  for (int base=0; base<nblk; base+=64){
    int i = base + lane;
    int v = (i < nblk) ? bsum[i] : 0;
    int s = v;
    #pragma unroll
    for (int o=1;o<64;o<<=1){
      int t = __shfl_up(s, o);
      if (lane >= o) s += t;
    }
    int total = __shfl(s, 63);
    if (i < nblk) bsum[i] = run + s - v;
    run += total;
  }
}

__global__ __launch_bounds__(256) void k_scan3(
    int* __restrict__ off, const int* __restrict__ bsum, int* __restrict__ cur)
{
  int i = blockIdx.x*256 + threadIdx.x;
  if (i >= 80000) return;
  int o = off[i] + bsum[i>>8];
  off[i] = o;
  cur[i] = o;
}

__global__ __launch_bounds__(256) void k_fill(
    const int* __restrict__ vox, int* __restrict__ cur, int* __restrict__ list)
{
  int pt = blockIdx.x*256 + threadIdx.x;
  if (pt >= 190080) return;
  int s = vox[pt];
  if (s < 0) return;
  int b = pt/95040;
  int slot = atomicAdd(&cur[b*40000 + s], 1);
  list[slot] = pt;
}

// ---------- zero the padding ring of Ah/Al ----------
__global__ __launch_bounds__(256) void k_zero_ring(hb* __restrict__ Ah, hb* __restrict__ Al)
{
  int i = blockIdx.x*256 + threadIdx.x;
  if (i >= 2*404*256) return;
  int c = i & 255;
  int t = i >> 8;
  int b = t / 404;
  int ridx = t % 404;
  int py, px;
  if (ridx < 102){ py = 0; px = ridx; }
  else if (ridx < 204){ py = 101; px = ridx-102; }
  else if (ridx < 304){ py = ridx-204+1; px = 0; }
  else { py = ridx-304+1; px = 101; }
  size_t o = (((size_t)b*102 + py)*102 + px)*256 + c;
  hb z = __float2bfloat16(0.f);
  Ah[o] = z; Al[o] = z;
}

// ---------- gather: writes bev fp32 + Ah/Al bf16 ----------
__global__ __launch_bounds__(256) void k_gather(
    const int* __restrict__ off, const int* __restrict__ cnt, const int* __restrict__ list,
    const float* __restrict__ ctx2, const float* __restrict__ dep, float* __restrict__ bev,
    hb* __restrict__ Ah, hb* __restrict__ Al)
{
  int tid = threadIdx.x;
  int bv = blockIdx.x*4 + (tid>>6);
  int c = tid & 63;
  int b = bv/40000, sid = bv%40000;
  int st = off[bv], nn = cnt[bv];
  float s = 0.f;
  for (int k=0;k<nn;++k){
    int pt = list[st+k];
    int r = pt%95040;
    int bn = b*6 + r/15840;
    int r2 = r%15840;
    int dd = r2/396, pim = r2%396;
    s += ctx2[((size_t)bn*396+pim)*64 + c] * dep[((size_t)bn*40+dd)*396 + pim];
  }
  int iz = sid/10000, rem = sid%10000;
  bev[(size_t)b*2560000 + (size_t)iz*640000 + (size_t)c*10000 + rem] = s;
  int ix = rem/100, iy = rem%100;
  size_t oh = (((size_t)b*102 + (ix+1))*102 + (iy+1))*256 + iz*64 + c;
  hb hv, lv; split2(s, &hv, &lv);
  Ah[oh] = hv; Al[oh] = lv;
}

// ---------- NCHW fp32 (*g) -> padded NHWC bf16 hi/lo ----------
__global__ __launch_bounds__(256) void k_tohwc2(
    const float* __restrict__ in, hb* __restrict__ Ah, hb* __restrict__ Al,
    const float* __restrict__ g)
{
  __shared__ float tile[32*105];
  int py = blockIdx.x;
  int b  = blockIdx.y;
  int cg = blockIdx.z;
  int tid = threadIdx.x;
  bool inner = (py >= 1 && py <= 100);
  if (inner){
    if (tid < 64){ int cil = tid & 31; int col = (tid>>5) ? 101 : 0; tile[cil*105 + col] = 0.f; }
    for (int i = tid; i < 3200; i += 256){
      int cil = i / 100, x = i % 100;
      int ci = cg*32 + cil;
      tile[cil*105 + (x+1)] = in[(((size_t)b*256 + ci)*100 + (py-1))*100 + x];
    }
  }
  __syncthreads();
  for (int i = tid; i < 32*102; i += 256){
    int px = i >> 5, cil = i & 31;
    int ci = cg*32 + cil;
    float v = 0.f;
    if (inner){
      v = tile[cil*105 + px];
      if (g) v *= g[b*256 + ci];
    }
    hb hv, lv; split2(v, &hv, &lv);
    size_t o = (((size_t)b*102 + py)*102 + px)*256 + ci;
    Ah[o] = hv; Al[o] = lv;
  }
}

// ---------- row mean (NCHW rows) ----------
__global__ __launch_bounds__(256) void k_rowmean(
    const float* __restrict__ in, float* __restrict__ out, int rowlen, float inv)
{
  __shared__ float ws[4];
  int row = blockIdx.x; int t = threadIdx.x;
  const float* p = in + (size_t)row*rowlen;
  float s = 0.f;
  for (int i=t; i<rowlen; i+=256) s += p[i];
  #pragma unroll
  for (int off=32; off; off>>=1) s += __shfl_down(s, off);
  if ((t&63)==0) ws[t>>6] = s;
  __syncthreads();
  if (t==0) out[row] = (ws[0]+ws[1]+ws[2]+ws[3]) * inv;
}

// ---------- BEV MFMA conv: wave = 2nb x 4y, B direct from global (reg prefetch) ----------
// 16 barriers/block (2 per kb). Block = 16x x 8y x 64co.
__global__ __launch_bounds__(256) void k_conv3_bevm(
    const hb* __restrict__ Ah, const hb* __restrict__ Al,
    const hb* __restrict__ Wph, const hb* __restrict__ Wpl,
    const float* __restrict__ bns, const float* __restrict__ bnb,
    const float* __restrict__ res, float* __restrict__ out, int Cout, int NBG)
{
  __shared__ __align__(16) short sAh[10*18*44];
  __shared__ __align__(16) short sAl[10*18*44];
  const int NB = Cout >> 4;
  int tid = threadIdx.x;
  int wv = tid >> 6, lane = tid & 63;
  int wc = wv & 1;       // co half
  int wy = wv >> 1;      // y half
  int L = blockIdx.x;
  int spatial = L / (NBG*2);
  int rem = L % (NBG*2);
  int cog = rem % NBG;
  int bb  = rem / NBG;
  int xg = spatial % 7, yg = spatial / 7;
  int x0 = xg*16;
  int m = lane & 15, q = lane >> 4;
  int nb0 = cog*4 + wc*2;      // global nb of this wave's first co-block
  floatx4 acc[4][2];
  #pragma unroll
  for (int r=0;r<4;++r)
    #pragma unroll
    for (int u=0;u<2;++u) acc[r][u] = (floatx4)(0.f);

  const short8* gAh = (const short8*)(const void*)Ah;
  const short8* gAl = (const short8*)(const void*)Al;
  const short8* gWh = (const short8*)(const void*)Wph;
  const short8* gWl = (const short8*)(const void*)Wpl;
  const size_t nbstride = (size_t)NB*64;

  short8 pbh[2], pbl[2];
  #pragma unroll
  for (int u=0;u<2;++u){
    pbh[u] = gWh[(size_t)(nb0+u)*64 + lane];
    pbl[u] = gWl[(size_t)(nb0+u)*64 + lane];
  }

  for (int kb=0; kb<8; ++kb){
    __syncthreads();               // protect sA from previous kb's readers
    for (int i = tid; i < 720; i += 256){
      int rc = i >> 2, part = i & 3;
      int r = rc / 18, c = rc % 18;
      int yr = yg*8 + r; if (yr > 101) yr = 101;
      int xc = x0 + c;   if (xc > 101) xc = 101;
      size_t so = ((size_t)((bb*102 + yr)*102 + xc))*32 + kb*4 + part;
      short8 vh = gAh[so], vl = gAl[so];
      int dst = (r*18 + c)*44 + part*8;
      *(short8*)(sAh + dst) = vh;
      *(short8*)(sAl + dst) = vl;
    }
    __syncthreads();               // sA visible
    #pragma unroll 3
    for (int tap=0; tap<9; ++tap){
      int idx2 = kb*9 + tap;
      short8 cbh0 = pbh[0], cbh1 = pbh[1];
      short8 cbl0 = pbl[0], cbl1 = pbl[1];
      int nx = (idx2+1 < 72) ? idx2+1 : 71;
      #pragma unroll
      for (int u=0;u<2;++u){
        pbh[u] = gWh[(size_t)nx*nbstride + (size_t)(nb0+u)*64 + lane];
        pbl[u] = gWl[(size_t)nx*nbstride + (size_t)(nb0+u)*64 + lane];
      }
      int dy = (tap*11) >> 5;
      int dx = tap - dy*3;
      int cc = dx + m;
      #pragma unroll
      for (int r=0; r<4; ++r){
        int a0 = ((wy*4 + r + dy)*18 + cc)*44 + q*8;
        short8 cah = *(const short8*)(sAh + a0);
        short8 cal = *(const short8*)(sAl + a0);
        acc[r][0] = __builtin_amdgcn_mfma_f32_16x16x32_bf16(cah, cbh0, acc[r][0], 0,0,0);
        acc[r][0] = __builtin_amdgcn_mfma_f32_16x16x32_bf16(cah, cbl0, acc[r][0], 0,0,0);
        acc[r][0] = __builtin_amdgcn_mfma_f32_16x16x32_bf16(cal, cbh0, acc[r][0], 0,0,0);
        acc[r][1] = __builtin_amdgcn_mfma_f32_16x16x32_bf16(cah, cbh1, acc[r][1], 0,0,0);
        acc[r][1] = __builtin_amdgcn_mfma_f32_16x16x32_bf16(cah, cbl1, acc[r][1], 0,0,0);
        acc[r][1] = __builtin_amdgcn_mfma_f32_16x16x32_bf16(cal, cbh1, acc[r][1], 0,0,0);
      }
    }
  }

  int n = lane & 15;
  int xq = x0 + q*4;
  #pragma unroll
  for (int r=0; r<4; ++r){
    int yo = yg*8 + wy*4 + r;
    if (yo < 100 && xq < 100){
      #pragma unroll
      for (int u=0; u<2; ++u){
        int co = (nb0+u)*16 + n;
        float s = bns[co], bv = bnb[co];
        floatx4 a = acc[r][u];
        float4 v;
        v.x = fmaxf(a[0]*s+bv, 0.f);
        v.y = fmaxf(a[1]*s+bv, 0.f);
        v.z = fmaxf(a[2]*s+bv, 0.f);
        v.w = fmaxf(a[3]*s+bv, 0.f);
        size_t o = ((size_t)(bb*Cout+co)*100 + yo)*100 + xq;
        if (res){
          float4 rv = *(const float4*)(res + o);
          v.x += rv.x; v.y += rv.y; v.z += rv.z; v.w += rv.w;
        }
        *(float4*)(out + o) = v;
      }
    }
  }
}

// ---------- final 1x1 conv 128->16 ----------
__global__ __launch_bounds__(256) void k_final2(
    const float* __restrict__ h, const float* __restrict__ W, const float* __restrict__ bias,
    float* __restrict__ out)
{
  __shared__ float wsl[2048];
  __shared__ float bs[16];
  int tid = threadIdx.x;
  int b = blockIdx.y;
  for (int i=tid; i<2048; i+=256) wsl[i] = W[i];
  if (tid < 16) bs[tid] = bias[tid];
  __syncthreads();
  int pix = blockIdx.x*256 + tid;
  if (pix >= 10000) return;
  float acc[16];
  #pragma unroll
  for (int oc=0; oc<16; ++oc) acc[oc] = bs[oc];
  const float* hb_ = h + (size_t)b*128*10000 + pix;
  for (int ci=0; ci<128; ++ci){
    float hv = hb_[(size_t)ci*10000];
    #pragma unroll
    for (int oc=0; oc<16; ++oc) acc[oc] += hv * wsl[oc*128 + ci];
  }
  #pragma unroll
  for (int oc=0; oc<16; ++oc)
    out[((size_t)(b*16+oc))*10000 + pix] = acc[oc];
}

extern "C" void kernel_launch(void* const* d_in, const int* in_sizes, int n_in,
                              void* d_out, int out_size, void* d_ws, size_t ws_size,
                              hipStream_t stream)
{
  (void)in_sizes; (void)n_in; (void)out_size; (void)ws_size;
  const float* feats = (const float*)d_in[0];
  const float* rots  = (const float*)d_in[1];
  const float* trans = (const float*)d_in[2];
  const float* intr  = (const float*)d_in[3];
  const float* nw1   = (const float*)d_in[4];
  const float* bn1s  = (const float*)d_in[5];
  const float* bn1b  = (const float*)d_in[6];
  const float* se1w1 = (const float*)d_in[7];
  const float* se1b1 = (const float*)d_in[8];
  const float* se1w2 = (const float*)d_in[9];
  const float* se1b2 = (const float*)d_in[10];
  const float* nw2   = (const float*)d_in[11];
  const float* bn2s  = (const float*)d_in[12];
  const float* bn2b  = (const float*)d_in[13];
  const float* dhw   = (const float*)d_in[14];
  const float* dhb   = (const float*)d_in[15];
  const float* chw   = (const float*)d_in[16];
  const float* chb   = (const float*)d_in[17];
  const float* bcw1  = (const float*)d_in[18];
  const float* bcs1  = (const float*)d_in[19];
  const float* bcb1  = (const float*)d_in[20];
  const float* bcsw1 = (const float*)d_in[21];
  const float* bcsb1 = (const float*)d_in[22];
  const float* bcsw2 = (const float*)d_in[23];
  const float* bcsb2 = (const float*)d_in[24];
  const float* bcw2  = (const float*)d_in[25];
  const float* bcs2  = (const float*)d_in[26];
  const float* bcb2  = (const float*)d_in[27];
  const float* dw1   = (const float*)d_in[28];
  const float* ds1   = (const float*)d_in[29];
  const float* db1   = (const float*)d_in[30];
  const float* dw2   = (const float*)d_in[31];
  const float* db2   = (const float*)d_in[32];
  float* out = (float*)d_out;

  // ---- workspace layout (float units) ----
  float* ws = (float*)d_ws;
  float* bev   = ws;                       // S0: 5,120,000
  float* h1    = ws + 5120000;             // S1: 5,120,000
  hb*    Ah    = (hb*)(ws + 10240000);     // S2: 2,663,424 fu
  hb*    Al    = (hb*)(ws + 12903424);     // S3: 2,663,424 fu
  float* x2    = ws + 15566848;            // S4: 1,216,512
  float* S5    = ws + 16783360;            // 589,824
  float* dep   = ws + 17373184;            // 190,080
  float* ctx2  = ws + 17563264;            // 304,128
  float* mean1 = ws + 17867392;            // 3072
  float* g1    = mean1 + 3072;
  float* mean2 = g1 + 3072;
  float* g2    = mean2 + 512;
  int*   vox   = (int*)(ws + 17875584);    // 190,080 ints
  // phase aliases
  hb* Fph  = (hb*)bev;
  hb* Wc1h = (hb*)(bev + 3041280);
  hb* Wc1l = (hb*)(bev + 3205120);
  float* x1 = h1;
  hb* Fpl  = (hb*)(h1 + 1216512);
  hb* Xh   = (hb*)Ah;
  hb* Xl   = (hb*)Al;
  hb* Wc2h = (hb*)S5;
  hb* Wc2l = (hb*)(S5 + 294912);
  hb* x2h  = (hb*)x2;
  hb* x2l  = (hb*)(x2 + 608256);
  hb* Whh  = (hb*)S5;
  hb* Whl  = (hb*)(S5 + 14336);
  int* cnt  = (int*)h1;
  int* off  = cnt + 80000;
  int* cur  = off + 80000;
  int* bsum = cur + 80000;
  int* list = bsum + 1024;
  float* h3 = h1;
  hb* Wp1h = (hb*)x2;
  hb* Wp1l = (hb*)(x2 + 294912);
  hb* Wp3h = (hb*)(x2 + 589824);
  hb* Wp3l = (hb*)(x2 + 589824 + 147456);
  hb* Wp2h = (hb*)S5;
  hb* Wp2l = (hb*)(S5 + 294912);

  // ---- image branch (MFMA) ----
  k_trans_featsP<<<dim3(7,20,12),256,0,stream>>>(feats,Fph,Fpl);
  k_wpackE<<<3584,256,0,stream>>>(nw1,nw2,Wc1h,Wc1l,Wc2h,Wc2l);
  k_mfma_gemm1<<<dim3(38,4),256,0,stream>>>(Fph,Fpl,Wc1h,Wc1l,bn1s,bn1b,x1);
  k_meanse<<<12,256,0,stream>>>(x1,se1w1,se1b1,se1w2,se1b2,g1);
  k_topad<<<dim3(14,12),256,0,stream>>>(x1,g1,Xh,Xl);
  k_conv3_img<<<dim3(3,24,4),256,0,stream>>>(Xh,Xl,Wc2h,Wc2l,bn2s,bn2b,x2h,x2l);
  k_wpackH<<<112,256,0,stream>>>(dhw,chw,Whh,Whl);
  k_headsM<<<dim3(38,2),256,0,stream>>>(x2h,x2l,Whh,Whl,dhb,chb,dep,ctx2);
  k_softmax40<<<19,256,0,stream>>>(dep);

  // ---- pack BEV conv weights kb-major ----
  k_wpackT3<<<5760,256,0,stream>>>(bcw1,bcw2,dw1,Wp1h,Wp1l,Wp2h,Wp2l,Wp3h,Wp3l);

  // ---- lift-splat (gather form; fused bf16 NHWC pack) ----
  hipMemsetAsync(cnt, 0, 80000*sizeof(int), stream);
  k_geom<<<(190080+255)/256,256,0,stream>>>(rots,trans,intr,vox,cnt);
  k_scan1<<<313,256,0,stream>>>(cnt,off,bsum);
  k_scan2<<<1,64,0,stream>>>(bsum,313);
  k_scan3<<<(80000+255)/256,256,0,stream>>>(off,bsum,cur);
  k_fill<<<(190080+255)/256,256,0,stream>>>(vox,cur,list);
  k_zero_ring<<<808,256,0,stream>>>(Ah,Al);
  k_gather<<<20000,256,0,stream>>>(off,cnt,list,ctx2,dep,bev,Ah,Al);

  // ---- BEV encoder (MFMA convs) ----
  k_conv3_bevm<<<728,256,0,stream>>>(Ah,Al,Wp1h,Wp1l,bcs1,bcb1,nullptr,h1,256,4);
  k_rowmean<<<512,256,0,stream>>>(h1,mean2,10000,1e-4f);
  k_se_fc<<<2,256,0,stream>>>(mean2,bcsw1,bcsb1,bcsw2,bcsb2,g2,16);
  k_tohwc2<<<dim3(102,2,8),256,0,stream>>>(h1,Ah,Al,g2);
  k_conv3_bevm<<<728,256,0,stream>>>(Ah,Al,Wp2h,Wp2l,bcs2,bcb2,bev,bev,256,4);
  k_tohwc2<<<dim3(102,2,8),256,0,stream>>>(bev,Ah,Al,nullptr);
  k_conv3_bevm<<<364,256,0,stream>>>(Ah,Al,Wp3h,Wp3l,ds1,db1,nullptr,h3,128,2);
  k_final2<<<dim3(40,2),256,0,stream>>>(h3,dw2,db2,out);
}

// Round 13
// 581.535 us; speedup vs baseline: 1.2337x; 1.0858x over previous
//
#include <hip/hip_runtime.h>
#include <hip/hip_bf16.h>
#include <cmath>

// LSS pipeline R13: gather de-serialized (fill precomputes pix+depv; unroll-2
// parallel ctx loads) + bev/h1 flipped to NHWC (coalesced gather writes,
// trivial packA instead of LDS-transpose tohwc2). conv3 keeps NCHW out.

typedef __attribute__((ext_vector_type(8))) short short8;
typedef __attribute__((ext_vector_type(4))) float floatx4;
typedef __hip_bfloat16 hb;

__device__ __forceinline__ float sigf(float x){ return 1.0f/(1.0f+expf(-x)); }
__device__ __forceinline__ float siluf(float x){ return x*sigf(x); }
__device__ __forceinline__ void split2(float v, hb* h, hb* l){
  hb hv = __float2bfloat16(v);
  *h = hv; *l = __float2bfloat16(v - __bfloat162float(hv));
}

// ---------- feats NCHW -> A-frag-packed bf16 hi/lo ----------
__global__ __launch_bounds__(256) void k_trans_featsP(
    const float* __restrict__ feats, hb* __restrict__ Fph, hb* __restrict__ Fpl)
{
  __shared__ float tile[64][65];
  int n = blockIdx.z;
  int p0 = blockIdx.x*64;
  int c0 = blockIdx.y*64;
  int tid = threadIdx.x;
  int tr = tid >> 6;
  int tc = tid & 63;
  #pragma unroll
  for (int it=0; it<16; ++it){
    int ci = c0 + it*4 + tr;
    int p = p0 + tc;
    float v = 0.f;
    if (p < 396) v = feats[((size_t)n*1280 + ci)*396 + p];
    tile[it*4+tr][tc] = v;
  }
  __syncthreads();
  #pragma unroll
  for (int iter=0; iter<2; ++iter){
    int idx = iter*256 + tid;
    int oc = idx >> 6;
    int pl = idx & 63;
    int p = p0 + pl;
    if (p < 396){
      int P = n*396 + p;
      int T = P >> 4, mm = P & 15;
      int kb = (c0 >> 5) + (oc >> 2);
      int q = oc & 3;
      int lane = q*16 + mm;
      size_t o = (((size_t)T*40 + kb)*64 + lane)*8;
      #pragma unroll
      for (int j=0; j<8; ++j){
        hb hv, lv; split2(tile[oc*8+j][pl], &hv, &lv);
        Fph[o+j] = hv; Fpl[o+j] = lv;
      }
    }
  }
}

// ---------- merged early packs ----------
__global__ __launch_bounds__(256) void k_wpackE(
    const float* __restrict__ nw1, const float* __restrict__ nw2,
    hb* __restrict__ Wc1h, hb* __restrict__ Wc1l,
    hb* __restrict__ Wc2h, hb* __restrict__ Wc2l)
{
  int i = blockIdx.x*256 + threadIdx.x;
  if (i < 327680){
    int j = i & 7;
    int lane = (i>>3) & 63;
    int t2 = i >> 9;
    int nb = t2 & 15;
    int kb = t2 >> 4;
    int ci = kb*32 + (lane>>4)*8 + j;
    int co = nb*16 + (lane&15);
    hb hv, lv; split2(nw1[(size_t)co*1280 + ci], &hv, &lv);
    Wc1h[i] = hv; Wc1l[i] = lv;
  } else {
    int i2 = i - 327680;
    if (i2 >= 589824) return;
    int j = i2 & 7;
    int t1 = i2 >> 3;
    int lane = t1 & 63;
    int t2 = t1 >> 6;
    int nb = t2 % 16;
    int t3 = t2 / 16;
    int tap = t3 % 9;
    int kb = t3 / 9;
    int ci = kb*32 + (lane>>4)*8 + j;
    int co = nb*16 + (lane&15);
    hb hv, lv; split2(nw2[(size_t)co*2304 + ci*9 + tap], &hv, &lv);
    Wc2h[i2] = hv; Wc2l[i2] = lv;
  }
}

// ---------- merged BEV packs kb-major ----------
__global__ __launch_bounds__(256) void k_wpackT3(
    const float* __restrict__ bcw1, const float* __restrict__ bcw2,
    const float* __restrict__ dw1,
    hb* __restrict__ W1h, hb* __restrict__ W1l,
    hb* __restrict__ W2h, hb* __restrict__ W2l,
    hb* __restrict__ W3h, hb* __restrict__ W3l)
{
  int gi = blockIdx.x*256 + threadIdx.x;
  const float* W; hb* Wh; hb* Wl; int NB; int i;
  if (gi < 589824){ W = bcw1; Wh = W1h; Wl = W1l; NB = 16; i = gi; }
  else if (gi < 1179648){ W = bcw2; Wh = W2h; Wl = W2l; NB = 16; i = gi - 589824; }
  else if (gi < 1474560){ W = dw1; Wh = W3h; Wl = W3l; NB = 8; i = gi - 1179648; }
  else return;
  int j = i & 7;
  int t1 = i >> 3;
  int lane = t1 & 63;
  int t2 = t1 >> 6;
  int nb = t2 % NB;
  int t3 = t2 / NB;
  int tap = t3 % 9;
  int kb = t3 / 9;
  int ci = kb*32 + (lane>>4)*8 + j;
  int co = nb*16 + (lane&15);
  hb hv, lv; split2(W[(size_t)co*2304 + ci*9 + tap], &hv, &lv);
  Wh[i] = hv; Wl[i] = lv;
}

// ---------- pack heads weights ----------
__global__ __launch_bounds__(256) void k_wpackH(
    const float* __restrict__ dhw, const float* __restrict__ chw,
    hb* __restrict__ Wph, hb* __restrict__ Wpl)
{
  int i = blockIdx.x*256 + threadIdx.x;
  if (i >= 8*7*512) return;
  int j = i & 7;
  int t1 = i >> 3;
  int lane = t1 & 63;
  int t2 = t1 >> 6;
  int nb = t2 % 7;
  int kb = t2 / 7;
  int ci = kb*32 + (lane>>4)*8 + j;
  int co = nb*16 + (lane&15);
  float w = 0.f;
  if (co < 40) w = dhw[(size_t)co*256 + ci];
  else if (co < 104) w = chw[(size_t)(co-40)*256 + ci];
  hb hv, lv; split2(w, &hv, &lv);
  Wph[i] = hv; Wpl[i] = lv;
}

// ---------- conv1 as MFMA GEMM; out NHWC ----------
__global__ __launch_bounds__(256) void k_mfma_gemm1(
    const hb* __restrict__ Fph, const hb* __restrict__ Fpl,
    const hb* __restrict__ Wph, const hb* __restrict__ Wpl,
    const float* __restrict__ bns, const float* __restrict__ bnb,
    float* __restrict__ out)
{
  __shared__ short8 lbh[256], lbl[256];
  int tid = threadIdx.x;
  int wv = tid >> 6, lane = tid & 63;
  int cog = blockIdx.y;
  int Pbase = blockIdx.x*128 + wv*32;
  int q = lane >> 4;
  int T0 = blockIdx.x*8 + wv*2; if (T0 > 296) T0 = 296;
  int T1 = T0 + 1;              if (T1 > 296) T1 = 296;
  size_t a0 = (size_t)T0*2560 + lane;
  size_t a1 = (size_t)T1*2560 + lane;
  const short8* gAh = (const short8*)(const void*)Fph;
  const short8* gAl = (const short8*)(const void*)Fpl;
  const short8* gWh = (const short8*)(const void*)Wph;
  const short8* gWl = (const short8*)(const void*)Wpl;
  size_t sb = (size_t)(cog*4 + wv)*64 + lane;
  floatx4 acc[2][4];
  #pragma unroll
  for (int i=0;i<2;++i)
    #pragma unroll
    for (int j=0;j<4;++j) acc[i][j] = (floatx4)(0.f);
  short8 ph = gWh[sb], pw = gWl[sb];
  short8 cah0 = gAh[a0], cal0 = gAl[a0], cah1 = gAh[a1], cal1 = gAl[a1];
  for (int kb=0; kb<40; ++kb){
    __syncthreads();
    lbh[tid] = ph; lbl[tid] = pw;
    int nx = (kb+1 < 40) ? kb+1 : 39;
    ph = gWh[(size_t)nx*1024 + sb]; pw = gWl[(size_t)nx*1024 + sb];
    __syncthreads();
    short8 nah0 = gAh[a0 + (size_t)nx*64];
    short8 nal0 = gAl[a0 + (size_t)nx*64];
    short8 nah1 = gAh[a1 + (size_t)nx*64];
    short8 nal1 = gAl[a1 + (size_t)nx*64];
    #pragma unroll
    for (int nb=0; nb<4; ++nb){
      short8 bh = lbh[nb*64 + lane];
      short8 bl = lbl[nb*64 + lane];
      acc[0][nb] = __builtin_amdgcn_mfma_f32_16x16x32_bf16(cah0, bh, acc[0][nb], 0,0,0);
      acc[0][nb] = __builtin_amdgcn_mfma_f32_16x16x32_bf16(cah0, bl, acc[0][nb], 0,0,0);
      acc[0][nb] = __builtin_amdgcn_mfma_f32_16x16x32_bf16(cal0, bh, acc[0][nb], 0,0,0);
      acc[1][nb] = __builtin_amdgcn_mfma_f32_16x16x32_bf16(cah1, bh, acc[1][nb], 0,0,0);
      acc[1][nb] = __builtin_amdgcn_mfma_f32_16x16x32_bf16(cah1, bl, acc[1][nb], 0,0,0);
      acc[1][nb] = __builtin_amdgcn_mfma_f32_16x16x32_bf16(cal1, bh, acc[1][nb], 0,0,0);
    }
    cah0 = nah0; cal0 = nal0; cah1 = nah1; cal1 = nal1;
  }
  int n16 = lane & 15;
  #pragma unroll
  for (int mg=0; mg<2; ++mg){
    #pragma unroll
    for (int nb=0; nb<4; ++nb){
      int co = cog*64 + nb*16 + n16;
      float s = bns[co], bv = bnb[co];
      #pragma unroll
      for (int r=0; r<4; ++r){
        int P = Pbase + mg*16 + q*4 + r;
        if (P < 4752) out[(size_t)P*256 + co] = siluf(acc[mg][nb][r]*s + bv);
      }
    }
  }
}

// ---------- fused mean(396) + SE FC (image branch) ----------
__global__ __launch_bounds__(256) void k_meanse(
    const float* __restrict__ x1, const float* __restrict__ w1, const float* __restrict__ b1,
    const float* __restrict__ w2, const float* __restrict__ b2, float* __restrict__ g)
{
  __shared__ float m[256];
  __shared__ float h[32];
  int n = blockIdx.x; int t = threadIdx.x;
  float s = 0.f;
  for (int p=0; p<396; ++p) s += x1[((size_t)n*396+p)*256 + t];
  m[t] = s*(1.f/396.f);
  __syncthreads();
  if (t < 32){
    float s2 = b1[t];
    for (int c=0; c<256; ++c) s2 += m[c]*w1[t*256+c];
    h[t] = siluf(s2);
  }
  __syncthreads();
  float s3 = b2[t];
  for (int j=0; j<32; ++j) s3 += h[j]*w2[t*32+j];
  g[n*256+t] = sigf(s3);
}

// ---------- SE FC (BEV, H=16) ----------
__global__ __launch_bounds__(256) void k_se_fc(
    const float* __restrict__ mean, const float* __restrict__ w1, const float* __restrict__ b1,
    const float* __restrict__ w2, const float* __restrict__ b2, float* __restrict__ g, int H)
{
  __shared__ float m[256];
  __shared__ float h[32];
  int n = blockIdx.x; int t = threadIdx.x;
  m[t] = mean[n*256 + t];
  __syncthreads();
  if (t < H){
    float s = b1[t];
    for (int c=0; c<256; ++c) s += m[c]*w1[t*256+c];
    h[t] = siluf(s);
  }
  __syncthreads();
  float s = b2[t];
  for (int j=0; j<H; ++j) s += h[j]*w2[t*H+j];
  g[n*256+t] = sigf(s);
}

// ---------- x1 NHWC * g -> padded [n][14][35][256] bf16 hi/lo ----------
__global__ __launch_bounds__(256) void k_topad(
    const float* __restrict__ x1, const float* __restrict__ g,
    hb* __restrict__ Xh, hb* __restrict__ Xl)
{
  int y = blockIdx.x;
  int n = blockIdx.y;
  int c = threadIdx.x;
  float gc = g[n*256+c];
  for (int xx=0; xx<35; ++xx){
    float v = 0.f;
    if (y>=1 && y<=12 && xx>=1 && xx<=33)
      v = x1[((size_t)n*396 + (y-1)*33 + (xx-1))*256 + c]*gc;
    hb hv, lv; split2(v, &hv, &lv);
    size_t o = (((size_t)n*14+y)*35+xx)*256 + c;
    Xh[o] = hv; Xl[o] = lv;
  }
}

// ---------- image 3x3 conv, LDS-staged MFMA ----------
__global__ __launch_bounds__(256) void k_conv3_img(
    const hb* __restrict__ Xh, const hb* __restrict__ Xl,
    const hb* __restrict__ Wph, const hb* __restrict__ Wpl,
    const float* __restrict__ bns, const float* __restrict__ bnb,
    hb* __restrict__ outh, hb* __restrict__ outl)
{
  __shared__ __align__(16) short sAh[10*18*44];
  __shared__ __align__(16) short sAl[10*18*44];
  __shared__ short8 lbh[2][256], lbl[2][256];
  int tid = threadIdx.x;
  int wv = tid >> 6, lane = tid & 63;
  int xg = blockIdx.x;
  int n = blockIdx.y >> 1, yg = blockIdx.y & 1;
  int cog = blockIdx.z;
  int x0 = xg*16;
  int y0 = yg*8 + wv;
  int m = lane & 15, q = lane >> 4;
  floatx4 acc[2][4];
  #pragma unroll
  for (int i=0;i<2;++i)
    #pragma unroll
    for (int j=0;j<4;++j) acc[i][j] = (floatx4)(0.f);

  const short8* gAh = (const short8*)(const void*)Xh;
  const short8* gAl = (const short8*)(const void*)Xl;
  const short8* gWh = (const short8*)(const void*)Wph;
  const short8* gWl = (const short8*)(const void*)Wpl;
  const size_t sb = (size_t)(cog*4 + wv)*64 + lane;
  const size_t nbase = (size_t)n*14*35*32;

  short8 ph = gWh[sb], pl = gWl[sb];
  int cur = 0;

  for (int kb=0; kb<8; ++kb){
    #pragma unroll 3
    for (int tap=0; tap<9; ++tap){
      int idx2 = kb*9 + tap;
      if (tap == 0){
        __syncthreads();
        for (int i = tid; i < 720; i += 256){
          int rc = i >> 2, part = i & 3;
          int r = rc / 18, c2 = rc % 18;
          int yr = yg*8 + r; if (yr > 13) yr = 13;
          int xc = x0 + c2;  if (xc > 34) xc = 34;
          size_t so = nbase + (size_t)(yr*35 + xc)*32 + kb*4 + part;
          short8 vh = gAh[so], vl = gAl[so];
          int dst = (r*18 + c2)*44 + part*8;
          *(short8*)(sAh + dst) = vh;
          *(short8*)(sAl + dst) = vl;
        }
      }
      lbh[cur][tid] = ph; lbl[cur][tid] = pl;
      int nx = (idx2+1 < 72) ? idx2+1 : 71;
      ph = gWh[(size_t)nx*1024 + sb];
      pl = gWl[(size_t)nx*1024 + sb];
      __syncthreads();
      int dy = (tap*11) >> 5;
      int dx = tap - dy*3;
      int cc = dx + m;
      int a0 = ((wv + dy)*18 + cc)*44 + q*8;
      int a1 = ((wv + 4 + dy)*18 + cc)*44 + q*8;
      short8 cah0 = *(const short8*)(sAh + a0);
      short8 cal0 = *(const short8*)(sAl + a0);
      short8 cah1 = *(const short8*)(sAh + a1);
      short8 cal1 = *(const short8*)(sAl + a1);
      #pragma unroll
      for (int nb=0; nb<4; ++nb){
        short8 bh = lbh[cur][nb*64 + lane];
        short8 bl = lbl[cur][nb*64 + lane];
        acc[0][nb] = __builtin_amdgcn_mfma_f32_16x16x32_bf16(cah0, bh, acc[0][nb], 0,0,0);
        acc[0][nb] = __builtin_amdgcn_mfma_f32_16x16x32_bf16(cah0, bl, acc[0][nb], 0,0,0);
        acc[0][nb] = __builtin_amdgcn_mfma_f32_16x16x32_bf16(cal0, bh, acc[0][nb], 0,0,0);
        acc[1][nb] = __builtin_amdgcn_mfma_f32_16x16x32_bf16(cah1, bh, acc[1][nb], 0,0,0);
        acc[1][nb] = __builtin_amdgcn_mfma_f32_16x16x32_bf16(cah1, bl, acc[1][nb], 0,0,0);
        acc[1][nb] = __builtin_amdgcn_mfma_f32_16x16x32_bf16(cal1, bh, acc[1][nb], 0,0,0);
      }
      cur ^= 1;
    }
  }

  int n16 = lane & 15;
  #pragma unroll
  for (int mg=0; mg<2; ++mg){
    int oy = y0 + mg*4;
    if (oy < 12){
      #pragma unroll
      for (int r=0; r<4; ++r){
        int ox = x0 + q*4 + r;
        if (ox < 33){
          int P = n*396 + oy*33 + ox;
          #pragma unroll
          for (int nb=0; nb<4; ++nb){
            int co = cog*64 + nb*16 + n16;
            float v = siluf(acc[mg][nb][r]*bns[co] + bnb[co]);
            hb hv, lv; split2(v, &hv, &lv);
            outh[(size_t)P*256 + co] = hv;
            outl[(size_t)P*256 + co] = lv;
          }
        }
      }
    }
  }
}

// ---------- heads as MFMA GEMM ----------
__global__ __launch_bounds__(256) void k_headsM(
    const hb* __restrict__ x2h, const hb* __restrict__ x2l,
    const hb* __restrict__ Whh, const hb* __restrict__ Whl,
    const float* __restrict__ dhb, const float* __restrict__ chb,
    float* __restrict__ dep, float* __restrict__ ctx2)
{
  __shared__ short8 lbh[256], lbl[256];
  int tid = threadIdx.x;
  int wv = tid >> 6, lane = tid & 63;
  int cog = blockIdx.y;
  int nb0 = cog*4;
  int nbN = cog ? 3 : 4;
  int Pbase = blockIdx.x*128 + wv*32;
  int m = lane & 15, q = lane >> 4;
  int P0 = Pbase + m;      if (P0 > 4751) P0 = 4751;
  int P1 = Pbase + 16 + m; if (P1 > 4751) P1 = 4751;
  size_t rA0 = (size_t)P0*32 + q;
  size_t rA1 = (size_t)P1*32 + q;
  const short8* gAh = (const short8*)(const void*)x2h;
  const short8* gAl = (const short8*)(const void*)x2l;
  const short8* gWh = (const short8*)(const void*)Whh;
  const short8* gWl = (const short8*)(const void*)Whl;
  floatx4 acc[2][4];
  #pragma unroll
  for (int i=0;i<2;++i)
    #pragma unroll
    for (int j=0;j<4;++j) acc[i][j] = (floatx4)(0.f);
  for (int kb=0; kb<8; ++kb){
    __syncthreads();
    for (int i=tid; i<nbN*64; i+=256){
      lbh[i] = gWh[(size_t)(kb*7 + nb0)*64 + i];
      lbl[i] = gWl[(size_t)(kb*7 + nb0)*64 + i];
    }
    __syncthreads();
    short8 ah0 = gAh[rA0 + kb*4], al0 = gAl[rA0 + kb*4];
    short8 ah1 = gAh[rA1 + kb*4], al1 = gAl[rA1 + kb*4];
    for (int nb=0; nb<nbN; ++nb){
      short8 bh = lbh[nb*64 + lane];
      short8 bl = lbl[nb*64 + lane];
      acc[0][nb] = __builtin_amdgcn_mfma_f32_16x16x32_bf16(ah0, bh, acc[0][nb], 0,0,0);
      acc[0][nb] = __builtin_amdgcn_mfma_f32_16x16x32_bf16(ah0, bl, acc[0][nb], 0,0,0);
      acc[0][nb] = __builtin_amdgcn_mfma_f32_16x16x32_bf16(al0, bh, acc[0][nb], 0,0,0);
      acc[1][nb] = __builtin_amdgcn_mfma_f32_16x16x32_bf16(ah1, bh, acc[1][nb], 0,0,0);
      acc[1][nb] = __builtin_amdgcn_mfma_f32_16x16x32_bf16(ah1, bl, acc[1][nb], 0,0,0);
      acc[1][nb] = __builtin_amdgcn_mfma_f32_16x16x32_bf16(al1, bh, acc[1][nb], 0,0,0);
    }
  }
  int n16 = lane & 15;
  #pragma unroll
  for (int mg=0; mg<2; ++mg){
    #pragma unroll
    for (int r=0; r<4; ++r){
      int P = Pbase + mg*16 + q*4 + r;
      if (P < 4752){
        int nn = P/396, pim = P%396;
        for (int nb=0; nb<nbN; ++nb){
          int co = cog*64 + nb*16 + n16;
          float v = acc[mg][nb][r];
          if (co < 40)
            dep[((size_t)nn*40 + co)*396 + pim] = v + dhb[co];
          else if (co < 104)
            ctx2[((size_t)nn*396 + pim)*64 + (co-40)] = v + chb[co-40];
        }
      }
    }
  }
}

// ---------- softmax over 40 depth channels ----------
__global__ __launch_bounds__(256) void k_softmax40(float* __restrict__ dep)
{
  int i = blockIdx.x*256 + threadIdx.x;
  if (i >= 12*396) return;
  int n = i/396, p = i%396;
  float* base = dep + (size_t)n*40*396 + p;
  float mx = -1e30f;
  for (int d=0; d<40; ++d) mx = fmaxf(mx, base[(size_t)d*396]);
  float s = 0.f;
  for (int d=0; d<40; ++d){ float e = expf(base[(size_t)d*396]-mx); base[(size_t)d*396]=e; s+=e; }
  float inv = 1.f/s;
  for (int d=0; d<40; ++d) base[(size_t)d*396] *= inv;
}

// ---------- geometry + count (fused) ----------
__global__ __launch_bounds__(256) void k_geom(
    const float* __restrict__ rots, const float* __restrict__ trans,
    const float* __restrict__ intr, int* __restrict__ vox, int* __restrict__ cnt)
{
  int pt = blockIdx.x*256 + threadIdx.x;
  if (pt >= 190080) return;
  int b = pt/95040; int r = pt%95040;
  int n = r/15840;  int r2 = r%15840;
  int d = r2/396;   int pim = r2%396;
  int y = pim/33, x = pim%33;
  int bn = b*6+n;
  const float* R = rots + (size_t)bn*9;
  const float* T = trans + (size_t)bn*3;
  const float* K = intr + (size_t)bn*9;
  float fx=K[0], cx=K[2], fy=K[4], cy=K[5];
  float xs = (float)x * 32.96875f;
  float ys = (float)((double)y * (383.0/11.0));
  float dv = 4.0f + (float)d;
  float camx = (xs-cx)*dv/fx;
  float camy = (ys-cy)*dv/fy;
  float gx = R[0]*camx + R[1]*camy + R[2]*dv + T[0];
  float gy = R[3]*camx + R[4]*camy + R[5]*dv + T[1];
  float gz = R[6]*camx + R[7]*camy + R[8]*dv + T[2];
  int ix = (int)floorf(gx + 50.f);
  int iy = (int)floorf(gy + 50.f);
  int iz = (int)floorf((gz + 10.f)/5.f);
  bool valid = (ix>=0 && ix<100 && iy>=0 && iy<100 && iz>=0 && iz<4);
  int sid = iz*10000 + ix*100 + iy;
  vox[pt] = valid ? sid : -1;
  if (valid) atomicAdd(&cnt[b*40000 + sid], 1);
}

// ---------- scan ----------
__global__ __launch_bounds__(256) void k_scan1(
    const int* __restrict__ cnt, int* __restrict__ off, int* __restrict__ bsum)
{
  __shared__ int s[256];
  int t = threadIdx.x;
  int i = blockIdx.x*256 + t;
  int v = (i < 80000) ? cnt[i] : 0;
  s[t] = v; __syncthreads();
  for (int o=1;o<256;o<<=1){
    int x = (t>=o) ? s[t-o] : 0;
    __syncthreads();
    s[t] += x;
    __syncthreads();
  }
  if (i < 80000) off[i] = s[t] - v;
  if (t == 255) bsum[blockIdx.x] = s[255];
}

__global__ void k_scan2(int* __restrict__ bsum, int nblk)
{
  int lane = threadIdx.x & 63;
  int run = 0;
  for (int base=0; base<nblk; base+=64){
    int i = base + lane;
    int v = (i < nblk) ? bsum[i] : 0;
    int s = v;
    #pragma unroll
    for (int o=1;o<64;o<<=1){
      int t = __shfl_up(s, o);
      if (lane >= o) s += t;
    }
    int total = __shfl(s, 63);
    if (i < nblk) bsum[i] = run + s - v;
    run += total;
  }
}

__global__ __launch_bounds__(256) void k_scan3(
    int* __restrict__ off, const int* __restrict__ bsum, int* __restrict__ cur)
{
  int i = blockIdx.x*256 + threadIdx.x;
  if (i >= 80000) return;
  int o = off[i] + bsum[i>>8];
  off[i] = o;
  cur[i] = o;
}

// ---------- fill: store ctx pixel index + dep value (dep ready by now) ----------
__global__ __launch_bounds__(256) void k_fill(
    const int* __restrict__ vox, int* __restrict__ cur, int* __restrict__ list,
    const float* __restrict__ dep, float* __restrict__ depv)
{
  int pt = blockIdx.x*256 + threadIdx.x;
  if (pt >= 190080) return;
  int s = vox[pt];
  if (s < 0) return;
  int b = pt/95040; int r = pt%95040;
  int bn = b*6 + r/15840;
  int r2 = r%15840;
  int dd = r2/396, pim = r2%396;
  int slot = atomicAdd(&cur[b*40000 + s], 1);
  list[slot] = bn*396 + pim;
  depv[slot] = dep[((size_t)bn*40 + dd)*396 + pim];
}

// ---------- zero the padding ring of Ah/Al ----------
__global__ __launch_bounds__(256) void k_zero_ring(hb* __restrict__ Ah, hb* __restrict__ Al)
{
  int i = blockIdx.x*256 + threadIdx.x;
  if (i >= 2*404*256) return;
  int c = i & 255;
  int t = i >> 8;
  int b = t / 404;
  int ridx = t % 404;
  int py, px;
  if (ridx < 102){ py = 0; px = ridx; }
  else if (ridx < 204){ py = 101; px = ridx-102; }
  else if (ridx < 304){ py = ridx-204+1; px = 0; }
  else { py = ridx-304+1; px = 101; }
  size_t o = (((size_t)b*102 + py)*102 + px)*256 + c;
  hb z = __float2bfloat16(0.f);
  Ah[o] = z; Al[o] = z;
}

// ---------- gather: unrolled parallel loads; bev NHWC write; Ah/Al bf16 ----------
__global__ __launch_bounds__(256) void k_gather(
    const int* __restrict__ off, const int* __restrict__ cnt, const int* __restrict__ list,
    const float* __restrict__ depv, const float* __restrict__ ctx2,
    float* __restrict__ bev, hb* __restrict__ Ah, hb* __restrict__ Al)
{
  int tid = threadIdx.x;
  int bv = blockIdx.x*4 + (tid>>6);
  int c = tid & 63;
  int b = bv/40000, sid = bv%40000;
  int st = off[bv], nn = cnt[bv];
  float s = 0.f;
  int k = 0;
  for (; k+2 <= nn; k += 2){
    int p0 = list[st+k], p1 = list[st+k+1];
    float d0 = depv[st+k], d1 = depv[st+k+1];
    float c0 = ctx2[(size_t)p0*64 + c];
    float c1 = ctx2[(size_t)p1*64 + c];
    s += c0*d0 + c1*d1;
  }
  if (k < nn)
    s += ctx2[(size_t)list[st+k]*64 + c] * depv[st+k];
  int iz = sid/10000, rem = sid%10000;
  bev[((size_t)b*10000 + rem)*256 + iz*64 + c] = s;   // NHWC
  int ix = rem/100, iy = rem%100;
  size_t oh = (((size_t)b*102 + (ix+1))*102 + (iy+1))*256 + iz*64 + c;
  hb hv, lv; split2(s, &hv, &lv);
  Ah[oh] = hv; Al[oh] = lv;
}

// ---------- NHWC fp32 (*g) -> padded NHWC bf16 hi/lo (elementwise, coalesced) ----------
// grid (100, 25, 2): row ix, iy-quad group, batch
__global__ __launch_bounds__(256) void k_packA(
    const float* __restrict__ src, const float* __restrict__ g,
    hb* __restrict__ Ah, hb* __restrict__ Al)
{
  int ix = blockIdx.x;
  int b = blockIdx.z;
  int c = threadIdx.x;
  float gc = g ? g[b*256 + c] : 1.f;
  #pragma unroll
  for (int i=0; i<4; ++i){
    int iy = blockIdx.y*4 + i;
    float v = src[((size_t)b*10000 + ix*100 + iy)*256 + c] * gc;
    hb hv, lv; split2(v, &hv, &lv);
    size_t o = (((size_t)b*102 + ix+1)*102 + iy+1)*256 + c;
    Ah[o] = hv; Al[o] = lv;
  }
}

// ---------- mean over 10000 pixels of NHWC h1 -> mean2 (atomic partials) ----------
__global__ __launch_bounds__(256) void k_mean_nhwc(
    const float* __restrict__ h1, float* __restrict__ mean2)
{
  int chunk = blockIdx.x;   // 0..39
  int b = blockIdx.y;
  int c = threadIdx.x;
  float s = 0.f;
  for (int p=0; p<250; ++p)
    s += h1[((size_t)b*10000 + chunk*250 + p)*256 + c];
  atomicAdd(&mean2[b*256 + c], s*1e-4f);
}

// ---------- BEV MFMA conv: wave = 2nb x 4y, B direct from global ----------
// res/outF in NHWC unless outNCHW; optional simultaneous bf16 A-pack skipped (race).
__global__ __launch_bounds__(256) void k_conv3_bevm(
    const hb* __restrict__ Ah, const hb* __restrict__ Al,
    const hb* __restrict__ Wph, const hb* __restrict__ Wpl,
    const float* __restrict__ bns, const float* __restrict__ bnb,
    const float* __restrict__ resN, float* __restrict__ outF, int outNCHW,
    int Cout, int NBG)
{
  __shared__ __align__(16) short sAh[10*18*44];
  __shared__ __align__(16) short sAl[10*18*44];
  const int NB = Cout >> 4;
  int tid = threadIdx.x;
  int wv = tid >> 6, lane = tid & 63;
  int wc = wv & 1;
  int wy = wv >> 1;
  int L = blockIdx.x;
  int spatial = L / (NBG*2);
  int rem = L % (NBG*2);
  int cog = rem % NBG;
  int bb  = rem / NBG;
  int xg = spatial % 7, yg = spatial / 7;
  int x0 = xg*16;
  int m = lane & 15, q = lane >> 4;
  int nb0 = cog*4 + wc*2;
  floatx4 acc[4][2];
  #pragma unroll
  for (int r=0;r<4;++r)
    #pragma unroll
    for (int u=0;u<2;++u) acc[r][u] = (floatx4)(0.f);

  const short8* gAh = (const short8*)(const void*)Ah;
  const short8* gAl = (const short8*)(const void*)Al;
  const short8* gWh = (const short8*)(const void*)Wph;
  const short8* gWl = (const short8*)(const void*)Wpl;
  const size_t nbstride = (size_t)NB*64;

  short8 pbh[2], pbl[2];
  #pragma unroll
  for (int u=0;u<2;++u){
    pbh[u] = gWh[(size_t)(nb0+u)*64 + lane];
    pbl[u] = gWl[(size_t)(nb0+u)*64 + lane];
  }

  for (int kb=0; kb<8; ++kb){
    __syncthreads();
    for (int i = tid; i < 720; i += 256){
      int rc = i >> 2, part = i & 3;
      int r = rc / 18, c = rc % 18;
      int yr = yg*8 + r; if (yr > 101) yr = 101;
      int xc = x0 + c;   if (xc > 101) xc = 101;
      size_t so = ((size_t)((bb*102 + yr)*102 + xc))*32 + kb*4 + part;
      short8 vh = gAh[so], vl = gAl[so];
      int dst = (r*18 + c)*44 + part*8;
      *(short8*)(sAh + dst) = vh;
      *(short8*)(sAl + dst) = vl;
    }
    __syncthreads();
    #pragma unroll 3
    for (int tap=0; tap<9; ++tap){
      int idx2 = kb*9 + tap;
      short8 cbh0 = pbh[0], cbh1 = pbh[1];
      short8 cbl0 = pbl[0], cbl1 = pbl[1];
      int nx = (idx2+1 < 72) ? idx2+1 : 71;
      #pragma unroll
      for (int u=0;u<2;++u){
        pbh[u] = gWh[(size_t)nx*nbstride + (size_t)(nb0+u)*64 + lane];
        pbl[u] = gWl[(size_t)nx*nbstride + (size_t)(nb0+u)*64 + lane];
      }
      int dy = (tap*11) >> 5;
      int dx = tap - dy*3;
      int cc = dx + m;
      #pragma unroll
      for (int r=0; r<4; ++r){
        int a0 = ((wy*4 + r + dy)*18 + cc)*44 + q*8;
        short8 cah = *(const short8*)(sAh + a0);
        short8 cal = *(const short8*)(sAl + a0);
        acc[r][0] = __builtin_amdgcn_mfma_f32_16x16x32_bf16(cah, cbh0, acc[r][0], 0,0,0);
        acc[r][0] = __builtin_amdgcn_mfma_f32_16x16x32_bf16(cah, cbl0, acc[r][0], 0,0,0);
        acc[r][0] = __builtin_amdgcn_mfma_f32_16x16x32_bf16(cal, cbh0, acc[r][0], 0,0,0);
        acc[r][1] = __builtin_amdgcn_mfma_f32_16x16x32_bf16(cah, cbh1, acc[r][1], 0,0,0);
        acc[r][1] = __builtin_amdgcn_mfma_f32_16x16x32_bf16(cah, cbl1, acc[r][1], 0,0,0);
        acc[r][1] = __builtin_amdgcn_mfma_f32_16x16x32_bf16(cal, cbh1, acc[r][1], 0,0,0);
      }
    }
  }

  int n = lane & 15;
  int xq = x0 + q*4;
  #pragma unroll
  for (int r=0; r<4; ++r){
    int yo = yg*8 + wy*4 + r;
    if (yo < 100 && xq < 100){
      #pragma unroll
      for (int u=0; u<2; ++u){
        int co = (nb0+u)*16 + n;
        float s = bns[co], bv = bnb[co];
        floatx4 a = acc[r][u];
        float v0 = fmaxf(a[0]*s+bv, 0.f);
        float v1 = fmaxf(a[1]*s+bv, 0.f);
        float v2 = fmaxf(a[2]*s+bv, 0.f);
        float v3 = fmaxf(a[3]*s+bv, 0.f);
        if (outNCHW){
          float4 v; v.x=v0; v.y=v1; v.z=v2; v.w=v3;
          size_t o = ((size_t)(bb*Cout+co)*100 + yo)*100 + xq;
          *(float4*)(outF + o) = v;
        } else {
          size_t base = ((size_t)bb*10000 + yo*100 + xq)*256 + co;
          if (resN){
            v0 += resN[base];
            v1 += resN[base+256];
            v2 += resN[base+512];
            v3 += resN[base+768];
          }
          outF[base]     = v0;
          outF[base+256] = v1;
          outF[base+512] = v2;
          outF[base+768] = v3;
        }
      }
    }
  }
}

// ---------- final 1x1 conv 128->16, one pass over h3 (NCHW) ----------
__global__ __launch_bounds__(256) void k_final2(
    const float* __restrict__ h, const float* __restrict__ W, const float* __restrict__ bias,
    float* __restrict__ out)
{
  __shared__ float wsl[2048];
  __shared__ float bs[16];
  int tid = threadIdx.x;
  int b = blockIdx.y;
  for (int i=tid; i<2048; i+=256) wsl[i] = W[i];
  if (tid < 16) bs[tid] = bias[tid];
  __syncthreads();
  int pix = blockIdx.x*256 + tid;
  if (pix >= 10000) return;
  float acc[16];
  #pragma unroll
  for (int oc=0; oc<16; ++oc) acc[oc] = bs[oc];
  const float* hb_ = h + (size_t)b*128*10000 + pix;
  for (int ci=0; ci<128; ++ci){
    float hv = hb_[(size_t)ci*10000];
    #pragma unroll
    for (int oc=0; oc<16; ++oc) acc[oc] += hv * wsl[oc*128 + ci];
  }
  #pragma unroll
  for (int oc=0; oc<16; ++oc)
    out[((size_t)(b*16+oc))*10000 + pix] = acc[oc];
}

extern "C" void kernel_launch(void* const* d_in, const int* in_sizes, int n_in,
                              void* d_out, int out_size, void* d_ws, size_t ws_size,
                              hipStream_t stream)
{
  (void)in_sizes; (void)n_in; (void)out_size; (void)ws_size;
  const float* feats = (const float*)d_in[0];
  const float* rots  = (const float*)d_in[1];
  const float* trans = (const float*)d_in[2];
  const float* intr  = (const float*)d_in[3];
  const float* nw1   = (const float*)d_in[4];
  const float* bn1s  = (const float*)d_in[5];
  const float* bn1b  = (const float*)d_in[6];
  const float* se1w1 = (const float*)d_in[7];
  const float* se1b1 = (const float*)d_in[8];
  const float* se1w2 = (const float*)d_in[9];
  const float* se1b2 = (const float*)d_in[10];
  const float* nw2   = (const float*)d_in[11];
  const float* bn2s  = (const float*)d_in[12];
  const float* bn2b  = (const float*)d_in[13];
  const float* dhw   = (const float*)d_in[14];
  const float* dhb   = (const float*)d_in[15];
  const float* chw   = (const float*)d_in[16];
  const float* chb   = (const float*)d_in[17];
  const float* bcw1  = (const float*)d_in[18];
  const float* bcs1  = (const float*)d_in[19];
  const float* bcb1  = (const float*)d_in[20];
  const float* bcsw1 = (const float*)d_in[21];
  const float* bcsb1 = (const float*)d_in[22];
  const float* bcsw2 = (const float*)d_in[23];
  const float* bcsb2 = (const float*)d_in[24];
  const float* bcw2  = (const float*)d_in[25];
  const float* bcs2  = (const float*)d_in[26];
  const float* bcb2  = (const float*)d_in[27];
  const float* dw1   = (const float*)d_in[28];
  const float* ds1   = (const float*)d_in[29];
  const float* db1   = (const float*)d_in[30];
  const float* dw2   = (const float*)d_in[31];
  const float* db2   = (const float*)d_in[32];
  float* out = (float*)d_out;

  // ---- workspace layout (float units) ----
  float* ws = (float*)d_ws;
  float* bev   = ws;                       // S0: 5,120,000 (NHWC [b][pix][256])
  float* h1    = ws + 5120000;             // S1: 5,120,000 (NHWC)
  hb*    Ah    = (hb*)(ws + 10240000);     // S2: 2,663,424 fu
  hb*    Al    = (hb*)(ws + 12903424);     // S3: 2,663,424 fu
  float* x2    = ws + 15566848;            // S4: 1,216,512
  float* S5    = ws + 16783360;            // 589,824
  float* dep   = ws + 17373184;            // 190,080
  float* ctx2  = ws + 17563264;            // 304,128
  float* mean1 = ws + 17867392;            // 3072
  float* g1    = mean1 + 3072;
  float* mean2 = g1 + 3072;
  float* g2    = mean2 + 512;
  int*   vox   = (int*)(ws + 17875584);    // 190,080 ints
  // phase aliases
  hb* Fph  = (hb*)bev;
  hb* Wc1h = (hb*)(bev + 3041280);
  hb* Wc1l = (hb*)(bev + 3205120);
  float* x1 = h1;
  hb* Fpl  = (hb*)(h1 + 1216512);
  hb* Xh   = (hb*)Ah;
  hb* Xl   = (hb*)Al;
  hb* Wc2h = (hb*)S5;
  hb* Wc2l = (hb*)(S5 + 294912);
  hb* x2h  = (hb*)x2;
  hb* x2l  = (hb*)(x2 + 608256);
  hb* Whh  = (hb*)S5;
  hb* Whl  = (hb*)(S5 + 14336);
  int* cnt  = (int*)h1;                    // splat arrays in h1 (dead until conv1 out)
  int* off  = cnt + 80000;
  int* cur  = off + 80000;
  int* bsum = cur + 80000;
  int* list = bsum + 1024;
  float* depv = (float*)(list + 190080);   // 190,080 fu, still inside h1
  float* h3 = h1;                          // conv3 out NCHW (h1 dead by then)
  hb* Wp1h = (hb*)x2;
  hb* Wp1l = (hb*)(x2 + 294912);
  hb* Wp3h = (hb*)(x2 + 589824);
  hb* Wp3l = (hb*)(x2 + 589824 + 147456);
  hb* Wp2h = (hb*)S5;
  hb* Wp2l = (hb*)(S5 + 294912);

  // ---- image branch (MFMA) ----
  k_trans_featsP<<<dim3(7,20,12),256,0,stream>>>(feats,Fph,Fpl);
  k_wpackE<<<3584,256,0,stream>>>(nw1,nw2,Wc1h,Wc1l,Wc2h,Wc2l);
  k_mfma_gemm1<<<dim3(38,4),256,0,stream>>>(Fph,Fpl,Wc1h,Wc1l,bn1s,bn1b,x1);
  k_meanse<<<12,256,0,stream>>>(x1,se1w1,se1b1,se1w2,se1b2,g1);
  k_topad<<<dim3(14,12),256,0,stream>>>(x1,g1,Xh,Xl);
  k_conv3_img<<<dim3(3,24,4),256,0,stream>>>(Xh,Xl,Wc2h,Wc2l,bn2s,bn2b,x2h,x2l);
  k_wpackH<<<112,256,0,stream>>>(dhw,chw,Whh,Whl);
  k_headsM<<<dim3(38,2),256,0,stream>>>(x2h,x2l,Whh,Whl,dhb,chb,dep,ctx2);
  k_softmax40<<<19,256,0,stream>>>(dep);

  // ---- pack BEV conv weights kb-major ----
  k_wpackT3<<<5760,256,0,stream>>>(bcw1,bcw2,dw1,Wp1h,Wp1l,Wp2h,Wp2l,Wp3h,Wp3l);

  // ---- lift-splat (gather form; NHWC bev + fused bf16 pack) ----
  hipMemsetAsync(cnt, 0, 80000*sizeof(int), stream);
  k_geom<<<(190080+255)/256,256,0,stream>>>(rots,trans,intr,vox,cnt);
  k_scan1<<<313,256,0,stream>>>(cnt,off,bsum);
  k_scan2<<<1,64,0,stream>>>(bsum,313);
  k_scan3<<<(80000+255)/256,256,0,stream>>>(off,bsum,cur);
  k_fill<<<(190080+255)/256,256,0,stream>>>(vox,cur,list,dep,depv);
  k_zero_ring<<<808,256,0,stream>>>(Ah,Al);
  k_gather<<<20000,256,0,stream>>>(off,cnt,list,depv,ctx2,bev,Ah,Al);

  // ---- BEV encoder (MFMA convs, NHWC activations) ----
  k_conv3_bevm<<<728,256,0,stream>>>(Ah,Al,Wp1h,Wp1l,bcs1,bcb1,nullptr,h1,0,256,4);
  hipMemsetAsync(mean2, 0, 512*sizeof(float), stream);
  k_mean_nhwc<<<dim3(40,2),256,0,stream>>>(h1,mean2);
  k_se_fc<<<2,256,0,stream>>>(mean2,bcsw1,bcsb1,bcsw2,bcsb2,g2,16);
  k_packA<<<dim3(100,25,2),256,0,stream>>>(h1,g2,Ah,Al);
  k_conv3_bevm<<<728,256,0,stream>>>(Ah,Al,Wp2h,Wp2l,bcs2,bcb2,bev,bev,0,256,4);
  k_packA<<<dim3(100,25,2),256,0,stream>>>(bev,nullptr,Ah,Al);
  k_conv3_bevm<<<364,256,0,stream>>>(Ah,Al,Wp3h,Wp3l,ds1,db1,nullptr,h3,1,128,2);
  k_final2<<<dim3(40,2),256,0,stream>>>(h3,dw2,db2,out);
}